// Round 2
// baseline (3471.490 us; speedup 1.0000x reference)
//
#include <hip/hip_runtime.h>
#include <math.h>

typedef float2 cplx;
#define PI_D 3.14159265358979323846

__device__ __forceinline__ int iabs_(int v){ return v < 0 ? -v : v; }

// ======================= table kernels =======================
__global__ void k_tables(double* lf, double* wq){
  if(threadIdx.x == 0){
    lf[0] = 0.0;
    double acc = 0.0;
    for(int i = 1; i <= 128; ++i){ acc += log((double)i); lf[i] = acc; }
  }
  int t = threadIdx.x;
  int b, j, off;
  if(t < 64){ b = 32; j = t; off = 0; }
  else if(t < 96){ b = 16; j = t - 64; off = 64; }
  else if(t < 112){ b = 8; j = t - 96; off = 96; }
  else if(t < 120){ b = 4; j = t - 112; off = 112; }
  else return;
  double beta = PI_D * (2*j+1) / (4.0*b);
  double s = 0.0;
  for(int p = 0; p < b; ++p) s += sin((2*p+1)*beta) / (2*p+1);
  wq[off+j] = 2.0*PI_D/((double)b*b) * sin(beta) * s;
}

__global__ void k_twiddle(cplx* E, int nfreq, int n, int center, double sgn){
  int idx = blockIdx.x*blockDim.x + threadIdx.x;
  if(idx >= nfreq*n) return;
  int p = idx / n, a = idx % n;
  double ang = sgn * 2.0*PI_D * (double)(p-center) * (double)a / (double)n;
  E[idx] = make_float2((float)cos(ang), (float)sin(ang));
}

// Wigner-d, n=0 column only: out[j][l][m] (W-wide, centered)
__global__ void k_wigner_col0(const double* __restrict__ lf, float* __restrict__ out,
                              int nb, int Lmax, int W, int mode, int bq){
  int idx = blockIdx.x*blockDim.x + threadIdx.x;
  int total = nb*Lmax*W;
  if(idx >= total) return;
  int m = idx % W;
  int l = (idx/W) % Lmax;
  int j = idx/(W*Lmax);
  int cw = (W-1)/2;
  int mh = m - cw;
  float r = 0.f;
  if(iabs_(mh) <= l){
    double beta = (mode==0) ? PI_D*(2*j+1)/(4.0*bq) : PI_D*(j+1)/16.0;
    double cb = cos(0.5*beta), sb = sin(0.5*beta);
    double lcb = log(cb), lsb = log(sb);
    int k0 = (mh < 0) ? -mh : 0;
    int k1 = (mh > 0) ? (l - mh) : l;
    double s = 0.0;
    for(int k = k0; k <= k1; ++k){
      double logc = 0.5*(lf[l+mh] + lf[l-mh] + 2.0*lf[l])
                    - lf[l-k] - lf[k] - lf[mh+k] - lf[l-mh-k];
      double term = exp(logc + (double)(2*l - mh - 2*k)*lcb + (double)(mh + 2*k)*lsb);
      s += ((mh + k) & 1) ? -term : term;
    }
    r = (float)s;
  }
  out[idx] = r;
}

// Full Wigner-d: out[j][l][p][q] (W x W, centered, zero-padded)
__global__ void k_wigner_full(const double* __restrict__ lf, float* __restrict__ out,
                              int nb, int L, int W, int mode, int bq){
  int idx = blockIdx.x*blockDim.x + threadIdx.x;
  int total = nb*L*W*W;
  if(idx >= total) return;
  int q = idx % W;
  int p = (idx/W) % W;
  int l = (idx/(W*W)) % L;
  int j = idx/(W*W*L);
  int cw = (W-1)/2;
  int mh = p - cw, nh = q - cw;
  float r = 0.f;
  if(iabs_(mh) <= l && iabs_(nh) <= l){
    double beta = (mode==0) ? PI_D*(2*j+1)/(4.0*bq) : PI_D*(j+1)/16.0;
    double cb = cos(0.5*beta), sb = sin(0.5*beta);
    double lcb = log(cb), lsb = log(sb);
    int k0 = (nh - mh > 0) ? (nh - mh) : 0;
    int a1 = l + nh, b1 = l - mh;
    int k1 = (a1 < b1) ? a1 : b1;
    double s = 0.0;
    for(int k = k0; k <= k1; ++k){
      double logc = 0.5*(lf[l+mh] + lf[l-mh] + lf[l+nh] + lf[l-nh])
                    - lf[l+nh-k] - lf[k] - lf[mh-nh+k] - lf[l-mh-k];
      double term = exp(logc + (double)(2*l + nh - mh - 2*k)*lcb + (double)(mh - nh + 2*k)*lsb);
      s += ((mh - nh + k) & 1) ? -term : term;
    }
    r = (float)s;
  }
  out[idx] = r;
}

// ======================= layer-0 (S2) kernels =======================
__global__ void k_fft0(const float* __restrict__ x, cplx* __restrict__ xf, const cplx* __restrict__ E0f){
  int idx = blockIdx.x*blockDim.x + threadIdx.x;
  if(idx >= 1536*31) return;
  int m = idx % 31;
  int r = idx / 31;
  const float* xr = x + (size_t)r*64;
  float sr = 0.f, si = 0.f;
  for(int a = 0; a < 64; ++a){
    cplx e = E0f[m*64 + a];
    float v = xr[a];
    sr += v*e.x; si += v*e.y;
  }
  xf[idx] = make_float2(sr*(1.f/64.f), si*(1.f/64.f));
}

__global__ void k_what0(const float* __restrict__ w0, const cplx* __restrict__ E0f, cplx* __restrict__ what0){
  int idx = blockIdx.x*blockDim.x + threadIdx.x;
  if(idx >= 96*2*31) return;
  int m = idx % 31;
  int bi = (idx/31) & 1;
  int oi = idx/62;
  const float* wr = w0 + (size_t)oi*128 + bi*64;
  float sr = 0.f, si = 0.f;
  for(int a = 0; a < 64; ++a){
    cplx e = E0f[m*64 + a];
    float v = wr[a];
    sr += v*e.x; si += v*e.y;
  }
  what0[idx] = make_float2(sr, si);
}

__global__ void k_X0(const cplx* __restrict__ xf, const float* __restrict__ d032,
                     const double* __restrict__ wq32, cplx* __restrict__ X0){
  int idx = blockIdx.x*blockDim.x + threadIdx.x;
  if(idx >= 24*16*31) return;
  int m = idx % 31;
  int l = (idx/31) % 16;
  int ci = idx/(31*16);
  float sx = 0.f, sy = 0.f;
  if(iabs_(m-15) <= l){
    for(int j = 0; j < 64; ++j){
      float d = d032[((size_t)j*16 + l)*31 + m] * (float)wq32[j];
      cplx v = xf[((size_t)ci*64 + j)*31 + m];
      sx += d*v.x; sy += d*v.y;
    }
  }
  X0[idx] = make_float2(sx, sy);
}

__global__ void k_Psi0(const cplx* __restrict__ what0, const float* __restrict__ dg32, cplx* __restrict__ Psi0){
  int idx = blockIdx.x*blockDim.x + threadIdx.x;
  if(idx >= 96*16*31) return;
  int m = idx % 31;
  int l = (idx/31) % 16;
  int oi = idx/(31*16);
  float sx = 0.f, sy = 0.f;
  if(iabs_(m-15) <= l){
    for(int bi = 0; bi < 2; ++bi){
      float d = dg32[((size_t)bi*16 + l)*31 + m];
      cplx v = what0[((size_t)oi*2 + bi)*31 + m];
      sx += d*v.x; sy += d*v.y;
    }
  }
  Psi0[idx] = make_float2(sx, sy);
}

__global__ void k_Z0(const cplx* __restrict__ X0, const cplx* __restrict__ Psi0, cplx* __restrict__ Z){
  int idx = blockIdx.x*blockDim.x + threadIdx.x;
  if(idx >= 8*32*16*961) return;
  int q = idx % 31;
  int p = (idx/31) % 31;
  int l = (idx/961) % 16;
  int o = (idx/(961*16)) % 32;
  int c = idx/(961*16*32);
  float sx = 0.f, sy = 0.f;
  if(iabs_(p-15) <= l && iabs_(q-15) <= l){
    for(int i = 0; i < 3; ++i){
      cplx a = X0[(((size_t)c*3 + i)*16 + l)*31 + p];
      cplx b = Psi0[(((size_t)o*3 + i)*16 + l)*31 + q];
      sx += a.x*b.x + a.y*b.y;
      sy += a.y*b.x - a.x*b.y;
    }
  }
  Z[idx] = make_float2(sx, sy);
}

// ======================= generic SO3 kernels =======================
__global__ void k_ifft(const cplx* __restrict__ Zt, const float* __restrict__ Wst,
                       const cplx* __restrict__ E, float* __restrict__ out,
                       int b, int C, int O){
  int M = 2*b-1, n2 = 2*b, cw = b-1;
  extern __shared__ char smem[];
  cplx* gt = (cplx*)smem;          // M*M
  cplx* Tt = gt + M*M;             // n2*M
  int blk = blockIdx.x;
  int j = blk % n2;
  int co = blk / n2;
  const cplx* Zp = Zt + (size_t)co * b * M * M;
  for(int t = threadIdx.x; t < M*M; t += blockDim.x){
    int p = t / M, q = t % M;
    int lmin = iabs_(p-cw); int l2 = iabs_(q-cw); if(l2 > lmin) lmin = l2;
    float sx = 0.f, sy = 0.f;
    for(int l = lmin; l < b; ++l){
      float w = Wst[(((size_t)j*b + l)*M + p)*M + q] * (float)(2*l+1);
      cplx z = Zp[((size_t)l*M + p)*M + q];
      sx += w*z.x; sy += w*z.y;
    }
    gt[t] = make_float2(sx, sy);
  }
  __syncthreads();
  for(int t = threadIdx.x; t < n2*M; t += blockDim.x){
    int a = t / M, q = t % M;
    float sx = 0.f, sy = 0.f;
    for(int p = 0; p < M; ++p){
      cplx e = E[p*n2 + a];
      cplx g = gt[p*M + q];
      sx += g.x*e.x - g.y*e.y;
      sy += g.x*e.y + g.y*e.x;
    }
    Tt[t] = make_float2(sx, sy);
  }
  __syncthreads();
  float* op = out + (size_t)co*n2*n2*n2 + (size_t)j*n2*n2;
  for(int t = threadIdx.x; t < n2*n2; t += blockDim.x){
    int a = t / n2, g = t % n2;
    float s = 0.f;
    for(int q = 0; q < M; ++q){
      cplx e = E[q*n2 + g];
      cplx T = Tt[a*M + q];
      s += T.x*e.x - T.y*e.y;   // real part only
    }
    op[t] = s;
  }
}

__global__ void k_fft2(const float* __restrict__ f, cplx* __restrict__ hf,
                       const cplx* __restrict__ E, int b, int Mt, int CI){
  int M = 2*b-1, n2 = 2*b;
  int off = (M - Mt)/2;
  extern __shared__ char smem[];
  float* ft = (float*)smem;                                // n2*n2
  cplx* Ft = (cplx*)(smem + sizeof(float)*n2*n2);          // n2*Mt
  int blk = blockIdx.x;
  int j = blk % n2, ci = blk / n2;
  const float* fp = f + ((size_t)ci*n2 + j)*n2*n2;
  for(int t = threadIdx.x; t < n2*n2; t += blockDim.x) ft[t] = fp[t];
  __syncthreads();
  for(int t = threadIdx.x; t < n2*Mt; t += blockDim.x){
    int a = t / Mt, q = t % Mt;
    float sr = 0.f, si = 0.f;
    for(int g = 0; g < n2; ++g){
      cplx e = E[(q+off)*n2 + g];     // use conj(e)
      float v = ft[a*n2 + g];
      sr += v*e.x; si -= v*e.y;
    }
    Ft[t] = make_float2(sr, si);
  }
  __syncthreads();
  float inv = 1.0f / ((float)n2*(float)n2);
  cplx* hp = hf + ((size_t)ci*n2 + j)*Mt*Mt;
  for(int t = threadIdx.x; t < Mt*Mt; t += blockDim.x){
    int p = t / Mt, q = t % Mt;
    float sx = 0.f, sy = 0.f;
    for(int a = 0; a < n2; ++a){
      cplx e = E[(p+off)*n2 + a];     // conj
      cplx F = Ft[a*Mt + q];
      sx += F.x*e.x + F.y*e.y;
      sy += F.y*e.x - F.x*e.y;
    }
    hp[t] = make_float2(sx*inv, sy*inv);
  }
}

__global__ void k_Xstep(const cplx* __restrict__ hf, const float* __restrict__ Wst,
                        const double* __restrict__ wqp, cplx* __restrict__ X,
                        int b, int Lout, int Mt, int CI){
  int M = 2*b-1, n2 = 2*b;
  int off = (M - Mt)/2, cw = (Mt-1)/2;
  int total = CI*Lout*Mt*Mt;
  int idx = blockIdx.x*blockDim.x + threadIdx.x;
  if(idx >= total) return;
  int q = idx % Mt;
  int p = (idx/Mt) % Mt;
  int l = (idx/(Mt*Mt)) % Lout;
  int ci = idx/(Mt*Mt*Lout);
  float sx = 0.f, sy = 0.f;
  if(iabs_(p-cw) <= l && iabs_(q-cw) <= l){
    for(int j = 0; j < n2; ++j){
      float w = Wst[(((size_t)j*b + l)*M + p + off)*M + q + off] * (float)wqp[j];
      cplx v = hf[(((size_t)ci*n2 + j)*Mt + p)*Mt + q];
      sx += w*v.x; sy += w*v.y;
    }
  }
  X[idx] = make_float2(sx, sy);
}

__global__ void k_what(const float* __restrict__ w, cplx* __restrict__ what,
                       const cplx* __restrict__ E, int n2, int Mt, int off, int OI){
  int total = OI*2*Mt;
  int idx = blockIdx.x*blockDim.x + threadIdx.x;
  if(idx >= total) return;
  int p = idx % Mt;
  int bi = (idx/Mt) & 1;
  int oi = idx/(2*Mt);
  const float* wr = w + (size_t)oi*4*n2 + (size_t)bi*2*n2;
  float sr = 0.f, si = 0.f;
  for(int a = 0; a < n2; ++a){
    float v = wr[2*a] + wr[2*a+1];
    cplx e = E[(p+off)*n2 + a];     // conj
    sr += v*e.x; si -= v*e.y;
  }
  what[idx] = make_float2(sr, si);
}

// Z[c,o,l,p,q] = sum_{i,k} X[c,i,l,p,k] * conj(Psi[o,i,l,q,k])
// Register-tiled: 64x64 block tile, 4x4 complex micro-tile per thread.
// Psi reconstructed on the fly: Psi = Dg0[l,q,k]*what[o,i,0,q] + Dg1[l,q,k]*what[o,i,1,q]
__global__ __launch_bounds__(256) void k_zconv_rt(
    const cplx* __restrict__ X, const cplx* __restrict__ what,
    const float* __restrict__ Dg, cplx* __restrict__ Z,
    int C, int O, int I, int Wt, int Wd, int Lx, int Ld){
  int l = blockIdx.z;
  int Lz = gridDim.z;
  int cw = (Wt-1)/2;
  int offd = (Wd-1)/2 - cw;
  int K21 = 2*l+1;
  int K = I*K21;
  int koff = cw - l;
  int RM = C*Wt, CN = O*Wt;
  int tx = threadIdx.x, ty = threadIdx.y;
  int tid = ty*16 + tx;

  __shared__ cplx As[16][64];
  __shared__ cplx Bs[16][64];

  // ---- fixed per-thread load coordinates ----
  int lm = tid & 63;        // tile-row (A) / tile-col (B) index, fixed
  int lk0 = tid >> 6;       // k sub-index base (0..3); k = lk0 + 4*t

  int arow = blockIdx.x*64 + lm;
  int ac = arow / Wt, ap = arow % Wt;
  bool av = (arow < RM) && (iabs_(ap - cw) <= l);
  const cplx* Xrow = X + (((size_t)ac*I)*Lx + l)*Wt*Wt + (size_t)ap*Wt + koff;
  size_t Xistride = (size_t)Lx*Wt*Wt;

  int bcol = blockIdx.y*64 + lm;
  int bo = bcol / Wt, bq = bcol % Wt;
  bool bv = (bcol < CN) && (iabs_(bq - cw) <= l);
  int qf = bq + offd;
  const float* Dg0 = Dg + ((size_t)l*Wd + qf)*Wd + (koff + offd);
  const float* Dg1 = Dg0 + (size_t)Ld*Wd*Wd;
  const cplx* wbase = what + ((size_t)bo*I)*2*Wt + bq;

  float accx[4][4], accy[4][4];
  #pragma unroll
  for(int u = 0; u < 4; ++u)
    #pragma unroll
    for(int v = 0; v < 4; ++v){ accx[u][v] = 0.f; accy[u][v] = 0.f; }

  for(int kk = 0; kk < K; kk += 16){
    #pragma unroll
    for(int t = 0; t < 4; ++t){
      int k = lk0 + 4*t;
      int kg = kk + k;
      cplx v = make_float2(0.f, 0.f);
      if(av && kg < K){
        int i = kg / K21, kr = kg - i*K21;
        v = Xrow[i*Xistride + kr];
      }
      As[k][lm] = v;
    }
    #pragma unroll
    for(int t = 0; t < 4; ++t){
      int k = lk0 + 4*t;
      int kg = kk + k;
      cplx v = make_float2(0.f, 0.f);
      if(bv && kg < K){
        int i = kg / K21, kr = kg - i*K21;
        float d0 = Dg0[kr];
        float d1 = Dg1[kr];
        cplx w0 = wbase[(size_t)i*2*Wt];
        cplx w1 = wbase[(size_t)i*2*Wt + Wt];
        v = make_float2(d0*w0.x + d1*w1.x, -(d0*w0.y + d1*w1.y)); // conj(Psi)
      }
      Bs[k][lm] = v;
    }
    __syncthreads();
    #pragma unroll
    for(int k = 0; k < 16; ++k){
      cplx a[4], b[4];
      #pragma unroll
      for(int u = 0; u < 4; ++u) a[u] = As[k][ty + 16*u];
      #pragma unroll
      for(int v = 0; v < 4; ++v) b[v] = Bs[k][tx + 16*v];
      #pragma unroll
      for(int u = 0; u < 4; ++u)
        #pragma unroll
        for(int v = 0; v < 4; ++v){
          accx[u][v] += a[u].x*b[v].x - a[u].y*b[v].y;
          accy[u][v] += a[u].x*b[v].y + a[u].y*b[v].x;
        }
    }
    __syncthreads();
  }

  // ---- epilogue ----
  #pragma unroll
  for(int u = 0; u < 4; ++u){
    int row = blockIdx.x*64 + ty + 16*u;
    if(row >= RM) continue;
    int c = row / Wt, p = row % Wt;
    bool rv = (iabs_(p - cw) <= l);
    #pragma unroll
    for(int v = 0; v < 4; ++v){
      int col = blockIdx.y*64 + tx + 16*v;
      if(col >= CN) continue;
      int o = col / Wt, q = col % Wt;
      bool cv = (iabs_(q - cw) <= l);
      size_t zidx = ((((size_t)c*O + o)*Lz + l)*Wt + p)*Wt + q;
      Z[zidx] = (rv && cv) ? make_float2(accx[u][v], accy[u][v])
                           : make_float2(0.f, 0.f);
    }
  }
}

// Identity-grid conv: Z[c,o,l,p,q] = sum_i X[c,i,l,p,q] * w[o,i]
__global__ void k_zid(const cplx* __restrict__ X, const float* __restrict__ w,
                      cplx* __restrict__ Z, int C, int O, int I, int Lz, int Wt, int Wx, int Lx){
  int total = C*O*Lz*Wt*Wt;
  int idx = blockIdx.x*blockDim.x + threadIdx.x;
  if(idx >= total) return;
  int q = idx % Wt;
  int p = (idx/Wt) % Wt;
  int l = (idx/(Wt*Wt)) % Lz;
  int o = (idx/(Wt*Wt*Lz)) % O;
  int c = idx/(Wt*Wt*Lz*O);
  int cw = (Wt-1)/2, offx = (Wx-Wt)/2;
  float sx = 0.f, sy = 0.f;
  if(iabs_(p-cw) <= l && iabs_(q-cw) <= l){
    for(int i = 0; i < I; ++i){
      cplx v = X[((((size_t)c*I + i)*Lx + l)*Wx + p + offx)*Wx + q + offx];
      float wv = w[o*I + i];
      sx += wv*v.x; sy += wv*v.y;
    }
  }
  Z[idx] = make_float2(sx, sy);
}

// ======================= norm / misc =======================
__global__ void k_gn(const float* __restrict__ x, const float* __restrict__ gam,
                     const float* __restrict__ bet, float* __restrict__ y,
                     int Cch, int G, int S, int relu){
  int n = blockIdx.x / G, g = blockIdx.x % G;
  int cpg = Cch / G;
  size_t base = ((size_t)n*Cch + (size_t)g*cpg)*S;
  int cnt = cpg*S;
  double s = 0.0, sq = 0.0;
  for(int t = threadIdx.x; t < cnt; t += blockDim.x){
    float v = x[base + t]; s += v; sq += (double)v*v;
  }
  __shared__ double rs[256], rq[256];
  int tid = threadIdx.x;
  rs[tid] = s; rq[tid] = sq;
  __syncthreads();
  for(int o = 128; o > 0; o >>= 1){
    if(tid < o){ rs[tid] += rs[tid+o]; rq[tid] += rq[tid+o]; }
    __syncthreads();
  }
  __shared__ float mu_s, inv_s;
  if(tid == 0){
    double m = rs[0]/cnt;
    double var = rq[0]/cnt - m*m;
    mu_s = (float)m;
    inv_s = (float)(1.0/sqrt(var + 1e-5));
  }
  __syncthreads();
  float mu = mu_s, inv = inv_s;
  for(int t = threadIdx.x; t < cnt; t += blockDim.x){
    int c = g*cpg + t/S;
    float v = (x[base+t]-mu)*inv*gam[c] + bet[c];
    y[base+t] = relu ? fmaxf(v, 0.f) : v;
  }
}

__global__ void k_bn(const float* __restrict__ x, const float* __restrict__ gam,
                     const float* __restrict__ bet, float* __restrict__ y,
                     int N, int Cch, int S){
  int c = blockIdx.x;
  int cnt = N*S;
  double s = 0.0, sq = 0.0;
  for(int t = threadIdx.x; t < cnt; t += blockDim.x){
    int n = t / S, sp = t % S;
    float v = x[((size_t)n*Cch + c)*S + sp];
    s += v; sq += (double)v*v;
  }
  __shared__ double rs[256], rq[256];
  int tid = threadIdx.x;
  rs[tid] = s; rq[tid] = sq;
  __syncthreads();
  for(int o = 128; o > 0; o >>= 1){
    if(tid < o){ rs[tid] += rs[tid+o]; rq[tid] += rq[tid+o]; }
    __syncthreads();
  }
  __shared__ float mu_s, inv_s;
  if(tid == 0){
    double m = rs[0]/cnt;
    double var = rq[0]/cnt - m*m;
    mu_s = (float)m;
    inv_s = (float)(1.0/sqrt(var + 1e-5));
  }
  __syncthreads();
  float mu = mu_s, inv = inv_s;
  float ga = gam[c], be = bet[c];
  for(int t = threadIdx.x; t < cnt; t += blockDim.x){
    int n = t / S, sp = t % S;
    size_t id = ((size_t)n*Cch + c)*S + sp;
    y[id] = (x[id]-mu)*inv*ga + be;
  }
}

__global__ void k_addrelu(const float* __restrict__ a, const float* __restrict__ b,
                          float* __restrict__ y, int n){
  int i = blockIdx.x*blockDim.x + threadIdx.x;
  if(i < n) y[i] = fmaxf(a[i] + b[i], 0.f);
}

__global__ void k_integrate(const float* __restrict__ h, const double* __restrict__ wq4,
                            float* __restrict__ out){
  int nc = blockIdx.x;   // n*128 + c
  const float* hp = h + (size_t)nc*512;
  float s = 0.f;
  for(int t = threadIdx.x; t < 512; t += 64){
    int j = t >> 6;
    s += hp[t] * (float)wq4[j];
  }
  for(int o = 32; o > 0; o >>= 1) s += __shfl_down(s, o);
  if(threadIdx.x == 0) out[nc] = s * (1.f/64.f);
}

// ======================= launch =======================
extern "C" void kernel_launch(void* const* d_in, const int* in_sizes, int n_in,
                              void* d_out, int out_size, void* d_ws, size_t ws_size,
                              hipStream_t stream){
  const float* xin = (const float*)d_in[0];
  const float* w0p = (const float*)d_in[1];
  const float* g0p = (const float*)d_in[2];
  const float* b0p = (const float*)d_in[3];
  const float* w1ap = (const float*)d_in[4];
  const float* g1ap = (const float*)d_in[5];
  const float* b1ap = (const float*)d_in[6];
  const float* w1bp = (const float*)d_in[7];
  const float* g1bp = (const float*)d_in[8];
  const float* b1bp = (const float*)d_in[9];
  const float* w1sp = (const float*)d_in[10];
  const float* g1sp = (const float*)d_in[11];
  const float* b1sp = (const float*)d_in[12];
  const float* w2ap = (const float*)d_in[13];
  const float* g2ap = (const float*)d_in[14];
  const float* b2ap = (const float*)d_in[15];
  const float* w2bp = (const float*)d_in[16];
  const float* g2bp = (const float*)d_in[17];
  const float* b2bp = (const float*)d_in[18];
  const float* w2sp = (const float*)d_in[19];
  const float* g2sp = (const float*)d_in[20];
  const float* b2sp = (const float*)d_in[21];
  float* outp = (float*)d_out;

  char* ws = (char*)d_ws;
  size_t off = 0;
  auto alloc = [&](size_t bytes)->char*{
    char* p = ws + off;
    off = (off + bytes + 255) & ~(size_t)255;
    return p;
  };
  // tables (persistent)
  double* lf   = (double*)alloc(130*8);
  double* wq   = (double*)alloc(120*8);      // [0:64) b32, [64:96) b16, [96:112) b8, [112:120) b4
  cplx* E16    = (cplx*)alloc(31*32*8);
  cplx* E8     = (cplx*)alloc(15*16*8);
  cplx* E4     = (cplx*)alloc(7*8*8);
  cplx* E0f    = (cplx*)alloc(31*64*8);
  float* d032  = (float*)alloc((size_t)64*16*31*4);
  float* dg32  = (float*)alloc((size_t)2*16*31*4);
  float* W16   = (float*)alloc((size_t)32*16*961*4);
  float* Dg16  = (float*)alloc((size_t)2*16*961*4);
  float* W8    = (float*)alloc((size_t)16*8*225*4);
  float* Dg8   = (float*)alloc((size_t)2*8*225*4);
  float* W4    = (float*)alloc((size_t)8*4*49*4);
  // arenas (explicit reuse; liveness verified per stage)
  char* A_ZHF = alloc((size_t)63*1024*1024);   // Z / hf alternate here (never live together)
  char* A_X   = alloc((size_t)32*1024*1024);   // X1 then X2
  char* A_H1  = alloc((size_t)34*1024*1024);
  char* A_H2  = alloc((size_t)34*1024*1024);
  char* A_S   = alloc((size_t)8*1024*1024);    // small per-phase scratch

  // phase aliases
  cplx* xf0    = (cplx*)(A_S);
  cplx* X0     = (cplx*)(A_S + (512<<10));
  cplx* what0  = (cplx*)(A_S + (768<<10));
  cplx* Psi0   = (cplx*)(A_S + (1<<20));
  cplx* Zt0    = (cplx*)A_ZHF;
  float* h0    = (float*)A_H1;
  float* h0n   = (float*)A_H2;
  cplx* hf1    = (cplx*)A_ZHF;
  cplx* X1     = (cplx*)A_X;
  cplx* what1a = (cplx*)A_S;
  cplx* Z1a    = (cplx*)A_ZHF;
  float* left1 = (float*)A_H1;
  float* left1n= (float*)A_H2;
  cplx* hf1b   = (cplx*)A_ZHF;
  cplx* X1b    = (cplx*)A_S;
  cplx* what1b = (cplx*)(A_S + (4<<20));
  cplx* Z1b    = (cplx*)A_ZHF;
  float* left2 = (float*)A_H1;
  float* left2n= (float*)(A_H1 + (16<<20));
  cplx* Z1s    = (cplx*)A_ZHF;
  float* sc1   = (float*)A_H2;
  float* sc1n  = (float*)(A_H2 + (16<<20));
  float* h1    = (float*)A_H1;
  cplx* hf2    = (cplx*)A_ZHF;
  cplx* X2     = (cplx*)A_X;
  cplx* what2a = (cplx*)A_S;
  cplx* Z2a    = (cplx*)A_ZHF;
  float* left3 = (float*)A_H2;
  float* left3n= (float*)(A_H2 + (16<<20));
  cplx* hf2b   = (cplx*)A_ZHF;
  cplx* X2b    = (cplx*)A_S;
  cplx* what2b = (cplx*)(A_S + (1<<20));
  cplx* Z2b    = (cplx*)A_ZHF;
  float* left4 = (float*)A_H1;
  float* left4n= (float*)(A_H1 + (4<<20));
  cplx* Z2s    = (cplx*)A_ZHF;
  float* sc2   = (float*)A_H2;
  float* sc2n  = (float*)(A_H2 + (4<<20));
  float* h2    = (float*)(A_H1 + (8<<20));

  // ---- tables ----
  k_tables<<<1,256,0,stream>>>(lf, wq);
  k_twiddle<<<(31*32+255)/256,256,0,stream>>>(E16, 31, 32, 15,  1.0);
  k_twiddle<<<1,256,0,stream>>>(E8, 15, 16, 7,  1.0);
  k_twiddle<<<1,64,0,stream>>>(E4, 7, 8, 3,  1.0);
  k_twiddle<<<(31*64+255)/256,256,0,stream>>>(E0f, 31, 64, 15, -1.0);
  k_wigner_col0<<<(64*16*31+255)/256,256,0,stream>>>(lf, d032, 64, 16, 31, 0, 32);
  k_wigner_col0<<<(2*16*31+255)/256,256,0,stream>>>(lf, dg32, 2, 16, 31, 1, 0);
  k_wigner_full<<<(32*16*961+255)/256,256,0,stream>>>(lf, W16, 32, 16, 31, 0, 16);
  k_wigner_full<<<(2*16*961+255)/256,256,0,stream>>>(lf, Dg16, 2, 16, 31, 1, 0);
  k_wigner_full<<<(16*8*225+255)/256,256,0,stream>>>(lf, W8, 16, 8, 15, 0, 8);
  k_wigner_full<<<(2*8*225+255)/256,256,0,stream>>>(lf, Dg8, 2, 8, 15, 1, 0);
  k_wigner_full<<<(8*4*49+255)/256,256,0,stream>>>(lf, W4, 8, 4, 7, 0, 4);

  // ---- layer 0: s2_conv(x, w0, 32, 16) + GN + ReLU ----
  k_fft0<<<(1536*31+255)/256,256,0,stream>>>(xin, xf0, E0f);
  k_what0<<<(96*2*31+255)/256,256,0,stream>>>(w0p, E0f, what0);
  k_X0<<<(24*16*31+255)/256,256,0,stream>>>(xf0, d032, wq, X0);
  k_Psi0<<<(96*16*31+255)/256,256,0,stream>>>(what0, dg32, Psi0);
  k_Z0<<<(8*32*16*961+255)/256,256,0,stream>>>(X0, Psi0, Zt0);
  k_ifft<<<8*32*32,256,(961+992)*8,stream>>>(Zt0, W16, E16, h0, 16, 8, 32);
  k_gn<<<8*16,256,0,stream>>>(h0, g0p, b0p, h0n, 32, 16, 32768, 1);

  // ---- layer 1a: so3_conv(h, w1a, 16, 16) + GN ----
  k_fft2<<<256*32,256,4096+32*31*8,stream>>>(h0n, hf1, E16, 16, 31, 256);
  k_Xstep<<<(256*16*961+255)/256,256,0,stream>>>(hf1, W16, wq+64, X1, 16, 16, 31, 256);
  k_what<<<(1024*2*31+255)/256,256,0,stream>>>(w1ap, what1a, E16, 32, 31, 0, 1024);
  { dim3 g(4,16,16), blk(16,16);
    k_zconv_rt<<<g,blk,0,stream>>>(X1, what1a, Dg16, Z1a, 8, 32, 32, 31, 31, 16, 16); }
  k_ifft<<<8*32*32,256,(961+992)*8,stream>>>(Z1a, W16, E16, left1, 16, 8, 32);
  k_gn<<<8*16,256,0,stream>>>(left1, g1ap, b1ap, left1n, 32, 16, 32768, 0);

  // ---- layer 1b: so3_conv(left, w1b, 16, 8) + GN + ReLU ----
  k_fft2<<<256*32,256,4096+32*15*8,stream>>>(left1n, hf1b, E16, 16, 15, 256);
  k_Xstep<<<(256*8*225+255)/256,256,0,stream>>>(hf1b, W16, wq+64, X1b, 16, 8, 15, 256);
  k_what<<<(2048*2*15+255)/256,256,0,stream>>>(w1bp, what1b, E16, 32, 15, 8, 2048);
  { dim3 g(2,15,8), blk(16,16);
    k_zconv_rt<<<g,blk,0,stream>>>(X1b, what1b, Dg16, Z1b, 8, 64, 32, 15, 31, 8, 16); }
  k_ifft<<<8*64*16,256,(225+240)*8,stream>>>(Z1b, W8, E8, left2, 8, 8, 64);
  k_gn<<<8*16,256,0,stream>>>(left2, g1bp, b1bp, left2n, 64, 16, 4096, 1);

  // ---- layer 1s: so3_conv(h, w1s, 16, 8, ID) + BN ; residual add ----
  k_zid<<<(8*64*8*225+255)/256,256,0,stream>>>(X1, w1sp, Z1s, 8, 64, 32, 8, 15, 31, 16);
  k_ifft<<<8*64*16,256,(225+240)*8,stream>>>(Z1s, W8, E8, sc1, 8, 8, 64);
  k_bn<<<64,256,0,stream>>>(sc1, g1sp, b1sp, sc1n, 8, 64, 4096);
  k_addrelu<<<(2097152+255)/256,256,0,stream>>>(left2n, sc1n, h1, 2097152);

  // ---- layer 2a: so3_conv(h, w2a, 8, 8) + GN ----
  k_fft2<<<512*16,256,1024+16*15*8,stream>>>(h1, hf2, E8, 8, 15, 512);
  k_Xstep<<<(512*8*225+255)/256,256,0,stream>>>(hf2, W8, wq+96, X2, 8, 8, 15, 512);
  k_what<<<(4096*2*15+255)/256,256,0,stream>>>(w2ap, what2a, E8, 16, 15, 0, 4096);
  { dim3 g(2,15,8), blk(16,16);
    k_zconv_rt<<<g,blk,0,stream>>>(X2, what2a, Dg8, Z2a, 8, 64, 64, 15, 15, 8, 8); }
  k_ifft<<<8*64*16,256,(225+240)*8,stream>>>(Z2a, W8, E8, left3, 8, 8, 64);
  k_gn<<<8*16,256,0,stream>>>(left3, g2ap, b2ap, left3n, 64, 16, 4096, 0);

  // ---- layer 2b: so3_conv(left, w2b, 8, 4) + GN + ReLU ----
  k_fft2<<<512*16,256,1024+16*7*8,stream>>>(left3n, hf2b, E8, 8, 7, 512);
  k_Xstep<<<(512*4*49+255)/256,256,0,stream>>>(hf2b, W8, wq+96, X2b, 8, 4, 7, 512);
  k_what<<<(8192*2*7+255)/256,256,0,stream>>>(w2bp, what2b, E8, 16, 7, 4, 8192);
  { dim3 g(1,14,4), blk(16,16);
    k_zconv_rt<<<g,blk,0,stream>>>(X2b, what2b, Dg8, Z2b, 8, 128, 64, 7, 15, 4, 8); }
  k_ifft<<<8*128*8,64,(49+56)*8,stream>>>(Z2b, W4, E4, left4, 4, 8, 128);
  k_gn<<<8*32,256,0,stream>>>(left4, g2bp, b2bp, left4n, 128, 32, 512, 1);

  // ---- layer 2s: so3_conv(h, w2s, 8, 4, ID) + BN ; residual add ----
  k_zid<<<(8*128*4*49+255)/256,256,0,stream>>>(X2, w2sp, Z2s, 8, 128, 64, 4, 7, 15, 8);
  k_ifft<<<8*128*8,64,(49+56)*8,stream>>>(Z2s, W4, E4, sc2, 4, 8, 128);
  k_bn<<<128,256,0,stream>>>(sc2, g2sp, b2sp, sc2n, 8, 128, 512);
  k_addrelu<<<(524288+255)/256,256,0,stream>>>(left4n, sc2n, h2, 524288);

  // ---- integrate ----
  k_integrate<<<1024,64,0,stream>>>(h2, wq+112, outp);
}

// Round 3
// 2681.057 us; speedup vs baseline: 1.2948x; 1.2948x over previous
//
#include <hip/hip_runtime.h>
#include <math.h>

typedef float2 cplx;
#define PI_D 3.14159265358979323846

__device__ __forceinline__ int iabs_(int v){ return v < 0 ? -v : v; }

// ======================= table kernels =======================
__global__ void k_tables(double* lf, double* wq){
  if(threadIdx.x == 0){
    lf[0] = 0.0;
    double acc = 0.0;
    for(int i = 1; i <= 128; ++i){ acc += log((double)i); lf[i] = acc; }
  }
  int t = threadIdx.x;
  int b, j, off;
  if(t < 64){ b = 32; j = t; off = 0; }
  else if(t < 96){ b = 16; j = t - 64; off = 64; }
  else if(t < 112){ b = 8; j = t - 96; off = 96; }
  else if(t < 120){ b = 4; j = t - 112; off = 112; }
  else return;
  double beta = PI_D * (2*j+1) / (4.0*b);
  double s = 0.0;
  for(int p = 0; p < b; ++p) s += sin((2*p+1)*beta) / (2*p+1);
  wq[off+j] = 2.0*PI_D/((double)b*b) * sin(beta) * s;
}

__global__ void k_twiddle(cplx* E, int nfreq, int n, int center, double sgn){
  int idx = blockIdx.x*blockDim.x + threadIdx.x;
  if(idx >= nfreq*n) return;
  int p = idx / n, a = idx % n;
  double ang = sgn * 2.0*PI_D * (double)(p-center) * (double)a / (double)n;
  E[idx] = make_float2((float)cos(ang), (float)sin(ang));
}

// Wigner-d, n=0 column only: out[j][l][m] (W-wide, centered)
__global__ void k_wigner_col0(const double* __restrict__ lf, float* __restrict__ out,
                              int nb, int Lmax, int W, int mode, int bq){
  int idx = blockIdx.x*blockDim.x + threadIdx.x;
  int total = nb*Lmax*W;
  if(idx >= total) return;
  int m = idx % W;
  int l = (idx/W) % Lmax;
  int j = idx/(W*Lmax);
  int cw = (W-1)/2;
  int mh = m - cw;
  float r = 0.f;
  if(iabs_(mh) <= l){
    double beta = (mode==0) ? PI_D*(2*j+1)/(4.0*bq) : PI_D*(j+1)/16.0;
    double cb = cos(0.5*beta), sb = sin(0.5*beta);
    double lcb = log(cb), lsb = log(sb);
    int k0 = (mh < 0) ? -mh : 0;
    int k1 = (mh > 0) ? (l - mh) : l;
    double s = 0.0;
    for(int k = k0; k <= k1; ++k){
      double logc = 0.5*(lf[l+mh] + lf[l-mh] + 2.0*lf[l])
                    - lf[l-k] - lf[k] - lf[mh+k] - lf[l-mh-k];
      double term = exp(logc + (double)(2*l - mh - 2*k)*lcb + (double)(mh + 2*k)*lsb);
      s += ((mh + k) & 1) ? -term : term;
    }
    r = (float)s;
  }
  out[idx] = r;
}

// Full Wigner-d: out[j][l][p][q] (W x W, centered, zero-padded)
__global__ void k_wigner_full(const double* __restrict__ lf, float* __restrict__ out,
                              int nb, int L, int W, int mode, int bq){
  int idx = blockIdx.x*blockDim.x + threadIdx.x;
  int total = nb*L*W*W;
  if(idx >= total) return;
  int q = idx % W;
  int p = (idx/W) % W;
  int l = (idx/(W*W)) % L;
  int j = idx/(W*W*L);
  int cw = (W-1)/2;
  int mh = p - cw, nh = q - cw;
  float r = 0.f;
  if(iabs_(mh) <= l && iabs_(nh) <= l){
    double beta = (mode==0) ? PI_D*(2*j+1)/(4.0*bq) : PI_D*(j+1)/16.0;
    double cb = cos(0.5*beta), sb = sin(0.5*beta);
    double lcb = log(cb), lsb = log(sb);
    int k0 = (nh - mh > 0) ? (nh - mh) : 0;
    int a1 = l + nh, b1 = l - mh;
    int k1 = (a1 < b1) ? a1 : b1;
    double s = 0.0;
    for(int k = k0; k <= k1; ++k){
      double logc = 0.5*(lf[l+mh] + lf[l-mh] + lf[l+nh] + lf[l-nh])
                    - lf[l+nh-k] - lf[k] - lf[mh-nh+k] - lf[l-mh-k];
      double term = exp(logc + (double)(2*l + nh - mh - 2*k)*lcb + (double)(mh - nh + 2*k)*lsb);
      s += ((mh - nh + k) & 1) ? -term : term;
    }
    r = (float)s;
  }
  out[idx] = r;
}

// ======================= layer-0 (S2) kernels =======================
__global__ void k_fft0(const float* __restrict__ x, cplx* __restrict__ xf, const cplx* __restrict__ E0f){
  int idx = blockIdx.x*blockDim.x + threadIdx.x;
  if(idx >= 1536*31) return;
  int m = idx % 31;
  int r = idx / 31;
  const float* xr = x + (size_t)r*64;
  float sr = 0.f, si = 0.f;
  for(int a = 0; a < 64; ++a){
    cplx e = E0f[m*64 + a];
    float v = xr[a];
    sr += v*e.x; si += v*e.y;
  }
  xf[idx] = make_float2(sr*(1.f/64.f), si*(1.f/64.f));
}

__global__ void k_what0(const float* __restrict__ w0, const cplx* __restrict__ E0f, cplx* __restrict__ what0){
  int idx = blockIdx.x*blockDim.x + threadIdx.x;
  if(idx >= 96*2*31) return;
  int m = idx % 31;
  int bi = (idx/31) & 1;
  int oi = idx/62;
  const float* wr = w0 + (size_t)oi*128 + bi*64;
  float sr = 0.f, si = 0.f;
  for(int a = 0; a < 64; ++a){
    cplx e = E0f[m*64 + a];
    float v = wr[a];
    sr += v*e.x; si += v*e.y;
  }
  what0[idx] = make_float2(sr, si);
}

__global__ void k_X0(const cplx* __restrict__ xf, const float* __restrict__ d032,
                     const double* __restrict__ wq32, cplx* __restrict__ X0){
  int idx = blockIdx.x*blockDim.x + threadIdx.x;
  if(idx >= 24*16*31) return;
  int m = idx % 31;
  int l = (idx/31) % 16;
  int ci = idx/(31*16);
  float sx = 0.f, sy = 0.f;
  if(iabs_(m-15) <= l){
    for(int j = 0; j < 64; ++j){
      float d = d032[((size_t)j*16 + l)*31 + m] * (float)wq32[j];
      cplx v = xf[((size_t)ci*64 + j)*31 + m];
      sx += d*v.x; sy += d*v.y;
    }
  }
  X0[idx] = make_float2(sx, sy);
}

__global__ void k_Psi0(const cplx* __restrict__ what0, const float* __restrict__ dg32, cplx* __restrict__ Psi0){
  int idx = blockIdx.x*blockDim.x + threadIdx.x;
  if(idx >= 96*16*31) return;
  int m = idx % 31;
  int l = (idx/31) % 16;
  int oi = idx/(31*16);
  float sx = 0.f, sy = 0.f;
  if(iabs_(m-15) <= l){
    for(int bi = 0; bi < 2; ++bi){
      float d = dg32[((size_t)bi*16 + l)*31 + m];
      cplx v = what0[((size_t)oi*2 + bi)*31 + m];
      sx += d*v.x; sy += d*v.y;
    }
  }
  Psi0[idx] = make_float2(sx, sy);
}

__global__ void k_Z0(const cplx* __restrict__ X0, const cplx* __restrict__ Psi0, cplx* __restrict__ Z){
  int idx = blockIdx.x*blockDim.x + threadIdx.x;
  if(idx >= 8*32*16*961) return;
  int q = idx % 31;
  int p = (idx/31) % 31;
  int l = (idx/961) % 16;
  int o = (idx/(961*16)) % 32;
  int c = idx/(961*16*32);
  float sx = 0.f, sy = 0.f;
  if(iabs_(p-15) <= l && iabs_(q-15) <= l){
    for(int i = 0; i < 3; ++i){
      cplx a = X0[(((size_t)c*3 + i)*16 + l)*31 + p];
      cplx b = Psi0[(((size_t)o*3 + i)*16 + l)*31 + q];
      sx += a.x*b.x + a.y*b.y;
      sy += a.y*b.x - a.x*b.y;
    }
  }
  Z[idx] = make_float2(sx, sy);
}

// ======================= generic SO3 kernels =======================
__global__ void k_ifft(const cplx* __restrict__ Zt, const float* __restrict__ Wst,
                       const cplx* __restrict__ E, float* __restrict__ out,
                       int b, int C, int O){
  int M = 2*b-1, n2 = 2*b, cw = b-1;
  extern __shared__ char smem[];
  cplx* gt = (cplx*)smem;          // M*M
  cplx* Tt = gt + M*M;             // n2*M
  int blk = blockIdx.x;
  int j = blk % n2;
  int co = blk / n2;
  const cplx* Zp = Zt + (size_t)co * b * M * M;
  for(int t = threadIdx.x; t < M*M; t += blockDim.x){
    int p = t / M, q = t % M;
    int lmin = iabs_(p-cw); int l2 = iabs_(q-cw); if(l2 > lmin) lmin = l2;
    float sx = 0.f, sy = 0.f;
    for(int l = lmin; l < b; ++l){
      float w = Wst[(((size_t)j*b + l)*M + p)*M + q] * (float)(2*l+1);
      cplx z = Zp[((size_t)l*M + p)*M + q];
      sx += w*z.x; sy += w*z.y;
    }
    gt[t] = make_float2(sx, sy);
  }
  __syncthreads();
  for(int t = threadIdx.x; t < n2*M; t += blockDim.x){
    int a = t / M, q = t % M;
    float sx = 0.f, sy = 0.f;
    for(int p = 0; p < M; ++p){
      cplx e = E[p*n2 + a];
      cplx g = gt[p*M + q];
      sx += g.x*e.x - g.y*e.y;
      sy += g.x*e.y + g.y*e.x;
    }
    Tt[t] = make_float2(sx, sy);
  }
  __syncthreads();
  float* op = out + (size_t)co*n2*n2*n2 + (size_t)j*n2*n2;
  for(int t = threadIdx.x; t < n2*n2; t += blockDim.x){
    int a = t / n2, g = t % n2;
    float s = 0.f;
    for(int q = 0; q < M; ++q){
      cplx e = E[q*n2 + g];
      cplx T = Tt[a*M + q];
      s += T.x*e.x - T.y*e.y;   // real part only
    }
    op[t] = s;
  }
}

__global__ void k_fft2(const float* __restrict__ f, cplx* __restrict__ hf,
                       const cplx* __restrict__ E, int b, int Mt, int CI){
  int M = 2*b-1, n2 = 2*b;
  int off = (M - Mt)/2;
  extern __shared__ char smem[];
  float* ft = (float*)smem;                                // n2*n2
  cplx* Ft = (cplx*)(smem + sizeof(float)*n2*n2);          // n2*Mt
  int blk = blockIdx.x;
  int j = blk % n2, ci = blk / n2;
  const float* fp = f + ((size_t)ci*n2 + j)*n2*n2;
  for(int t = threadIdx.x; t < n2*n2; t += blockDim.x) ft[t] = fp[t];
  __syncthreads();
  for(int t = threadIdx.x; t < n2*Mt; t += blockDim.x){
    int a = t / Mt, q = t % Mt;
    float sr = 0.f, si = 0.f;
    for(int g = 0; g < n2; ++g){
      cplx e = E[(q+off)*n2 + g];     // use conj(e)
      float v = ft[a*n2 + g];
      sr += v*e.x; si -= v*e.y;
    }
    Ft[t] = make_float2(sr, si);
  }
  __syncthreads();
  float inv = 1.0f / ((float)n2*(float)n2);
  cplx* hp = hf + ((size_t)ci*n2 + j)*Mt*Mt;
  for(int t = threadIdx.x; t < Mt*Mt; t += blockDim.x){
    int p = t / Mt, q = t % Mt;
    float sx = 0.f, sy = 0.f;
    for(int a = 0; a < n2; ++a){
      cplx e = E[(p+off)*n2 + a];     // conj
      cplx F = Ft[a*Mt + q];
      sx += F.x*e.x + F.y*e.y;
      sy += F.y*e.x - F.x*e.y;
    }
    hp[t] = make_float2(sx*inv, sy*inv);
  }
}

__global__ void k_Xstep(const cplx* __restrict__ hf, const float* __restrict__ Wst,
                        const double* __restrict__ wqp, cplx* __restrict__ X,
                        int b, int Lout, int Mt, int CI){
  int M = 2*b-1, n2 = 2*b;
  int off = (M - Mt)/2, cw = (Mt-1)/2;
  int total = CI*Lout*Mt*Mt;
  int idx = blockIdx.x*blockDim.x + threadIdx.x;
  if(idx >= total) return;
  int q = idx % Mt;
  int p = (idx/Mt) % Mt;
  int l = (idx/(Mt*Mt)) % Lout;
  int ci = idx/(Mt*Mt*Lout);
  float sx = 0.f, sy = 0.f;
  if(iabs_(p-cw) <= l && iabs_(q-cw) <= l){
    for(int j = 0; j < n2; ++j){
      float w = Wst[(((size_t)j*b + l)*M + p + off)*M + q + off] * (float)wqp[j];
      cplx v = hf[(((size_t)ci*n2 + j)*Mt + p)*Mt + q];
      sx += w*v.x; sy += w*v.y;
    }
  }
  X[idx] = make_float2(sx, sy);
}

__global__ void k_what(const float* __restrict__ w, cplx* __restrict__ what,
                       const cplx* __restrict__ E, int n2, int Mt, int off, int OI){
  int total = OI*2*Mt;
  int idx = blockIdx.x*blockDim.x + threadIdx.x;
  if(idx >= total) return;
  int p = idx % Mt;
  int bi = (idx/Mt) & 1;
  int oi = idx/(2*Mt);
  const float* wr = w + (size_t)oi*4*n2 + (size_t)bi*2*n2;
  float sr = 0.f, si = 0.f;
  for(int a = 0; a < n2; ++a){
    float v = wr[2*a] + wr[2*a+1];
    cplx e = E[(p+off)*n2 + a];     // conj
    sr += v*e.x; si -= v*e.y;
  }
  what[idx] = make_float2(sr, si);
}

// ---- factorized spectral conv ----
// Y[ci,l,pp,bi,qq] = sum_k X[ci,l,pp+l0,k+l0] * Dg[bi,l,qq+l0d,k+l0d]
// compact per-l storage; prefix S(l) = l(2l-1)(2l+1)/3
__global__ void k_ystep(const cplx* __restrict__ X, const float* __restrict__ Dg,
                        cplx* __restrict__ Y, int CI, int Wt, int Wd, int Lx, int Ld){
  int l = blockIdx.z;
  int K21 = 2*l+1;
  int cw = (Wt-1)/2, cwd = (Wd-1)/2;
  int l0 = cw - l, l0d = cwd - l;
  int tot = CI*2*K21*K21;
  int idx = blockIdx.x*blockDim.x + threadIdx.x;
  if(idx >= tot) return;
  int qq = idx % K21;
  int bi = (idx/K21) & 1;
  int rest = idx/(2*K21);
  int pp = rest % K21;
  int ci = rest / K21;
  size_t yoff = (size_t)CI*2*((size_t)l*(2*l-1)*(2*l+1)/3);
  const cplx* xp = X + (((size_t)ci*Lx + l)*Wt + (pp+l0))*Wt + l0;
  const float* dp = Dg + (((size_t)bi*Ld + l)*Wd + (qq+l0d))*Wd + l0d;
  float sx = 0.f, sy = 0.f;
  for(int k = 0; k < K21; ++k){
    float d = dp[k];
    cplx v = xp[k];
    sx += d*v.x; sy += d*v.y;
  }
  Y[yoff + (((size_t)ci*K21 + pp)*2 + bi)*K21 + qq] = make_float2(sx, sy);
}

// Z[c,o,l,p,q] = sum_{i,bi} Y[c*I+i,l,pp,bi,qq] * conj(what[(o*I+i)*2+bi, q])
// each thread computes No outputs o = og*No + t; pads written as zeros.
__global__ void k_zstep(const cplx* __restrict__ Y, const cplx* __restrict__ what,
                        cplx* __restrict__ Z, int C, int O, int I, int Wt, int No){
  int l = blockIdx.z;
  int Lz = gridDim.z;
  int K21 = 2*l+1;
  int cw = (Wt-1)/2;
  int l0 = cw - l;
  int Og = O/No;
  int tot = C*Og*Wt*Wt;
  int idx = blockIdx.x*blockDim.x + threadIdx.x;
  if(idx >= tot) return;
  int q = idx % Wt;
  int p = (idx/Wt) % Wt;
  int og = (idx/(Wt*Wt)) % Og;
  int c = idx/(Wt*Wt*Og);
  bool valid = (iabs_(p-cw) <= l) && (iabs_(q-cw) <= l);
  if(!valid){
    for(int t = 0; t < No; ++t){
      int o = og*No + t;
      Z[((((size_t)c*O + o)*Lz + l)*Wt + p)*Wt + q] = make_float2(0.f, 0.f);
    }
    return;
  }
  int pp = p - l0, qq = q - l0;
  size_t yoff = (size_t)C*I*2*((size_t)l*(2*l-1)*(2*l+1)/3);
  const cplx* yrow = Y + yoff + (((size_t)(c*I)*K21 + pp)*2)*K21 + qq;
  size_t ystride = (size_t)K21*2*K21;   // per-i
  const cplx* wp = what + q;
  float ax[8], ay[8];
  for(int t = 0; t < No; ++t){ ax[t] = 0.f; ay[t] = 0.f; }
  for(int i = 0; i < I; ++i){
    cplx y0 = yrow[(size_t)i*ystride];
    cplx y1 = yrow[(size_t)i*ystride + K21];
    int wb = ((og*No)*I + i)*2*Wt;
    int ws = I*2*Wt;   // per-t (o) stride
    for(int t = 0; t < No; ++t){
      cplx w0 = wp[wb + t*ws];
      cplx w1 = wp[wb + t*ws + Wt];
      ax[t] += y0.x*w0.x + y0.y*w0.y + y1.x*w1.x + y1.y*w1.y;
      ay[t] += y0.y*w0.x - y0.x*w0.y + y1.y*w1.x - y1.x*w1.y;
    }
  }
  for(int t = 0; t < No; ++t){
    int o = og*No + t;
    Z[((((size_t)c*O + o)*Lz + l)*Wt + p)*Wt + q] = make_float2(ax[t], ay[t]);
  }
}

// Identity-grid conv: Z[c,o,l,p,q] = sum_i X[c,i,l,p,q] * w[o,i]
__global__ void k_zid(const cplx* __restrict__ X, const float* __restrict__ w,
                      cplx* __restrict__ Z, int C, int O, int I, int Lz, int Wt, int Wx, int Lx){
  int total = C*O*Lz*Wt*Wt;
  int idx = blockIdx.x*blockDim.x + threadIdx.x;
  if(idx >= total) return;
  int q = idx % Wt;
  int p = (idx/Wt) % Wt;
  int l = (idx/(Wt*Wt)) % Lz;
  int o = (idx/(Wt*Wt*Lz)) % O;
  int c = idx/(Wt*Wt*Lz*O);
  int cw = (Wt-1)/2, offx = (Wx-Wt)/2;
  float sx = 0.f, sy = 0.f;
  if(iabs_(p-cw) <= l && iabs_(q-cw) <= l){
    for(int i = 0; i < I; ++i){
      cplx v = X[((((size_t)c*I + i)*Lx + l)*Wx + p + offx)*Wx + q + offx];
      float wv = w[o*I + i];
      sx += wv*v.x; sy += wv*v.y;
    }
  }
  Z[idx] = make_float2(sx, sy);
}

// ======================= norm / misc =======================
__global__ void k_gn(const float* __restrict__ x, const float* __restrict__ gam,
                     const float* __restrict__ bet, float* __restrict__ y,
                     int Cch, int G, int S, int relu){
  int n = blockIdx.x / G, g = blockIdx.x % G;
  int cpg = Cch / G;
  size_t base = ((size_t)n*Cch + (size_t)g*cpg)*S;
  int cnt = cpg*S;
  double s = 0.0, sq = 0.0;
  for(int t = threadIdx.x; t < cnt; t += blockDim.x){
    float v = x[base + t]; s += v; sq += (double)v*v;
  }
  __shared__ double rs[256], rq[256];
  int tid = threadIdx.x;
  rs[tid] = s; rq[tid] = sq;
  __syncthreads();
  for(int o = 128; o > 0; o >>= 1){
    if(tid < o){ rs[tid] += rs[tid+o]; rq[tid] += rq[tid+o]; }
    __syncthreads();
  }
  __shared__ float mu_s, inv_s;
  if(tid == 0){
    double m = rs[0]/cnt;
    double var = rq[0]/cnt - m*m;
    mu_s = (float)m;
    inv_s = (float)(1.0/sqrt(var + 1e-5));
  }
  __syncthreads();
  float mu = mu_s, inv = inv_s;
  for(int t = threadIdx.x; t < cnt; t += blockDim.x){
    int c = g*cpg + t/S;
    float v = (x[base+t]-mu)*inv*gam[c] + bet[c];
    y[base+t] = relu ? fmaxf(v, 0.f) : v;
  }
}

__global__ void k_bn(const float* __restrict__ x, const float* __restrict__ gam,
                     const float* __restrict__ bet, float* __restrict__ y,
                     int N, int Cch, int S){
  int c = blockIdx.x;
  int cnt = N*S;
  double s = 0.0, sq = 0.0;
  for(int t = threadIdx.x; t < cnt; t += blockDim.x){
    int n = t / S, sp = t % S;
    float v = x[((size_t)n*Cch + c)*S + sp];
    s += v; sq += (double)v*v;
  }
  __shared__ double rs[256], rq[256];
  int tid = threadIdx.x;
  rs[tid] = s; rq[tid] = sq;
  __syncthreads();
  for(int o = 128; o > 0; o >>= 1){
    if(tid < o){ rs[tid] += rs[tid+o]; rq[tid] += rq[tid+o]; }
    __syncthreads();
  }
  __shared__ float mu_s, inv_s;
  if(tid == 0){
    double m = rs[0]/cnt;
    double var = rq[0]/cnt - m*m;
    mu_s = (float)m;
    inv_s = (float)(1.0/sqrt(var + 1e-5));
  }
  __syncthreads();
  float mu = mu_s, inv = inv_s;
  float ga = gam[c], be = bet[c];
  for(int t = threadIdx.x; t < cnt; t += blockDim.x){
    int n = t / S, sp = t % S;
    size_t id = ((size_t)n*Cch + c)*S + sp;
    y[id] = (x[id]-mu)*inv*ga + be;
  }
}

__global__ void k_addrelu(const float* __restrict__ a, const float* __restrict__ b,
                          float* __restrict__ y, int n){
  int i = blockIdx.x*blockDim.x + threadIdx.x;
  if(i < n) y[i] = fmaxf(a[i] + b[i], 0.f);
}

__global__ void k_integrate(const float* __restrict__ h, const double* __restrict__ wq4,
                            float* __restrict__ out){
  int nc = blockIdx.x;   // n*128 + c
  const float* hp = h + (size_t)nc*512;
  float s = 0.f;
  for(int t = threadIdx.x; t < 512; t += 64){
    int j = t >> 6;
    s += hp[t] * (float)wq4[j];
  }
  for(int o = 32; o > 0; o >>= 1) s += __shfl_down(s, o);
  if(threadIdx.x == 0) out[nc] = s * (1.f/64.f);
}

// ======================= launch =======================
extern "C" void kernel_launch(void* const* d_in, const int* in_sizes, int n_in,
                              void* d_out, int out_size, void* d_ws, size_t ws_size,
                              hipStream_t stream){
  const float* xin = (const float*)d_in[0];
  const float* w0p = (const float*)d_in[1];
  const float* g0p = (const float*)d_in[2];
  const float* b0p = (const float*)d_in[3];
  const float* w1ap = (const float*)d_in[4];
  const float* g1ap = (const float*)d_in[5];
  const float* b1ap = (const float*)d_in[6];
  const float* w1bp = (const float*)d_in[7];
  const float* g1bp = (const float*)d_in[8];
  const float* b1bp = (const float*)d_in[9];
  const float* w1sp = (const float*)d_in[10];
  const float* g1sp = (const float*)d_in[11];
  const float* b1sp = (const float*)d_in[12];
  const float* w2ap = (const float*)d_in[13];
  const float* g2ap = (const float*)d_in[14];
  const float* b2ap = (const float*)d_in[15];
  const float* w2bp = (const float*)d_in[16];
  const float* g2bp = (const float*)d_in[17];
  const float* b2bp = (const float*)d_in[18];
  const float* w2sp = (const float*)d_in[19];
  const float* g2sp = (const float*)d_in[20];
  const float* b2sp = (const float*)d_in[21];
  float* outp = (float*)d_out;

  char* ws = (char*)d_ws;
  size_t off = 0;
  auto alloc = [&](size_t bytes)->char*{
    char* p = ws + off;
    off = (off + bytes + 255) & ~(size_t)255;
    return p;
  };
  // tables (persistent)
  double* lf   = (double*)alloc(130*8);
  double* wq   = (double*)alloc(120*8);      // [0:64) b32, [64:96) b16, [96:112) b8, [112:120) b4
  cplx* E16    = (cplx*)alloc(31*32*8);
  cplx* E8     = (cplx*)alloc(15*16*8);
  cplx* E4     = (cplx*)alloc(7*8*8);
  cplx* E0f    = (cplx*)alloc(31*64*8);
  float* d032  = (float*)alloc((size_t)64*16*31*4);
  float* dg32  = (float*)alloc((size_t)2*16*31*4);
  float* W16   = (float*)alloc((size_t)32*16*961*4);
  float* Dg16  = (float*)alloc((size_t)2*16*961*4);
  float* W8    = (float*)alloc((size_t)16*8*225*4);
  float* Dg8   = (float*)alloc((size_t)2*8*225*4);
  float* W4    = (float*)alloc((size_t)8*4*49*4);
  // arenas (explicit reuse; liveness verified per stage)
  char* A_ZHF = alloc((size_t)63*1024*1024);   // Z / hf alternate here (never live together)
  char* A_X   = alloc((size_t)32*1024*1024);   // X1 then X2 (live across shortcut convs)
  char* A_H1  = alloc((size_t)34*1024*1024);
  char* A_H2  = alloc((size_t)34*1024*1024);
  char* A_S   = alloc((size_t)8*1024*1024);    // small per-phase scratch

  // phase aliases
  cplx* xf0    = (cplx*)(A_S);
  cplx* X0     = (cplx*)(A_S + (512<<10));
  cplx* what0  = (cplx*)(A_S + (768<<10));
  cplx* Psi0   = (cplx*)(A_S + (1<<20));
  cplx* Zt0    = (cplx*)A_ZHF;
  float* h0    = (float*)A_H1;
  float* h0n   = (float*)A_H2;
  cplx* hf1    = (cplx*)A_ZHF;
  cplx* X1     = (cplx*)A_X;
  cplx* what1a = (cplx*)A_S;
  cplx* Y1a    = (cplx*)A_H1;       // 22.3 MB; h0 dead after gn
  cplx* Z1a    = (cplx*)A_ZHF;      // hf1 dead after Xstep
  float* left1 = (float*)A_H1;      // Y1a dead after zstep
  float* left1n= (float*)A_H2;
  cplx* hf1b   = (cplx*)A_ZHF;
  cplx* X1b    = (cplx*)A_S;
  cplx* what1b = (cplx*)(A_S + (4<<20));
  cplx* Y1b    = (cplx*)A_H2;       // 2.8 MB; left1n dead after fft2
  cplx* Z1b    = (cplx*)A_ZHF;
  float* left2 = (float*)A_H1;
  float* left2n= (float*)(A_H1 + (16<<20));
  cplx* Z1s    = (cplx*)A_ZHF;
  float* sc1   = (float*)A_H2;      // Y1b dead
  float* sc1n  = (float*)(A_H2 + (16<<20));
  float* h1    = (float*)A_H1;
  cplx* hf2    = (cplx*)A_ZHF;
  cplx* X2     = (cplx*)A_X;
  cplx* what2a = (cplx*)A_S;
  cplx* Y2a    = (cplx*)A_H1;       // 5.6 MB; h1 dead after fft2
  cplx* Z2a    = (cplx*)A_ZHF;
  float* left3 = (float*)A_H2;
  float* left3n= (float*)(A_H2 + (16<<20));
  cplx* hf2b   = (cplx*)A_ZHF;
  cplx* X2b    = (cplx*)A_S;
  cplx* what2b = (cplx*)(A_S + (1<<20));
  cplx* Y2b    = (cplx*)(A_S + (2<<20));  // 688 KB
  cplx* Z2b    = (cplx*)A_ZHF;
  float* left4 = (float*)A_H1;
  float* left4n= (float*)(A_H1 + (4<<20));
  cplx* Z2s    = (cplx*)A_ZHF;
  float* sc2   = (float*)A_H2;
  float* sc2n  = (float*)(A_H2 + (4<<20));
  float* h2    = (float*)(A_H1 + (8<<20));

  // ---- tables ----
  k_tables<<<1,256,0,stream>>>(lf, wq);
  k_twiddle<<<(31*32+255)/256,256,0,stream>>>(E16, 31, 32, 15,  1.0);
  k_twiddle<<<1,256,0,stream>>>(E8, 15, 16, 7,  1.0);
  k_twiddle<<<1,64,0,stream>>>(E4, 7, 8, 3,  1.0);
  k_twiddle<<<(31*64+255)/256,256,0,stream>>>(E0f, 31, 64, 15, -1.0);
  k_wigner_col0<<<(64*16*31+255)/256,256,0,stream>>>(lf, d032, 64, 16, 31, 0, 32);
  k_wigner_col0<<<(2*16*31+255)/256,256,0,stream>>>(lf, dg32, 2, 16, 31, 1, 0);
  k_wigner_full<<<(32*16*961+255)/256,256,0,stream>>>(lf, W16, 32, 16, 31, 0, 16);
  k_wigner_full<<<(2*16*961+255)/256,256,0,stream>>>(lf, Dg16, 2, 16, 31, 1, 0);
  k_wigner_full<<<(16*8*225+255)/256,256,0,stream>>>(lf, W8, 16, 8, 15, 0, 8);
  k_wigner_full<<<(2*8*225+255)/256,256,0,stream>>>(lf, Dg8, 2, 8, 15, 1, 0);
  k_wigner_full<<<(8*4*49+255)/256,256,0,stream>>>(lf, W4, 8, 4, 7, 0, 4);

  // ---- layer 0: s2_conv(x, w0, 32, 16) + GN + ReLU ----
  k_fft0<<<(1536*31+255)/256,256,0,stream>>>(xin, xf0, E0f);
  k_what0<<<(96*2*31+255)/256,256,0,stream>>>(w0p, E0f, what0);
  k_X0<<<(24*16*31+255)/256,256,0,stream>>>(xf0, d032, wq, X0);
  k_Psi0<<<(96*16*31+255)/256,256,0,stream>>>(what0, dg32, Psi0);
  k_Z0<<<(8*32*16*961+255)/256,256,0,stream>>>(X0, Psi0, Zt0);
  k_ifft<<<8*32*32,256,(961+992)*8,stream>>>(Zt0, W16, E16, h0, 16, 8, 32);
  k_gn<<<8*16,256,0,stream>>>(h0, g0p, b0p, h0n, 32, 16, 32768, 1);

  // ---- layer 1a: so3_conv(h, w1a, 16, 16) + GN ----
  k_fft2<<<256*32,256,4096+32*31*8,stream>>>(h0n, hf1, E16, 16, 31, 256);
  k_Xstep<<<(256*16*961+255)/256,256,0,stream>>>(hf1, W16, wq+64, X1, 16, 16, 31, 256);
  k_what<<<(1024*2*31+255)/256,256,0,stream>>>(w1ap, what1a, E16, 32, 31, 0, 1024);
  { dim3 g((256*2*961+255)/256,1,16);
    k_ystep<<<g,256,0,stream>>>(X1, Dg16, Y1a, 256, 31, 31, 16, 16); }
  { dim3 g((8*8*961+255)/256,1,16);
    k_zstep<<<g,256,0,stream>>>(Y1a, what1a, Z1a, 8, 32, 32, 31, 4); }
  k_ifft<<<8*32*32,256,(961+992)*8,stream>>>(Z1a, W16, E16, left1, 16, 8, 32);
  k_gn<<<8*16,256,0,stream>>>(left1, g1ap, b1ap, left1n, 32, 16, 32768, 0);

  // ---- layer 1b: so3_conv(left, w1b, 16, 8) + GN + ReLU ----
  k_fft2<<<256*32,256,4096+32*15*8,stream>>>(left1n, hf1b, E16, 16, 15, 256);
  k_Xstep<<<(256*8*225+255)/256,256,0,stream>>>(hf1b, W16, wq+64, X1b, 16, 8, 15, 256);
  k_what<<<(2048*2*15+255)/256,256,0,stream>>>(w1bp, what1b, E16, 32, 15, 8, 2048);
  { dim3 g((256*2*225+255)/256,1,8);
    k_ystep<<<g,256,0,stream>>>(X1b, Dg16, Y1b, 256, 15, 31, 8, 16); }
  { dim3 g((8*16*225+255)/256,1,8);
    k_zstep<<<g,256,0,stream>>>(Y1b, what1b, Z1b, 8, 64, 32, 15, 4); }
  k_ifft<<<8*64*16,256,(225+240)*8,stream>>>(Z1b, W8, E8, left2, 8, 8, 64);
  k_gn<<<8*16,256,0,stream>>>(left2, g1bp, b1bp, left2n, 64, 16, 4096, 1);

  // ---- layer 1s: so3_conv(h, w1s, 16, 8, ID) + BN ; residual add ----
  k_zid<<<(8*64*8*225+255)/256,256,0,stream>>>(X1, w1sp, Z1s, 8, 64, 32, 8, 15, 31, 16);
  k_ifft<<<8*64*16,256,(225+240)*8,stream>>>(Z1s, W8, E8, sc1, 8, 8, 64);
  k_bn<<<64,256,0,stream>>>(sc1, g1sp, b1sp, sc1n, 8, 64, 4096);
  k_addrelu<<<(2097152+255)/256,256,0,stream>>>(left2n, sc1n, h1, 2097152);

  // ---- layer 2a: so3_conv(h, w2a, 8, 8) + GN ----
  k_fft2<<<512*16,256,1024+16*15*8,stream>>>(h1, hf2, E8, 8, 15, 512);
  k_Xstep<<<(512*8*225+255)/256,256,0,stream>>>(hf2, W8, wq+96, X2, 8, 8, 15, 512);
  k_what<<<(4096*2*15+255)/256,256,0,stream>>>(w2ap, what2a, E8, 16, 15, 0, 4096);
  { dim3 g((512*2*225+255)/256,1,8);
    k_ystep<<<g,256,0,stream>>>(X2, Dg8, Y2a, 512, 15, 15, 8, 8); }
  { dim3 g((8*16*225+255)/256,1,8);
    k_zstep<<<g,256,0,stream>>>(Y2a, what2a, Z2a, 8, 64, 64, 15, 4); }
  k_ifft<<<8*64*16,256,(225+240)*8,stream>>>(Z2a, W8, E8, left3, 8, 8, 64);
  k_gn<<<8*16,256,0,stream>>>(left3, g2ap, b2ap, left3n, 64, 16, 4096, 0);

  // ---- layer 2b: so3_conv(left, w2b, 8, 4) + GN + ReLU ----
  k_fft2<<<512*16,256,1024+16*7*8,stream>>>(left3n, hf2b, E8, 8, 7, 512);
  k_Xstep<<<(512*4*49+255)/256,256,0,stream>>>(hf2b, W8, wq+96, X2b, 8, 4, 7, 512);
  k_what<<<(8192*2*7+255)/256,256,0,stream>>>(w2bp, what2b, E8, 16, 7, 4, 8192);
  { dim3 g((512*2*49+255)/256,1,4);
    k_ystep<<<g,256,0,stream>>>(X2b, Dg8, Y2b, 512, 7, 15, 4, 8); }
  { dim3 g((8*32*49+255)/256,1,4);
    k_zstep<<<g,256,0,stream>>>(Y2b, what2b, Z2b, 8, 128, 64, 7, 4); }
  k_ifft<<<8*128*8,64,(49+56)*8,stream>>>(Z2b, W4, E4, left4, 4, 8, 128);
  k_gn<<<8*32,256,0,stream>>>(left4, g2bp, b2bp, left4n, 128, 32, 512, 1);

  // ---- layer 2s: so3_conv(h, w2s, 8, 4, ID) + BN ; residual add ----
  k_zid<<<(8*128*4*49+255)/256,256,0,stream>>>(X2, w2sp, Z2s, 8, 128, 64, 4, 7, 15, 8);
  k_ifft<<<8*128*8,64,(49+56)*8,stream>>>(Z2s, W4, E4, sc2, 4, 8, 128);
  k_bn<<<128,256,0,stream>>>(sc2, g2sp, b2sp, sc2n, 8, 128, 512);
  k_addrelu<<<(524288+255)/256,256,0,stream>>>(left4n, sc2n, h2, 524288);

  // ---- integrate ----
  k_integrate<<<1024,64,0,stream>>>(h2, wq+112, outp);
}

// Round 4
// 2262.503 us; speedup vs baseline: 1.5344x; 1.1850x over previous
//
#include <hip/hip_runtime.h>
#include <math.h>

typedef float2 cplx;
#define PI_D 3.14159265358979323846

__device__ __forceinline__ int iabs_(int v){ return v < 0 ? -v : v; }

// ======================= table kernels =======================
__global__ void k_tables(double* lf, double* wq){
  if(threadIdx.x == 0){
    lf[0] = 0.0;
    double acc = 0.0;
    for(int i = 1; i <= 128; ++i){ acc += log((double)i); lf[i] = acc; }
  }
  int t = threadIdx.x;
  int b, j, off;
  if(t < 64){ b = 32; j = t; off = 0; }
  else if(t < 96){ b = 16; j = t - 64; off = 64; }
  else if(t < 112){ b = 8; j = t - 96; off = 96; }
  else if(t < 120){ b = 4; j = t - 112; off = 112; }
  else return;
  double beta = PI_D * (2*j+1) / (4.0*b);
  double s = 0.0;
  for(int p = 0; p < b; ++p) s += sin((2*p+1)*beta) / (2*p+1);
  wq[off+j] = 2.0*PI_D/((double)b*b) * sin(beta) * s;
}

__global__ void k_twiddle(cplx* E, int nfreq, int n, int center, double sgn){
  int idx = blockIdx.x*blockDim.x + threadIdx.x;
  if(idx >= nfreq*n) return;
  int p = idx / n, a = idx % n;
  double ang = sgn * 2.0*PI_D * (double)(p-center) * (double)a / (double)n;
  E[idx] = make_float2((float)cos(ang), (float)sin(ang));
}

// Wigner-d, n=0 column only; smode: 0 none, 1 *(2l+1), 2 *wqs[j]
__global__ void k_wigner_col0(const double* __restrict__ lf, float* __restrict__ out,
                              int nb, int Lmax, int W, int mode, int bq,
                              const double* __restrict__ wqs, int smode){
  int idx = blockIdx.x*blockDim.x + threadIdx.x;
  int total = nb*Lmax*W;
  if(idx >= total) return;
  int m = idx % W;
  int l = (idx/W) % Lmax;
  int j = idx/(W*Lmax);
  int cw = (W-1)/2;
  int mh = m - cw;
  float r = 0.f;
  if(iabs_(mh) <= l){
    double beta = (mode==0) ? PI_D*(2*j+1)/(4.0*bq) : PI_D*(j+1)/16.0;
    double cb = cos(0.5*beta), sb = sin(0.5*beta);
    double lcb = log(cb), lsb = log(sb);
    int k0 = (mh < 0) ? -mh : 0;
    int k1 = (mh > 0) ? (l - mh) : l;
    double s = 0.0;
    for(int k = k0; k <= k1; ++k){
      double logc = 0.5*(lf[l+mh] + lf[l-mh] + 2.0*lf[l])
                    - lf[l-k] - lf[k] - lf[mh+k] - lf[l-mh-k];
      double term = exp(logc + (double)(2*l - mh - 2*k)*lcb + (double)(mh + 2*k)*lsb);
      s += ((mh + k) & 1) ? -term : term;
    }
    if(smode == 1) s *= (double)(2*l+1);
    else if(smode == 2) s *= wqs[j];
    r = (float)s;
  }
  out[idx] = r;
}

// Full Wigner-d; smode: 0 none, 1 *(2l+1), 2 *wqs[j]
__global__ void k_wigner_full(const double* __restrict__ lf, float* __restrict__ out,
                              int nb, int L, int W, int mode, int bq,
                              const double* __restrict__ wqs, int smode){
  int idx = blockIdx.x*blockDim.x + threadIdx.x;
  int total = nb*L*W*W;
  if(idx >= total) return;
  int q = idx % W;
  int p = (idx/W) % W;
  int l = (idx/(W*W)) % L;
  int j = idx/(W*W*L);
  int cw = (W-1)/2;
  int mh = p - cw, nh = q - cw;
  float r = 0.f;
  if(iabs_(mh) <= l && iabs_(nh) <= l){
    double beta = (mode==0) ? PI_D*(2*j+1)/(4.0*bq) : PI_D*(j+1)/16.0;
    double cb = cos(0.5*beta), sb = sin(0.5*beta);
    double lcb = log(cb), lsb = log(sb);
    int k0 = (nh - mh > 0) ? (nh - mh) : 0;
    int a1 = l + nh, b1 = l - mh;
    int k1 = (a1 < b1) ? a1 : b1;
    double s = 0.0;
    for(int k = k0; k <= k1; ++k){
      double logc = 0.5*(lf[l+mh] + lf[l-mh] + lf[l+nh] + lf[l-nh])
                    - lf[l+nh-k] - lf[k] - lf[mh-nh+k] - lf[l-mh-k];
      double term = exp(logc + (double)(2*l + nh - mh - 2*k)*lcb + (double)(mh - nh + 2*k)*lsb);
      s += ((mh - nh + k) & 1) ? -term : term;
    }
    if(smode == 1) s *= (double)(2*l+1);
    else if(smode == 2) s *= wqs[j];
    r = (float)s;
  }
  out[idx] = r;
}

// ======================= layer-0 (S2) kernels =======================
__global__ void k_fft0(const float* __restrict__ x, cplx* __restrict__ xf, const cplx* __restrict__ E0f){
  int idx = blockIdx.x*blockDim.x + threadIdx.x;
  if(idx >= 1536*31) return;
  int m = idx % 31;
  int r = idx / 31;
  const float* xr = x + (size_t)r*64;
  float sr = 0.f, si = 0.f;
  for(int a = 0; a < 64; ++a){
    cplx e = E0f[m*64 + a];
    float v = xr[a];
    sr += v*e.x; si += v*e.y;
  }
  xf[idx] = make_float2(sr*(1.f/64.f), si*(1.f/64.f));
}

__global__ void k_what0(const float* __restrict__ w0, const cplx* __restrict__ E0f, cplx* __restrict__ what0){
  int idx = blockIdx.x*blockDim.x + threadIdx.x;
  if(idx >= 96*2*31) return;
  int m = idx % 31;
  int bi = (idx/31) & 1;
  int oi = idx/62;
  const float* wr = w0 + (size_t)oi*128 + bi*64;
  float sr = 0.f, si = 0.f;
  for(int a = 0; a < 64; ++a){
    cplx e = E0f[m*64 + a];
    float v = wr[a];
    sr += v*e.x; si += v*e.y;
  }
  what0[idx] = make_float2(sr, si);
}

// uses pre-scaled d032w (wq folded)
__global__ void k_X0(const cplx* __restrict__ xf, const float* __restrict__ d032w,
                     cplx* __restrict__ X0){
  int idx = blockIdx.x*blockDim.x + threadIdx.x;
  if(idx >= 24*16*31) return;
  int m = idx % 31;
  int l = (idx/31) % 16;
  int ci = idx/(31*16);
  float sx = 0.f, sy = 0.f;
  if(iabs_(m-15) <= l){
    for(int j = 0; j < 64; ++j){
      float d = d032w[((size_t)j*16 + l)*31 + m];
      cplx v = xf[((size_t)ci*64 + j)*31 + m];
      sx += d*v.x; sy += d*v.y;
    }
  }
  X0[idx] = make_float2(sx, sy);
}

__global__ void k_Psi0(const cplx* __restrict__ what0, const float* __restrict__ dg32, cplx* __restrict__ Psi0){
  int idx = blockIdx.x*blockDim.x + threadIdx.x;
  if(idx >= 96*16*31) return;
  int m = idx % 31;
  int l = (idx/31) % 16;
  int oi = idx/(31*16);
  float sx = 0.f, sy = 0.f;
  if(iabs_(m-15) <= l){
    for(int bi = 0; bi < 2; ++bi){
      float d = dg32[((size_t)bi*16 + l)*31 + m];
      cplx v = what0[((size_t)oi*2 + bi)*31 + m];
      sx += d*v.x; sy += d*v.y;
    }
  }
  Psi0[idx] = make_float2(sx, sy);
}

__global__ void k_Z0(const cplx* __restrict__ X0, const cplx* __restrict__ Psi0, cplx* __restrict__ Z){
  int idx = blockIdx.x*blockDim.x + threadIdx.x;
  if(idx >= 8*32*16*961) return;
  int q = idx % 31;
  int p = (idx/31) % 31;
  int l = (idx/961) % 16;
  int o = (idx/(961*16)) % 32;
  int c = idx/(961*16*32);
  float sx = 0.f, sy = 0.f;
  if(iabs_(p-15) <= l && iabs_(q-15) <= l){
    for(int i = 0; i < 3; ++i){
      cplx a = X0[(((size_t)c*3 + i)*16 + l)*31 + p];
      cplx b = Psi0[(((size_t)o*3 + i)*16 + l)*31 + q];
      sx += a.x*b.x + a.y*b.y;
      sy += a.y*b.x - a.x*b.y;
    }
  }
  Z[idx] = make_float2(sx, sy);
}

// ======================= tiled SO3 inverse FFT =======================
// blockDim must be n2*((M+3)/4) == n2*n2/4  (b16: 256, b8: 64)
// Wst = Wi (pre-scaled by (2l+1))
__global__ void k_ifft_t(const cplx* __restrict__ Zt, const float* __restrict__ Wst,
                         const cplx* __restrict__ E, float* __restrict__ out, int b){
  int M = 2*b-1, n2 = 2*b, Mp = n2, Mpt = n2+2, cw = b-1;
  int ng = (M+3)/4;
  extern __shared__ char smem[];
  cplx* Es = (cplx*)smem;          // M*n2
  cplx* gt = Es + M*n2;            // M*Mp
  cplx* Tt = gt + M*Mp;            // n2*Mpt
  int j = blockIdx.x % n2;
  int co = blockIdx.x / n2;
  int tid = threadIdx.x, bd = blockDim.x;
  for(int t = tid; t < M*n2; t += bd) Es[t] = E[t];
  for(int t = tid; t < M*(Mp-M); t += bd){
    int r = t/(Mp-M), c = M + t%(Mp-M);
    gt[r*Mp + c] = make_float2(0.f, 0.f);
  }
  const cplx* Zp = Zt + (size_t)co*b*M*M;
  const float* Wj = Wst + (size_t)j*b*M*M;
  for(int t = tid; t < M*M; t += bd){
    int p = t/M, q = t - p*M;
    int lmin = iabs_(p-cw); int l2 = iabs_(q-cw); if(l2 > lmin) lmin = l2;
    float sx = 0.f, sy = 0.f;
    for(int l = lmin; l < b; ++l){
      float w = Wj[((size_t)l*M + p)*M + q];
      cplx z = Zp[((size_t)l*M + p)*M + q];
      sx += w*z.x; sy += w*z.y;
    }
    gt[p*Mp + q] = make_float2(sx, sy);
  }
  __syncthreads();
  // stage 2: Tt[a][q] = sum_p Es[p][a] * gt[p][q]
  if(tid < n2*ng){
    int a = tid/ng, qg = tid - a*ng; int q0 = 4*qg;
    float ax0=0,ax1=0,ax2=0,ax3=0, ay0=0,ay1=0,ay2=0,ay3=0;
    for(int p = 0; p < M; ++p){
      cplx e = Es[p*n2 + a];
      const float4* g4 = (const float4*)(gt + p*Mp + q0);
      float4 ga = g4[0], gb = g4[1];
      ax0 += ga.x*e.x - ga.y*e.y; ay0 += ga.x*e.y + ga.y*e.x;
      ax1 += ga.z*e.x - ga.w*e.y; ay1 += ga.z*e.y + ga.w*e.x;
      ax2 += gb.x*e.x - gb.y*e.y; ay2 += gb.x*e.y + gb.y*e.x;
      ax3 += gb.z*e.x - gb.w*e.y; ay3 += gb.z*e.y + gb.w*e.x;
    }
    cplx* tp = Tt + a*Mpt + q0;
    tp[0] = make_float2(ax0,ay0); tp[1] = make_float2(ax1,ay1);
    tp[2] = make_float2(ax2,ay2); tp[3] = make_float2(ax3,ay3);
  }
  __syncthreads();
  // stage 3: out[a][g] = Re sum_q Tt[a][q] * Es[q][g]
  {
    int gc = n2/4;
    int a = tid/gc, gg = tid - a*gc; int g0 = 4*gg;
    if(a < n2){
      float s0=0,s1=0,s2=0,s3=0;
      for(int q = 0; q < M; ++q){
        cplx T = Tt[a*Mpt + q];
        const float4* e4 = (const float4*)(Es + q*n2 + g0);
        float4 ea = e4[0], eb = e4[1];
        s0 += T.x*ea.x - T.y*ea.y;
        s1 += T.x*ea.z - T.y*ea.w;
        s2 += T.x*eb.x - T.y*eb.y;
        s3 += T.x*eb.z - T.y*eb.w;
      }
      float* op = out + (size_t)co*n2*n2*n2 + (size_t)j*n2*n2 + a*n2 + g0;
      *(float4*)op = make_float4(s0,s1,s2,s3);
    }
  }
}

// small (b=4) ifft, original style, Wi pre-scaled
__global__ void k_ifft_s(const cplx* __restrict__ Zt, const float* __restrict__ Wst,
                         const cplx* __restrict__ E, float* __restrict__ out, int b){
  int M = 2*b-1, n2 = 2*b, cw = b-1;
  extern __shared__ char smem[];
  cplx* gt = (cplx*)smem;          // M*M
  cplx* Tt = gt + M*M;             // n2*M
  int blk = blockIdx.x;
  int j = blk % n2;
  int co = blk / n2;
  const cplx* Zp = Zt + (size_t)co * b * M * M;
  for(int t = threadIdx.x; t < M*M; t += blockDim.x){
    int p = t / M, q = t % M;
    int lmin = iabs_(p-cw); int l2 = iabs_(q-cw); if(l2 > lmin) lmin = l2;
    float sx = 0.f, sy = 0.f;
    for(int l = lmin; l < b; ++l){
      float w = Wst[(((size_t)j*b + l)*M + p)*M + q];
      cplx z = Zp[((size_t)l*M + p)*M + q];
      sx += w*z.x; sy += w*z.y;
    }
    gt[t] = make_float2(sx, sy);
  }
  __syncthreads();
  for(int t = threadIdx.x; t < n2*M; t += blockDim.x){
    int a = t / M, q = t % M;
    float sx = 0.f, sy = 0.f;
    for(int p = 0; p < M; ++p){
      cplx e = E[p*n2 + a];
      cplx g = gt[p*M + q];
      sx += g.x*e.x - g.y*e.y;
      sy += g.x*e.y + g.y*e.x;
    }
    Tt[t] = make_float2(sx, sy);
  }
  __syncthreads();
  float* op = out + (size_t)co*n2*n2*n2 + (size_t)j*n2*n2;
  for(int t = threadIdx.x; t < n2*n2; t += blockDim.x){
    int a = t / n2, g = t % n2;
    float s = 0.f;
    for(int q = 0; q < M; ++q){
      cplx e = E[q*n2 + g];
      cplx T = Tt[a*M + q];
      s += T.x*e.x - T.y*e.y;
    }
    op[t] = s;
  }
}

// ======================= tiled forward 2D DFT =======================
// blockDim must be n2*((Mt+3)/4)
__global__ void k_fft2_t(const float* __restrict__ f, cplx* __restrict__ hf,
                         const cplx* __restrict__ E, int b, int Mt){
  int M = 2*b-1, n2 = 2*b;
  int off = (M - Mt)/2;
  int ng = (Mt+3)/4;
  int MtP = 4*ng;
  int fs = n2+1;   // ft row stride (floats)
  int es = n2+1;   // Es row stride (cplx)
  extern __shared__ char smem[];
  float* ft = (float*)smem;                         // n2*fs
  cplx* Ft  = (cplx*)(ft + n2*fs);                  // n2*MtP
  cplx* Es  = Ft + n2*MtP;                          // Mt*es
  cplx* EsT = Es + Mt*es;                           // n2*MtP
  int j = blockIdx.x % n2, ci = blockIdx.x / n2;
  int tid = threadIdx.x, bd = blockDim.x;
  const float* fp = f + ((size_t)ci*n2 + j)*n2*n2;
  for(int t = tid; t < n2*n2; t += bd){
    int r = t/n2, g = t - r*n2;
    ft[r*fs + g] = fp[t];
  }
  for(int t = tid; t < Mt*n2; t += bd){
    int r = t/n2, a = t - r*n2;
    Es[r*es + a] = E[(r+off)*n2 + a];
  }
  for(int t = tid; t < n2*MtP; t += bd){
    int g = t/MtP, q = t - g*MtP;
    cplx v = make_float2(0.f, 0.f);
    if(q < Mt) v = E[(q+off)*n2 + g];
    EsT[t] = v;
  }
  __syncthreads();
  // stage A: Ft[a][q] = sum_g ft[a][g] * conj(E[q+off][g])
  {
    int a = tid/ng, qg = tid - a*ng; int q0 = 4*qg;
    if(a < n2){
      float ax0=0,ax1=0,ax2=0,ax3=0, ay0=0,ay1=0,ay2=0,ay3=0;
      const float* fr = ft + a*fs;
      for(int g = 0; g < n2; ++g){
        float v = fr[g];
        const float4* e4 = (const float4*)(EsT + g*MtP + q0);
        float4 ea = e4[0], eb = e4[1];
        ax0 += v*ea.x; ay0 -= v*ea.y;
        ax1 += v*ea.z; ay1 -= v*ea.w;
        ax2 += v*eb.x; ay2 -= v*eb.y;
        ax3 += v*eb.z; ay3 -= v*eb.w;
      }
      cplx* Fp = Ft + a*MtP + q0;
      Fp[0] = make_float2(ax0,ay0); Fp[1] = make_float2(ax1,ay1);
      Fp[2] = make_float2(ax2,ay2); Fp[3] = make_float2(ax3,ay3);
    }
  }
  __syncthreads();
  // stage B: hf[p][q] = (1/n2^2) sum_a conj(Es[p][a]) * Ft[a][q]
  {
    int p = tid/ng, qg = tid - p*ng; int q0 = 4*qg;
    if(p < Mt){
      float ax0=0,ax1=0,ax2=0,ax3=0, ay0=0,ay1=0,ay2=0,ay3=0;
      for(int a = 0; a < n2; ++a){
        cplx e = Es[p*es + a];
        const float4* F4 = (const float4*)(Ft + a*MtP + q0);
        float4 Fa = F4[0], Fb = F4[1];
        ax0 += e.x*Fa.x + e.y*Fa.y; ay0 += e.x*Fa.y - e.y*Fa.x;
        ax1 += e.x*Fa.z + e.y*Fa.w; ay1 += e.x*Fa.w - e.y*Fa.z;
        ax2 += e.x*Fb.x + e.y*Fb.y; ay2 += e.x*Fb.y - e.y*Fb.x;
        ax3 += e.x*Fb.z + e.y*Fb.w; ay3 += e.x*Fb.w - e.y*Fb.z;
      }
      float inv = 1.0f/((float)n2*(float)n2);
      cplx* hp = hf + ((size_t)ci*n2 + j)*Mt*Mt + p*Mt;
      if(q0   < Mt) hp[q0  ] = make_float2(ax0*inv, ay0*inv);
      if(q0+1 < Mt) hp[q0+1] = make_float2(ax1*inv, ay1*inv);
      if(q0+2 < Mt) hp[q0+2] = make_float2(ax2*inv, ay2*inv);
      if(q0+3 < Mt) hp[q0+3] = make_float2(ax3*inv, ay3*inv);
    }
  }
}

// X[ci,l,p,q] = sum_j Wx[j,l,p,q]*hf[ci,j,p,q]  (wq pre-folded into Wx)
__global__ void k_Xstep(const cplx* __restrict__ hf, const float* __restrict__ Wst,
                        cplx* __restrict__ X, int b, int Lout, int Mt, int CI){
  int M = 2*b-1, n2 = 2*b;
  int off = (M - Mt)/2, cw = (Mt-1)/2;
  int total = CI*Lout*Mt*Mt;
  int idx = blockIdx.x*blockDim.x + threadIdx.x;
  if(idx >= total) return;
  int q = idx % Mt;
  int p = (idx/Mt) % Mt;
  int l = (idx/(Mt*Mt)) % Lout;
  int ci = idx/(Mt*Mt*Lout);
  float sx = 0.f, sy = 0.f;
  if(iabs_(p-cw) <= l && iabs_(q-cw) <= l){
    for(int j = 0; j < n2; ++j){
      float w = Wst[(((size_t)j*b + l)*M + p + off)*M + q + off];
      cplx v = hf[(((size_t)ci*n2 + j)*Mt + p)*Mt + q];
      sx += w*v.x; sy += w*v.y;
    }
  }
  X[idx] = make_float2(sx, sy);
}

__global__ void k_what(const float* __restrict__ w, cplx* __restrict__ what,
                       const cplx* __restrict__ E, int n2, int Mt, int off, int OI){
  int total = OI*2*Mt;
  int idx = blockIdx.x*blockDim.x + threadIdx.x;
  if(idx >= total) return;
  int p = idx % Mt;
  int bi = (idx/Mt) & 1;
  int oi = idx/(2*Mt);
  const float* wr = w + (size_t)oi*4*n2 + (size_t)bi*2*n2;
  float sr = 0.f, si = 0.f;
  for(int a = 0; a < n2; ++a){
    float v = wr[2*a] + wr[2*a+1];
    cplx e = E[(p+off)*n2 + a];     // conj
    sr += v*e.x; si -= v*e.y;
  }
  what[idx] = make_float2(sr, si);
}

// ---- factorized spectral conv ----
__global__ void k_ystep(const cplx* __restrict__ X, const float* __restrict__ Dg,
                        cplx* __restrict__ Y, int CI, int Wt, int Wd, int Lx, int Ld){
  int l = blockIdx.z;
  int K21 = 2*l+1;
  int cw = (Wt-1)/2, cwd = (Wd-1)/2;
  int l0 = cw - l, l0d = cwd - l;
  int tot = CI*2*K21*K21;
  int idx = blockIdx.x*blockDim.x + threadIdx.x;
  if(idx >= tot) return;
  int qq = idx % K21;
  int bi = (idx/K21) & 1;
  int rest = idx/(2*K21);
  int pp = rest % K21;
  int ci = rest / K21;
  size_t yoff = (size_t)CI*2*((size_t)l*(2*l-1)*(2*l+1)/3);
  const cplx* xp = X + (((size_t)ci*Lx + l)*Wt + (pp+l0))*Wt + l0;
  const float* dp = Dg + (((size_t)bi*Ld + l)*Wd + (qq+l0d))*Wd + l0d;
  float sx = 0.f, sy = 0.f;
  for(int k = 0; k < K21; ++k){
    float d = dp[k];
    cplx v = xp[k];
    sx += d*v.x; sy += d*v.y;
  }
  Y[yoff + (((size_t)ci*K21 + pp)*2 + bi)*K21 + qq] = make_float2(sx, sy);
}

__global__ void k_zstep(const cplx* __restrict__ Y, const cplx* __restrict__ what,
                        cplx* __restrict__ Z, int C, int O, int I, int Wt, int No){
  int l = blockIdx.z;
  int Lz = gridDim.z;
  int K21 = 2*l+1;
  int cw = (Wt-1)/2;
  int l0 = cw - l;
  int Og = O/No;
  int tot = C*Og*Wt*Wt;
  int idx = blockIdx.x*blockDim.x + threadIdx.x;
  if(idx >= tot) return;
  int q = idx % Wt;
  int p = (idx/Wt) % Wt;
  int og = (idx/(Wt*Wt)) % Og;
  int c = idx/(Wt*Wt*Og);
  bool valid = (iabs_(p-cw) <= l) && (iabs_(q-cw) <= l);
  if(!valid){
    for(int t = 0; t < No; ++t){
      int o = og*No + t;
      Z[((((size_t)c*O + o)*Lz + l)*Wt + p)*Wt + q] = make_float2(0.f, 0.f);
    }
    return;
  }
  int pp = p - l0, qq = q - l0;
  size_t yoff = (size_t)C*I*2*((size_t)l*(2*l-1)*(2*l+1)/3);
  const cplx* yrow = Y + yoff + (((size_t)(c*I)*K21 + pp)*2)*K21 + qq;
  size_t ystride = (size_t)K21*2*K21;
  const cplx* wp = what + q;
  float ax[8], ay[8];
  for(int t = 0; t < No; ++t){ ax[t] = 0.f; ay[t] = 0.f; }
  for(int i = 0; i < I; ++i){
    cplx y0 = yrow[(size_t)i*ystride];
    cplx y1 = yrow[(size_t)i*ystride + K21];
    int wb = ((og*No)*I + i)*2*Wt;
    int ws = I*2*Wt;
    for(int t = 0; t < No; ++t){
      cplx w0 = wp[wb + t*ws];
      cplx w1 = wp[wb + t*ws + Wt];
      ax[t] += y0.x*w0.x + y0.y*w0.y + y1.x*w1.x + y1.y*w1.y;
      ay[t] += y0.y*w0.x - y0.x*w0.y + y1.y*w1.x - y1.x*w1.y;
    }
  }
  for(int t = 0; t < No; ++t){
    int o = og*No + t;
    Z[((((size_t)c*O + o)*Lz + l)*Wt + p)*Wt + q] = make_float2(ax[t], ay[t]);
  }
}

__global__ void k_zid(const cplx* __restrict__ X, const float* __restrict__ w,
                      cplx* __restrict__ Z, int C, int O, int I, int Lz, int Wt, int Wx, int Lx){
  int total = C*O*Lz*Wt*Wt;
  int idx = blockIdx.x*blockDim.x + threadIdx.x;
  if(idx >= total) return;
  int q = idx % Wt;
  int p = (idx/Wt) % Wt;
  int l = (idx/(Wt*Wt)) % Lz;
  int o = (idx/(Wt*Wt*Lz)) % O;
  int c = idx/(Wt*Wt*Lz*O);
  int cw = (Wt-1)/2, offx = (Wx-Wt)/2;
  float sx = 0.f, sy = 0.f;
  if(iabs_(p-cw) <= l && iabs_(q-cw) <= l){
    for(int i = 0; i < I; ++i){
      cplx v = X[((((size_t)c*I + i)*Lx + l)*Wx + p + offx)*Wx + q + offx];
      float wv = w[o*I + i];
      sx += wv*v.x; sy += wv*v.y;
    }
  }
  Z[idx] = make_float2(sx, sy);
}

// ======================= norm / misc =======================
__global__ void k_gn(const float* __restrict__ x, const float* __restrict__ gam,
                     const float* __restrict__ bet, float* __restrict__ y,
                     int Cch, int G, int S, int relu){
  int n = blockIdx.x / G, g = blockIdx.x % G;
  int cpg = Cch / G;
  size_t base = ((size_t)n*Cch + (size_t)g*cpg)*S;
  int cnt = cpg*S;
  double s = 0.0, sq = 0.0;
  for(int t = threadIdx.x; t < cnt; t += blockDim.x){
    float v = x[base + t]; s += v; sq += (double)v*v;
  }
  __shared__ double rs[256], rq[256];
  int tid = threadIdx.x;
  rs[tid] = s; rq[tid] = sq;
  __syncthreads();
  for(int o = 128; o > 0; o >>= 1){
    if(tid < o){ rs[tid] += rs[tid+o]; rq[tid] += rq[tid+o]; }
    __syncthreads();
  }
  __shared__ float mu_s, inv_s;
  if(tid == 0){
    double m = rs[0]/cnt;
    double var = rq[0]/cnt - m*m;
    mu_s = (float)m;
    inv_s = (float)(1.0/sqrt(var + 1e-5));
  }
  __syncthreads();
  float mu = mu_s, inv = inv_s;
  for(int t = threadIdx.x; t < cnt; t += blockDim.x){
    int c = g*cpg + t/S;
    float v = (x[base+t]-mu)*inv*gam[c] + bet[c];
    y[base+t] = relu ? fmaxf(v, 0.f) : v;
  }
}

__global__ void k_bn(const float* __restrict__ x, const float* __restrict__ gam,
                     const float* __restrict__ bet, float* __restrict__ y,
                     int N, int Cch, int S){
  int c = blockIdx.x;
  int cnt = N*S;
  double s = 0.0, sq = 0.0;
  for(int t = threadIdx.x; t < cnt; t += blockDim.x){
    int n = t / S, sp = t % S;
    float v = x[((size_t)n*Cch + c)*S + sp];
    s += v; sq += (double)v*v;
  }
  __shared__ double rs[256], rq[256];
  int tid = threadIdx.x;
  rs[tid] = s; rq[tid] = sq;
  __syncthreads();
  for(int o = 128; o > 0; o >>= 1){
    if(tid < o){ rs[tid] += rs[tid+o]; rq[tid] += rq[tid+o]; }
    __syncthreads();
  }
  __shared__ float mu_s, inv_s;
  if(tid == 0){
    double m = rs[0]/cnt;
    double var = rq[0]/cnt - m*m;
    mu_s = (float)m;
    inv_s = (float)(1.0/sqrt(var + 1e-5));
  }
  __syncthreads();
  float mu = mu_s, inv = inv_s;
  float ga = gam[c], be = bet[c];
  for(int t = threadIdx.x; t < cnt; t += blockDim.x){
    int n = t / S, sp = t % S;
    size_t id = ((size_t)n*Cch + c)*S + sp;
    y[id] = (x[id]-mu)*inv*ga + be;
  }
}

__global__ void k_addrelu(const float* __restrict__ a, const float* __restrict__ b,
                          float* __restrict__ y, int n){
  int i = blockIdx.x*blockDim.x + threadIdx.x;
  if(i < n) y[i] = fmaxf(a[i] + b[i], 0.f);
}

__global__ void k_integrate(const float* __restrict__ h, const double* __restrict__ wq4,
                            float* __restrict__ out){
  int nc = blockIdx.x;
  const float* hp = h + (size_t)nc*512;
  float s = 0.f;
  for(int t = threadIdx.x; t < 512; t += 64){
    int j = t >> 6;
    s += hp[t] * (float)wq4[j];
  }
  for(int o = 32; o > 0; o >>= 1) s += __shfl_down(s, o);
  if(threadIdx.x == 0) out[nc] = s * (1.f/64.f);
}

// ======================= launch =======================
extern "C" void kernel_launch(void* const* d_in, const int* in_sizes, int n_in,
                              void* d_out, int out_size, void* d_ws, size_t ws_size,
                              hipStream_t stream){
  const float* xin = (const float*)d_in[0];
  const float* w0p = (const float*)d_in[1];
  const float* g0p = (const float*)d_in[2];
  const float* b0p = (const float*)d_in[3];
  const float* w1ap = (const float*)d_in[4];
  const float* g1ap = (const float*)d_in[5];
  const float* b1ap = (const float*)d_in[6];
  const float* w1bp = (const float*)d_in[7];
  const float* g1bp = (const float*)d_in[8];
  const float* b1bp = (const float*)d_in[9];
  const float* w1sp = (const float*)d_in[10];
  const float* g1sp = (const float*)d_in[11];
  const float* b1sp = (const float*)d_in[12];
  const float* w2ap = (const float*)d_in[13];
  const float* g2ap = (const float*)d_in[14];
  const float* b2ap = (const float*)d_in[15];
  const float* w2bp = (const float*)d_in[16];
  const float* g2bp = (const float*)d_in[17];
  const float* b2bp = (const float*)d_in[18];
  const float* w2sp = (const float*)d_in[19];
  const float* g2sp = (const float*)d_in[20];
  const float* b2sp = (const float*)d_in[21];
  float* outp = (float*)d_out;

  char* ws = (char*)d_ws;
  size_t off = 0;
  auto alloc = [&](size_t bytes)->char*{
    char* p = ws + off;
    off = (off + bytes + 255) & ~(size_t)255;
    return p;
  };
  // tables (persistent)
  double* lf   = (double*)alloc(130*8);
  double* wq   = (double*)alloc(120*8);
  cplx* E16    = (cplx*)alloc(31*32*8);
  cplx* E8     = (cplx*)alloc(15*16*8);
  cplx* E4     = (cplx*)alloc(7*8*8);
  cplx* E0f    = (cplx*)alloc(31*64*8);
  float* d032w = (float*)alloc((size_t)64*16*31*4);
  float* dg32  = (float*)alloc((size_t)2*16*31*4);
  float* Wi16  = (float*)alloc((size_t)32*16*961*4);
  float* Wx16  = (float*)alloc((size_t)32*16*961*4);
  float* Dg16  = (float*)alloc((size_t)2*16*961*4);
  float* Wi8   = (float*)alloc((size_t)16*8*225*4);
  float* Wx8   = (float*)alloc((size_t)16*8*225*4);
  float* Dg8   = (float*)alloc((size_t)2*8*225*4);
  float* Wi4   = (float*)alloc((size_t)8*4*49*4);
  // arenas
  char* A_ZHF = alloc((size_t)63*1024*1024);
  char* A_X   = alloc((size_t)32*1024*1024);
  char* A_H1  = alloc((size_t)34*1024*1024);
  char* A_H2  = alloc((size_t)34*1024*1024);
  char* A_S   = alloc((size_t)8*1024*1024);

  // phase aliases
  cplx* xf0    = (cplx*)(A_S);
  cplx* X0     = (cplx*)(A_S + (512<<10));
  cplx* what0  = (cplx*)(A_S + (768<<10));
  cplx* Psi0   = (cplx*)(A_S + (1<<20));
  cplx* Zt0    = (cplx*)A_ZHF;
  float* h0    = (float*)A_H1;
  float* h0n   = (float*)A_H2;
  cplx* hf1    = (cplx*)A_ZHF;
  cplx* X1     = (cplx*)A_X;
  cplx* what1a = (cplx*)A_S;
  cplx* Y1a    = (cplx*)A_H1;
  cplx* Z1a    = (cplx*)A_ZHF;
  float* left1 = (float*)A_H1;
  float* left1n= (float*)A_H2;
  cplx* hf1b   = (cplx*)A_ZHF;
  cplx* X1b    = (cplx*)A_S;
  cplx* what1b = (cplx*)(A_S + (4<<20));
  cplx* Y1b    = (cplx*)A_H2;
  cplx* Z1b    = (cplx*)A_ZHF;
  float* left2 = (float*)A_H1;
  float* left2n= (float*)(A_H1 + (16<<20));
  cplx* Z1s    = (cplx*)A_ZHF;
  float* sc1   = (float*)A_H2;
  float* sc1n  = (float*)(A_H2 + (16<<20));
  float* h1    = (float*)A_H1;
  cplx* hf2    = (cplx*)A_ZHF;
  cplx* X2     = (cplx*)A_X;
  cplx* what2a = (cplx*)A_S;
  cplx* Y2a    = (cplx*)A_H1;
  cplx* Z2a    = (cplx*)A_ZHF;
  float* left3 = (float*)A_H2;
  float* left3n= (float*)(A_H2 + (16<<20));
  cplx* hf2b   = (cplx*)A_ZHF;
  cplx* X2b    = (cplx*)A_S;
  cplx* what2b = (cplx*)(A_S + (1<<20));
  cplx* Y2b    = (cplx*)(A_S + (2<<20));
  cplx* Z2b    = (cplx*)A_ZHF;
  float* left4 = (float*)A_H1;
  float* left4n= (float*)(A_H1 + (4<<20));
  cplx* Z2s    = (cplx*)A_ZHF;
  float* sc2   = (float*)A_H2;
  float* sc2n  = (float*)(A_H2 + (4<<20));
  float* h2    = (float*)(A_H1 + (8<<20));

  auto ifft_smem = [](int b)->size_t{
    int M = 2*b-1, n2 = 2*b;
    return (size_t)(M*n2 + M*n2 + n2*(n2+2))*8;
  };
  auto fft2_smem = [](int b, int Mt)->size_t{
    int n2 = 2*b; int ng = (Mt+3)/4, MtP = 4*ng;
    return (size_t)(n2*(n2+1))*4 + (size_t)(n2*MtP)*8
         + (size_t)(Mt*(n2+1))*8 + (size_t)(n2*MtP)*8;
  };

  // ---- tables ----
  k_tables<<<1,256,0,stream>>>(lf, wq);
  k_twiddle<<<(31*32+255)/256,256,0,stream>>>(E16, 31, 32, 15,  1.0);
  k_twiddle<<<1,256,0,stream>>>(E8, 15, 16, 7,  1.0);
  k_twiddle<<<1,64,0,stream>>>(E4, 7, 8, 3,  1.0);
  k_twiddle<<<(31*64+255)/256,256,0,stream>>>(E0f, 31, 64, 15, -1.0);
  k_wigner_col0<<<(64*16*31+255)/256,256,0,stream>>>(lf, d032w, 64, 16, 31, 0, 32, wq, 2);
  k_wigner_col0<<<(2*16*31+255)/256,256,0,stream>>>(lf, dg32, 2, 16, 31, 1, 0, wq, 0);
  k_wigner_full<<<(32*16*961+255)/256,256,0,stream>>>(lf, Wi16, 32, 16, 31, 0, 16, wq, 1);
  k_wigner_full<<<(32*16*961+255)/256,256,0,stream>>>(lf, Wx16, 32, 16, 31, 0, 16, wq+64, 2);
  k_wigner_full<<<(2*16*961+255)/256,256,0,stream>>>(lf, Dg16, 2, 16, 31, 1, 0, wq, 0);
  k_wigner_full<<<(16*8*225+255)/256,256,0,stream>>>(lf, Wi8, 16, 8, 15, 0, 8, wq, 1);
  k_wigner_full<<<(16*8*225+255)/256,256,0,stream>>>(lf, Wx8, 16, 8, 15, 0, 8, wq+96, 2);
  k_wigner_full<<<(2*8*225+255)/256,256,0,stream>>>(lf, Dg8, 2, 8, 15, 1, 0, wq, 0);
  k_wigner_full<<<(8*4*49+255)/256,256,0,stream>>>(lf, Wi4, 8, 4, 7, 0, 4, wq, 1);

  // ---- layer 0: s2_conv(x, w0, 32, 16) + GN + ReLU ----
  k_fft0<<<(1536*31+255)/256,256,0,stream>>>(xin, xf0, E0f);
  k_what0<<<(96*2*31+255)/256,256,0,stream>>>(w0p, E0f, what0);
  k_X0<<<(24*16*31+255)/256,256,0,stream>>>(xf0, d032w, X0);
  k_Psi0<<<(96*16*31+255)/256,256,0,stream>>>(what0, dg32, Psi0);
  k_Z0<<<(8*32*16*961+255)/256,256,0,stream>>>(X0, Psi0, Zt0);
  k_ifft_t<<<8*32*32,256,ifft_smem(16),stream>>>(Zt0, Wi16, E16, h0, 16);
  k_gn<<<8*16,256,0,stream>>>(h0, g0p, b0p, h0n, 32, 16, 32768, 1);

  // ---- layer 1a: so3_conv(h, w1a, 16, 16) + GN ----
  k_fft2_t<<<256*32,256,fft2_smem(16,31),stream>>>(h0n, hf1, E16, 16, 31);
  k_Xstep<<<(256*16*961+255)/256,256,0,stream>>>(hf1, Wx16, X1, 16, 16, 31, 256);
  k_what<<<(1024*2*31+255)/256,256,0,stream>>>(w1ap, what1a, E16, 32, 31, 0, 1024);
  { dim3 g((256*2*961+255)/256,1,16);
    k_ystep<<<g,256,0,stream>>>(X1, Dg16, Y1a, 256, 31, 31, 16, 16); }
  { dim3 g((8*8*961+255)/256,1,16);
    k_zstep<<<g,256,0,stream>>>(Y1a, what1a, Z1a, 8, 32, 32, 31, 4); }
  k_ifft_t<<<8*32*32,256,ifft_smem(16),stream>>>(Z1a, Wi16, E16, left1, 16);
  k_gn<<<8*16,256,0,stream>>>(left1, g1ap, b1ap, left1n, 32, 16, 32768, 0);

  // ---- layer 1b: so3_conv(left, w1b, 16, 8) + GN + ReLU ----
  k_fft2_t<<<256*32,128,fft2_smem(16,15),stream>>>(left1n, hf1b, E16, 16, 15);
  k_Xstep<<<(256*8*225+255)/256,256,0,stream>>>(hf1b, Wx16, X1b, 16, 8, 15, 256);
  k_what<<<(2048*2*15+255)/256,256,0,stream>>>(w1bp, what1b, E16, 32, 15, 8, 2048);
  { dim3 g((256*2*225+255)/256,1,8);
    k_ystep<<<g,256,0,stream>>>(X1b, Dg16, Y1b, 256, 15, 31, 8, 16); }
  { dim3 g((8*16*225+255)/256,1,8);
    k_zstep<<<g,256,0,stream>>>(Y1b, what1b, Z1b, 8, 64, 32, 15, 4); }
  k_ifft_t<<<8*64*16,64,ifft_smem(8),stream>>>(Z1b, Wi8, E8, left2, 8);
  k_gn<<<8*16,256,0,stream>>>(left2, g1bp, b1bp, left2n, 64, 16, 4096, 1);

  // ---- layer 1s: so3_conv(h, w1s, 16, 8, ID) + BN ; residual add ----
  k_zid<<<(8*64*8*225+255)/256,256,0,stream>>>(X1, w1sp, Z1s, 8, 64, 32, 8, 15, 31, 16);
  k_ifft_t<<<8*64*16,64,ifft_smem(8),stream>>>(Z1s, Wi8, E8, sc1, 8);
  k_bn<<<64,256,0,stream>>>(sc1, g1sp, b1sp, sc1n, 8, 64, 4096);
  k_addrelu<<<(2097152+255)/256,256,0,stream>>>(left2n, sc1n, h1, 2097152);

  // ---- layer 2a: so3_conv(h, w2a, 8, 8) + GN ----
  k_fft2_t<<<512*16,64,fft2_smem(8,15),stream>>>(h1, hf2, E8, 8, 15);
  k_Xstep<<<(512*8*225+255)/256,256,0,stream>>>(hf2, Wx8, X2, 8, 8, 15, 512);
  k_what<<<(4096*2*15+255)/256,256,0,stream>>>(w2ap, what2a, E8, 16, 15, 0, 4096);
  { dim3 g((512*2*225+255)/256,1,8);
    k_ystep<<<g,256,0,stream>>>(X2, Dg8, Y2a, 512, 15, 15, 8, 8); }
  { dim3 g((8*16*225+255)/256,1,8);
    k_zstep<<<g,256,0,stream>>>(Y2a, what2a, Z2a, 8, 64, 64, 15, 4); }
  k_ifft_t<<<8*64*16,64,ifft_smem(8),stream>>>(Z2a, Wi8, E8, left3, 8);
  k_gn<<<8*16,256,0,stream>>>(left3, g2ap, b2ap, left3n, 64, 16, 4096, 0);

  // ---- layer 2b: so3_conv(left, w2b, 8, 4) + GN + ReLU ----
  k_fft2_t<<<512*16,32,fft2_smem(8,7),stream>>>(left3n, hf2b, E8, 8, 7);
  k_Xstep<<<(512*4*49+255)/256,256,0,stream>>>(hf2b, Wx8, X2b, 8, 4, 7, 512);
  k_what<<<(8192*2*7+255)/256,256,0,stream>>>(w2bp, what2b, E8, 16, 7, 4, 8192);
  { dim3 g((512*2*49+255)/256,1,4);
    k_ystep<<<g,256,0,stream>>>(X2b, Dg8, Y2b, 512, 7, 15, 4, 8); }
  { dim3 g((8*32*49+255)/256,1,4);
    k_zstep<<<g,256,0,stream>>>(Y2b, what2b, Z2b, 8, 128, 64, 7, 4); }
  k_ifft_s<<<8*128*8,64,(49+56)*8,stream>>>(Z2b, Wi4, E4, left4, 4);
  k_gn<<<8*32,256,0,stream>>>(left4, g2bp, b2bp, left4n, 128, 32, 512, 1);

  // ---- layer 2s: so3_conv(h, w2s, 8, 4, ID) + BN ; residual add ----
  k_zid<<<(8*128*4*49+255)/256,256,0,stream>>>(X2, w2sp, Z2s, 8, 128, 64, 4, 7, 15, 8);
  k_ifft_s<<<8*128*8,64,(49+56)*8,stream>>>(Z2s, Wi4, E4, sc2, 4);
  k_bn<<<128,256,0,stream>>>(sc2, g2sp, b2sp, sc2n, 8, 128, 512);
  k_addrelu<<<(524288+255)/256,256,0,stream>>>(left4n, sc2n, h2, 524288);

  // ---- integrate ----
  k_integrate<<<1024,64,0,stream>>>(h2, wq+112, outp);
}

// Round 5
// 1564.017 us; speedup vs baseline: 2.2196x; 1.4466x over previous
//
#include <hip/hip_runtime.h>
#include <math.h>

typedef float2 cplx;
#define PI_D 3.14159265358979323846

__device__ __forceinline__ int iabs_(int v){ return v < 0 ? -v : v; }

// ======================= table kernels =======================
__global__ void k_tables(double* lf, double* wq){
  if(threadIdx.x == 0){
    lf[0] = 0.0;
    double acc = 0.0;
    for(int i = 1; i <= 128; ++i){ acc += log((double)i); lf[i] = acc; }
  }
  int t = threadIdx.x;
  int b, j, off;
  if(t < 64){ b = 32; j = t; off = 0; }
  else if(t < 96){ b = 16; j = t - 64; off = 64; }
  else if(t < 112){ b = 8; j = t - 96; off = 96; }
  else if(t < 120){ b = 4; j = t - 112; off = 112; }
  else return;
  double beta = PI_D * (2*j+1) / (4.0*b);
  double s = 0.0;
  for(int p = 0; p < b; ++p) s += sin((2*p+1)*beta) / (2*p+1);
  wq[off+j] = 2.0*PI_D/((double)b*b) * sin(beta) * s;
}

__global__ void k_twiddle(cplx* E, int nfreq, int n, int center, double sgn){
  int idx = blockIdx.x*blockDim.x + threadIdx.x;
  if(idx >= nfreq*n) return;
  int p = idx / n, a = idx % n;
  double ang = sgn * 2.0*PI_D * (double)(p-center) * (double)a / (double)n;
  E[idx] = make_float2((float)cos(ang), (float)sin(ang));
}

// Wigner-d, n=0 column only; smode: 0 none, 1 *(2l+1), 2 *wqs[j]
__global__ void k_wigner_col0(const double* __restrict__ lf, float* __restrict__ out,
                              int nb, int Lmax, int W, int mode, int bq,
                              const double* __restrict__ wqs, int smode){
  int idx = blockIdx.x*blockDim.x + threadIdx.x;
  int total = nb*Lmax*W;
  if(idx >= total) return;
  int m = idx % W;
  int l = (idx/W) % Lmax;
  int j = idx/(W*Lmax);
  int cw = (W-1)/2;
  int mh = m - cw;
  float r = 0.f;
  if(iabs_(mh) <= l){
    double beta = (mode==0) ? PI_D*(2*j+1)/(4.0*bq) : PI_D*(j+1)/16.0;
    double cb = cos(0.5*beta), sb = sin(0.5*beta);
    double lcb = log(cb), lsb = log(sb);
    int k0 = (mh < 0) ? -mh : 0;
    int k1 = (mh > 0) ? (l - mh) : l;
    double s = 0.0;
    for(int k = k0; k <= k1; ++k){
      double logc = 0.5*(lf[l+mh] + lf[l-mh] + 2.0*lf[l])
                    - lf[l-k] - lf[k] - lf[mh+k] - lf[l-mh-k];
      double term = exp(logc + (double)(2*l - mh - 2*k)*lcb + (double)(mh + 2*k)*lsb);
      s += ((mh + k) & 1) ? -term : term;
    }
    if(smode == 1) s *= (double)(2*l+1);
    else if(smode == 2) s *= wqs[j];
    r = (float)s;
  }
  out[idx] = r;
}

// Full Wigner-d; smode: 0 none, 1 *(2l+1), 2 *wqs[j]
__global__ void k_wigner_full(const double* __restrict__ lf, float* __restrict__ out,
                              int nb, int L, int W, int mode, int bq,
                              const double* __restrict__ wqs, int smode){
  int idx = blockIdx.x*blockDim.x + threadIdx.x;
  int total = nb*L*W*W;
  if(idx >= total) return;
  int q = idx % W;
  int p = (idx/W) % W;
  int l = (idx/(W*W)) % L;
  int j = idx/(W*W*L);
  int cw = (W-1)/2;
  int mh = p - cw, nh = q - cw;
  float r = 0.f;
  if(iabs_(mh) <= l && iabs_(nh) <= l){
    double beta = (mode==0) ? PI_D*(2*j+1)/(4.0*bq) : PI_D*(j+1)/16.0;
    double cb = cos(0.5*beta), sb = sin(0.5*beta);
    double lcb = log(cb), lsb = log(sb);
    int k0 = (nh - mh > 0) ? (nh - mh) : 0;
    int a1 = l + nh, b1 = l - mh;
    int k1 = (a1 < b1) ? a1 : b1;
    double s = 0.0;
    for(int k = k0; k <= k1; ++k){
      double logc = 0.5*(lf[l+mh] + lf[l-mh] + lf[l+nh] + lf[l-nh])
                    - lf[l+nh-k] - lf[k] - lf[mh-nh+k] - lf[l-mh-k];
      double term = exp(logc + (double)(2*l + nh - mh - 2*k)*lcb + (double)(mh - nh + 2*k)*lsb);
      s += ((mh - nh + k) & 1) ? -term : term;
    }
    if(smode == 1) s *= (double)(2*l+1);
    else if(smode == 2) s *= wqs[j];
    r = (float)s;
  }
  out[idx] = r;
}

// ======================= layer-0 (S2) kernels =======================
__global__ void k_fft0(const float* __restrict__ x, cplx* __restrict__ xf, const cplx* __restrict__ E0f){
  int idx = blockIdx.x*blockDim.x + threadIdx.x;
  if(idx >= 1536*31) return;
  int m = idx % 31;
  int r = idx / 31;
  const float* xr = x + (size_t)r*64;
  float sr = 0.f, si = 0.f;
  for(int a = 0; a < 64; ++a){
    cplx e = E0f[m*64 + a];
    float v = xr[a];
    sr += v*e.x; si += v*e.y;
  }
  xf[idx] = make_float2(sr*(1.f/64.f), si*(1.f/64.f));
}

__global__ void k_what0(const float* __restrict__ w0, const cplx* __restrict__ E0f, cplx* __restrict__ what0){
  int idx = blockIdx.x*blockDim.x + threadIdx.x;
  if(idx >= 96*2*31) return;
  int m = idx % 31;
  int bi = (idx/31) & 1;
  int oi = idx/62;
  const float* wr = w0 + (size_t)oi*128 + bi*64;
  float sr = 0.f, si = 0.f;
  for(int a = 0; a < 64; ++a){
    cplx e = E0f[m*64 + a];
    float v = wr[a];
    sr += v*e.x; si += v*e.y;
  }
  what0[idx] = make_float2(sr, si);
}

__global__ void k_X0(const cplx* __restrict__ xf, const float* __restrict__ d032w,
                     cplx* __restrict__ X0){
  int idx = blockIdx.x*blockDim.x + threadIdx.x;
  if(idx >= 24*16*31) return;
  int m = idx % 31;
  int l = (idx/31) % 16;
  int ci = idx/(31*16);
  float sx = 0.f, sy = 0.f;
  if(iabs_(m-15) <= l){
    for(int j = 0; j < 64; ++j){
      float d = d032w[((size_t)j*16 + l)*31 + m];
      cplx v = xf[((size_t)ci*64 + j)*31 + m];
      sx += d*v.x; sy += d*v.y;
    }
  }
  X0[idx] = make_float2(sx, sy);
}

__global__ void k_Psi0(const cplx* __restrict__ what0, const float* __restrict__ dg32, cplx* __restrict__ Psi0){
  int idx = blockIdx.x*blockDim.x + threadIdx.x;
  if(idx >= 96*16*31) return;
  int m = idx % 31;
  int l = (idx/31) % 16;
  int oi = idx/(31*16);
  float sx = 0.f, sy = 0.f;
  if(iabs_(m-15) <= l){
    for(int bi = 0; bi < 2; ++bi){
      float d = dg32[((size_t)bi*16 + l)*31 + m];
      cplx v = what0[((size_t)oi*2 + bi)*31 + m];
      sx += d*v.x; sy += d*v.y;
    }
  }
  Psi0[idx] = make_float2(sx, sy);
}

__global__ void k_Z0(const cplx* __restrict__ X0, const cplx* __restrict__ Psi0, cplx* __restrict__ Z){
  int idx = blockIdx.x*blockDim.x + threadIdx.x;
  if(idx >= 8*32*16*961) return;
  int q = idx % 31;
  int p = (idx/31) % 31;
  int l = (idx/961) % 16;
  int o = (idx/(961*16)) % 32;
  int c = idx/(961*16*32);
  float sx = 0.f, sy = 0.f;
  if(iabs_(p-15) <= l && iabs_(q-15) <= l){
    for(int i = 0; i < 3; ++i){
      cplx a = X0[(((size_t)c*3 + i)*16 + l)*31 + p];
      cplx b = Psi0[(((size_t)o*3 + i)*16 + l)*31 + q];
      sx += a.x*b.x + a.y*b.y;
      sy += a.y*b.x - a.x*b.y;
    }
  }
  Z[idx] = make_float2(sx, sy);
}

// ======================= tiled SO3 inverse FFT =======================
__global__ void k_ifft_t(const cplx* __restrict__ Zt, const float* __restrict__ Wst,
                         const cplx* __restrict__ E, float* __restrict__ out, int b){
  int M = 2*b-1, n2 = 2*b, Mp = n2, Mpt = n2+2, cw = b-1;
  int ng = (M+3)/4;
  extern __shared__ char smem[];
  cplx* Es = (cplx*)smem;          // M*n2
  cplx* gt = Es + M*n2;            // M*Mp
  cplx* Tt = gt + M*Mp;            // n2*Mpt
  int j = blockIdx.x % n2;
  int co = blockIdx.x / n2;
  int tid = threadIdx.x, bd = blockDim.x;
  for(int t = tid; t < M*n2; t += bd) Es[t] = E[t];
  for(int t = tid; t < M*(Mp-M); t += bd){
    int r = t/(Mp-M), c = M + t%(Mp-M);
    gt[r*Mp + c] = make_float2(0.f, 0.f);
  }
  const cplx* Zp = Zt + (size_t)co*b*M*M;
  const float* Wj = Wst + (size_t)j*b*M*M;
  for(int t = tid; t < M*M; t += bd){
    int p = t/M, q = t - p*M;
    int lmin = iabs_(p-cw); int l2 = iabs_(q-cw); if(l2 > lmin) lmin = l2;
    float sx = 0.f, sy = 0.f;
    for(int l = lmin; l < b; ++l){
      float w = Wj[((size_t)l*M + p)*M + q];
      cplx z = Zp[((size_t)l*M + p)*M + q];
      sx += w*z.x; sy += w*z.y;
    }
    gt[p*Mp + q] = make_float2(sx, sy);
  }
  __syncthreads();
  if(tid < n2*ng){
    int a = tid/ng, qg = tid - a*ng; int q0 = 4*qg;
    float ax0=0,ax1=0,ax2=0,ax3=0, ay0=0,ay1=0,ay2=0,ay3=0;
    for(int p = 0; p < M; ++p){
      cplx e = Es[p*n2 + a];
      const float4* g4 = (const float4*)(gt + p*Mp + q0);
      float4 ga = g4[0], gb = g4[1];
      ax0 += ga.x*e.x - ga.y*e.y; ay0 += ga.x*e.y + ga.y*e.x;
      ax1 += ga.z*e.x - ga.w*e.y; ay1 += ga.z*e.y + ga.w*e.x;
      ax2 += gb.x*e.x - gb.y*e.y; ay2 += gb.x*e.y + gb.y*e.x;
      ax3 += gb.z*e.x - gb.w*e.y; ay3 += gb.z*e.y + gb.w*e.x;
    }
    cplx* tp = Tt + a*Mpt + q0;
    tp[0] = make_float2(ax0,ay0); tp[1] = make_float2(ax1,ay1);
    tp[2] = make_float2(ax2,ay2); tp[3] = make_float2(ax3,ay3);
  }
  __syncthreads();
  {
    int gc = n2/4;
    int a = tid/gc, gg = tid - a*gc; int g0 = 4*gg;
    if(a < n2){
      float s0=0,s1=0,s2=0,s3=0;
      for(int q = 0; q < M; ++q){
        cplx T = Tt[a*Mpt + q];
        const float4* e4 = (const float4*)(Es + q*n2 + g0);
        float4 ea = e4[0], eb = e4[1];
        s0 += T.x*ea.x - T.y*ea.y;
        s1 += T.x*ea.z - T.y*ea.w;
        s2 += T.x*eb.x - T.y*eb.y;
        s3 += T.x*eb.z - T.y*eb.w;
      }
      float* op = out + (size_t)co*n2*n2*n2 + (size_t)j*n2*n2 + a*n2 + g0;
      *(float4*)op = make_float4(s0,s1,s2,s3);
    }
  }
}

// small (b=4) ifft
__global__ void k_ifft_s(const cplx* __restrict__ Zt, const float* __restrict__ Wst,
                         const cplx* __restrict__ E, float* __restrict__ out, int b){
  int M = 2*b-1, n2 = 2*b, cw = b-1;
  extern __shared__ char smem[];
  cplx* gt = (cplx*)smem;
  cplx* Tt = gt + M*M;
  int blk = blockIdx.x;
  int j = blk % n2;
  int co = blk / n2;
  const cplx* Zp = Zt + (size_t)co * b * M * M;
  for(int t = threadIdx.x; t < M*M; t += blockDim.x){
    int p = t / M, q = t % M;
    int lmin = iabs_(p-cw); int l2 = iabs_(q-cw); if(l2 > lmin) lmin = l2;
    float sx = 0.f, sy = 0.f;
    for(int l = lmin; l < b; ++l){
      float w = Wst[(((size_t)j*b + l)*M + p)*M + q];
      cplx z = Zp[((size_t)l*M + p)*M + q];
      sx += w*z.x; sy += w*z.y;
    }
    gt[t] = make_float2(sx, sy);
  }
  __syncthreads();
  for(int t = threadIdx.x; t < n2*M; t += blockDim.x){
    int a = t / M, q = t % M;
    float sx = 0.f, sy = 0.f;
    for(int p = 0; p < M; ++p){
      cplx e = E[p*n2 + a];
      cplx g = gt[p*M + q];
      sx += g.x*e.x - g.y*e.y;
      sy += g.x*e.y + g.y*e.x;
    }
    Tt[t] = make_float2(sx, sy);
  }
  __syncthreads();
  float* op = out + (size_t)co*n2*n2*n2 + (size_t)j*n2*n2;
  for(int t = threadIdx.x; t < n2*n2; t += blockDim.x){
    int a = t / n2, g = t % n2;
    float s = 0.f;
    for(int q = 0; q < M; ++q){
      cplx e = E[q*n2 + g];
      cplx T = Tt[a*M + q];
      s += T.x*e.x - T.y*e.y;
    }
    op[t] = s;
  }
}

// ======================= batched forward 2D DFT (+fused GN apply) =======================
// blockDim = JB * n2 * ng ; grid = CI * (n2/JB)
// LDS order: ft | Ft | EsT | Es  (keeps float4 regions 16B-aligned)
__global__ void k_fft2_b(const float* __restrict__ f, cplx* __restrict__ hf,
                         const cplx* __restrict__ E, int b, int Mt, int JB,
                         const float2* __restrict__ st, const float* __restrict__ gam,
                         const float* __restrict__ bet, int Cch, int cpg, int relu){
  int M = 2*b-1, n2 = 2*b;
  int off = (M - Mt)/2;
  int ng = (Mt+3)/4, MtP = 4*ng;
  int fs = n2+1, es = n2+1;
  int tpj = n2*ng;
  extern __shared__ char smem[];
  float* ft = (float*)smem;                       // JB*n2*fs
  cplx* Ft  = (cplx*)(ft + JB*n2*fs);             // JB*n2*MtP
  cplx* EsT = Ft + (size_t)JB*n2*MtP;             // n2*MtP
  cplx* Es  = EsT + (size_t)n2*MtP;               // Mt*es
  int nj = n2/JB;
  int ci = blockIdx.x / nj, jg = blockIdx.x % nj;
  int tid = threadIdx.x, bd = blockDim.x;
  float mu = 0.f, inv = 1.f, ga = 1.f, be = 0.f;
  if(st){
    int c = ci % Cch, n = ci / Cch;
    float2 sv = st[n*(Cch/cpg) + c/cpg];
    mu = sv.x; inv = sv.y; ga = gam[c]; be = bet[c];
  }
  const float* fbase = f + ((size_t)ci*n2 + (size_t)jg*JB)*n2*n2;
  for(int t = tid; t < JB*n2*n2; t += bd){
    int sj = t/(n2*n2); int r = t - sj*n2*n2;
    float v = fbase[(size_t)sj*n2*n2 + r];
    if(st){ v = (v - mu)*inv*ga + be; if(relu) v = fmaxf(v, 0.f); }
    ft[sj*n2*fs + (r/n2)*fs + (r%n2)] = v;
  }
  for(int t = tid; t < n2*MtP; t += bd){
    int g = t/MtP, q = t - g*MtP;
    cplx v = make_float2(0.f, 0.f);
    if(q < Mt) v = E[(q+off)*n2 + g];
    EsT[t] = v;
  }
  for(int t = tid; t < Mt*n2; t += bd){
    int r = t/n2, a = t - r*n2;
    Es[r*es + a] = E[(r+off)*n2 + a];
  }
  __syncthreads();
  int slab = tid / tpj, tl = tid - slab*tpj;
  // stage A: Ft[a][q] = sum_g ft[a][g]*conj(E[q][g])
  {
    int a = tl/ng, qg = tl - a*ng; int q0 = 4*qg;
    const float* fr = ft + slab*n2*fs + a*fs;
    float ax0=0,ax1=0,ax2=0,ax3=0, ay0=0,ay1=0,ay2=0,ay3=0;
    for(int g = 0; g < n2; ++g){
      float v = fr[g];
      const float4* e4 = (const float4*)(EsT + g*MtP + q0);
      float4 ea = e4[0], eb = e4[1];
      ax0 += v*ea.x; ay0 -= v*ea.y;
      ax1 += v*ea.z; ay1 -= v*ea.w;
      ax2 += v*eb.x; ay2 -= v*eb.y;
      ax3 += v*eb.z; ay3 -= v*eb.w;
    }
    cplx* Fp = Ft + slab*n2*MtP + a*MtP + q0;
    Fp[0] = make_float2(ax0,ay0); Fp[1] = make_float2(ax1,ay1);
    Fp[2] = make_float2(ax2,ay2); Fp[3] = make_float2(ax3,ay3);
  }
  __syncthreads();
  // stage B: hf[p][q] = (1/n2^2) sum_a conj(Es[p][a]) * Ft[a][q]
  {
    int p = tl/ng, qg = tl - p*ng; int q0 = 4*qg;
    if(p < Mt){
      float ax0=0,ax1=0,ax2=0,ax3=0, ay0=0,ay1=0,ay2=0,ay3=0;
      const cplx* Fb = Ft + slab*n2*MtP;
      for(int a = 0; a < n2; ++a){
        cplx e = Es[p*es + a];
        const float4* F4 = (const float4*)(Fb + a*MtP + q0);
        float4 Fa = F4[0], Fbv = F4[1];
        ax0 += e.x*Fa.x + e.y*Fa.y;  ay0 += e.x*Fa.y - e.y*Fa.x;
        ax1 += e.x*Fa.z + e.y*Fa.w;  ay1 += e.x*Fa.w - e.y*Fa.z;
        ax2 += e.x*Fbv.x + e.y*Fbv.y; ay2 += e.x*Fbv.y - e.y*Fbv.x;
        ax3 += e.x*Fbv.z + e.y*Fbv.w; ay3 += e.x*Fbv.w - e.y*Fbv.z;
      }
      float invn = 1.0f/((float)n2*(float)n2);
      int j = jg*JB + slab;
      cplx* hp = hf + ((size_t)ci*n2 + j)*Mt*Mt + p*Mt;
      if(q0   < Mt) hp[q0  ] = make_float2(ax0*invn, ay0*invn);
      if(q0+1 < Mt) hp[q0+1] = make_float2(ax1*invn, ay1*invn);
      if(q0+2 < Mt) hp[q0+2] = make_float2(ax2*invn, ay2*invn);
      if(q0+3 < Mt) hp[q0+3] = make_float2(ax3*invn, ay3*invn);
    }
  }
}

// X[ci,l,p,q] = sum_j Wx[j,l,p,q]*hf[ci,j,p,q]  (wq pre-folded into Wx)
__global__ void k_Xstep(const cplx* __restrict__ hf, const float* __restrict__ Wst,
                        cplx* __restrict__ X, int b, int Lout, int Mt, int CI){
  int M = 2*b-1, n2 = 2*b;
  int off = (M - Mt)/2, cw = (Mt-1)/2;
  int total = CI*Lout*Mt*Mt;
  int idx = blockIdx.x*blockDim.x + threadIdx.x;
  if(idx >= total) return;
  int q = idx % Mt;
  int p = (idx/Mt) % Mt;
  int l = (idx/(Mt*Mt)) % Lout;
  int ci = idx/(Mt*Mt*Lout);
  float sx = 0.f, sy = 0.f;
  if(iabs_(p-cw) <= l && iabs_(q-cw) <= l){
    for(int j = 0; j < n2; ++j){
      float w = Wst[(((size_t)j*b + l)*M + p + off)*M + q + off];
      cplx v = hf[(((size_t)ci*n2 + j)*Mt + p)*Mt + q];
      sx += w*v.x; sy += w*v.y;
    }
  }
  X[idx] = make_float2(sx, sy);
}

__global__ void k_what(const float* __restrict__ w, cplx* __restrict__ what,
                       const cplx* __restrict__ E, int n2, int Mt, int off, int OI){
  int total = OI*2*Mt;
  int idx = blockIdx.x*blockDim.x + threadIdx.x;
  if(idx >= total) return;
  int p = idx % Mt;
  int bi = (idx/Mt) & 1;
  int oi = idx/(2*Mt);
  const float* wr = w + (size_t)oi*4*n2 + (size_t)bi*2*n2;
  float sr = 0.f, si = 0.f;
  for(int a = 0; a < n2; ++a){
    float v = wr[2*a] + wr[2*a+1];
    cplx e = E[(p+off)*n2 + a];
    sr += v*e.x; si -= v*e.y;
  }
  what[idx] = make_float2(sr, si);
}

// ---- factorized spectral conv ----
__global__ void k_ystep(const cplx* __restrict__ X, const float* __restrict__ Dg,
                        cplx* __restrict__ Y, int CI, int Wt, int Wd, int Lx, int Ld){
  int l = blockIdx.z;
  int K21 = 2*l+1;
  int cw = (Wt-1)/2, cwd = (Wd-1)/2;
  int l0 = cw - l, l0d = cwd - l;
  int tot = CI*2*K21*K21;
  int idx = blockIdx.x*blockDim.x + threadIdx.x;
  if(idx >= tot) return;
  int qq = idx % K21;
  int bi = (idx/K21) & 1;
  int rest = idx/(2*K21);
  int pp = rest % K21;
  int ci = rest / K21;
  size_t yoff = (size_t)CI*2*((size_t)l*(2*l-1)*(2*l+1)/3);
  const cplx* xp = X + (((size_t)ci*Lx + l)*Wt + (pp+l0))*Wt + l0;
  const float* dp = Dg + (((size_t)bi*Ld + l)*Wd + (qq+l0d))*Wd + l0d;
  float sx = 0.f, sy = 0.f;
  for(int k = 0; k < K21; ++k){
    float d = dp[k];
    cplx v = xp[k];
    sx += d*v.x; sy += d*v.y;
  }
  Y[yoff + (((size_t)ci*K21 + pp)*2 + bi)*K21 + qq] = make_float2(sx, sy);
}

__global__ void k_zstep(const cplx* __restrict__ Y, const cplx* __restrict__ what,
                        cplx* __restrict__ Z, int C, int O, int I, int Wt, int No){
  int l = blockIdx.z;
  int Lz = gridDim.z;
  int K21 = 2*l+1;
  int cw = (Wt-1)/2;
  int l0 = cw - l;
  int Og = O/No;
  int tot = C*Og*Wt*Wt;
  int idx = blockIdx.x*blockDim.x + threadIdx.x;
  if(idx >= tot) return;
  int q = idx % Wt;
  int p = (idx/Wt) % Wt;
  int og = (idx/(Wt*Wt)) % Og;
  int c = idx/(Wt*Wt*Og);
  bool valid = (iabs_(p-cw) <= l) && (iabs_(q-cw) <= l);
  if(!valid){
    for(int t = 0; t < No; ++t){
      int o = og*No + t;
      Z[((((size_t)c*O + o)*Lz + l)*Wt + p)*Wt + q] = make_float2(0.f, 0.f);
    }
    return;
  }
  int pp = p - l0, qq = q - l0;
  size_t yoff = (size_t)C*I*2*((size_t)l*(2*l-1)*(2*l+1)/3);
  const cplx* yrow = Y + yoff + (((size_t)(c*I)*K21 + pp)*2)*K21 + qq;
  size_t ystride = (size_t)K21*2*K21;
  const cplx* wp = what + q;
  float ax[8], ay[8];
  for(int t = 0; t < No; ++t){ ax[t] = 0.f; ay[t] = 0.f; }
  for(int i = 0; i < I; ++i){
    cplx y0 = yrow[(size_t)i*ystride];
    cplx y1 = yrow[(size_t)i*ystride + K21];
    int wb = ((og*No)*I + i)*2*Wt;
    int ws = I*2*Wt;
    for(int t = 0; t < No; ++t){
      cplx w0 = wp[wb + t*ws];
      cplx w1 = wp[wb + t*ws + Wt];
      ax[t] += y0.x*w0.x + y0.y*w0.y + y1.x*w1.x + y1.y*w1.y;
      ay[t] += y0.y*w0.x - y0.x*w0.y + y1.y*w1.x - y1.x*w1.y;
    }
  }
  for(int t = 0; t < No; ++t){
    int o = og*No + t;
    Z[((((size_t)c*O + o)*Lz + l)*Wt + p)*Wt + q] = make_float2(ax[t], ay[t]);
  }
}

__global__ void k_zid(const cplx* __restrict__ X, const float* __restrict__ w,
                      cplx* __restrict__ Z, int C, int O, int I, int Lz, int Wt, int Wx, int Lx){
  int total = C*O*Lz*Wt*Wt;
  int idx = blockIdx.x*blockDim.x + threadIdx.x;
  if(idx >= total) return;
  int q = idx % Wt;
  int p = (idx/Wt) % Wt;
  int l = (idx/(Wt*Wt)) % Lz;
  int o = (idx/(Wt*Wt*Lz)) % O;
  int c = idx/(Wt*Wt*Lz*O);
  int cw = (Wt-1)/2, offx = (Wx-Wt)/2;
  float sx = 0.f, sy = 0.f;
  if(iabs_(p-cw) <= l && iabs_(q-cw) <= l){
    for(int i = 0; i < I; ++i){
      cplx v = X[((((size_t)c*I + i)*Lx + l)*Wx + p + offx)*Wx + q + offx];
      float wv = w[o*I + i];
      sx += wv*v.x; sy += wv*v.y;
    }
  }
  Z[idx] = make_float2(sx, sy);
}

// ======================= norm (split stats + fused apply) =======================
// group gi base = gi*grpbase; data = nch chunks of len, stride apart.
__global__ void k_nstat_part(const float* __restrict__ x, double2* __restrict__ part,
                             int nch, int len, long stride, long grpbase, int P){
  int gi = blockIdx.x / P, pp = blockIdx.x % P;
  const float* gx = x + (long)gi*grpbase;
  long total = (long)nch*len;
  long per = (total + P - 1)/P;
  long s0 = (long)pp*per;
  long s1 = s0 + per; if(s1 > total) s1 = total;
  double s = 0.0, sq = 0.0;
  for(long f = s0 + threadIdx.x; f < s1; f += blockDim.x){
    long ch = f/len, e = f - ch*len;
    float v = gx[ch*stride + e];
    s += v; sq += (double)v*v;
  }
  __shared__ double rs[256], rq[256];
  int tid = threadIdx.x;
  rs[tid] = s; rq[tid] = sq;
  __syncthreads();
  for(int o = 128; o > 0; o >>= 1){
    if(tid < o){ rs[tid] += rs[tid+o]; rq[tid] += rq[tid+o]; }
    __syncthreads();
  }
  if(tid == 0) part[gi*P + pp] = make_double2(rs[0], rq[0]);
}

__global__ void k_nstat_fin(const double2* __restrict__ part, float2* __restrict__ st,
                            int ngroups, int P, double cnt){
  int gi = threadIdx.x;
  if(gi >= ngroups) return;
  double s = 0.0, sq = 0.0;
  for(int p = 0; p < P; ++p){ double2 v = part[gi*P + p]; s += v.x; sq += v.y; }
  double mu = s/cnt;
  double var = sq/cnt - mu*mu;
  st[gi] = make_float2((float)mu, (float)(1.0/sqrt(var + 1e-5)));
}

// y = relu( relu(gn(a)) + bn(b) )
__global__ void k_addrelu2(const float* __restrict__ a, const float* __restrict__ b,
                           const float2* __restrict__ gst, const float* __restrict__ gga,
                           const float* __restrict__ gbe,
                           const float2* __restrict__ bst, const float* __restrict__ bga,
                           const float* __restrict__ bbe,
                           float* __restrict__ y, int C, int S, int G, int n_total){
  int idx = blockIdx.x*blockDim.x + threadIdx.x;
  if(idx >= n_total) return;
  int c = (idx/S) % C;
  int n = idx/(S*C);
  int cpg = C/G;
  float2 gs = gst[n*G + c/cpg];
  float2 bs = bst[c];
  float va = fmaxf((a[idx]-gs.x)*gs.y*gga[c] + gbe[c], 0.f);
  float vb = (b[idx]-bs.x)*bs.y*bga[c] + bbe[c];
  y[idx] = fmaxf(va + vb, 0.f);
}

__global__ void k_integrate(const float* __restrict__ h, const double* __restrict__ wq4,
                            float* __restrict__ out){
  int nc = blockIdx.x;
  const float* hp = h + (size_t)nc*512;
  float s = 0.f;
  for(int t = threadIdx.x; t < 512; t += 64){
    int j = t >> 6;
    s += hp[t] * (float)wq4[j];
  }
  for(int o = 32; o > 0; o >>= 1) s += __shfl_down(s, o);
  if(threadIdx.x == 0) out[nc] = s * (1.f/64.f);
}

// ======================= launch =======================
extern "C" void kernel_launch(void* const* d_in, const int* in_sizes, int n_in,
                              void* d_out, int out_size, void* d_ws, size_t ws_size,
                              hipStream_t stream){
  const float* xin = (const float*)d_in[0];
  const float* w0p = (const float*)d_in[1];
  const float* g0p = (const float*)d_in[2];
  const float* b0p = (const float*)d_in[3];
  const float* w1ap = (const float*)d_in[4];
  const float* g1ap = (const float*)d_in[5];
  const float* b1ap = (const float*)d_in[6];
  const float* w1bp = (const float*)d_in[7];
  const float* g1bp = (const float*)d_in[8];
  const float* b1bp = (const float*)d_in[9];
  const float* w1sp = (const float*)d_in[10];
  const float* g1sp = (const float*)d_in[11];
  const float* b1sp = (const float*)d_in[12];
  const float* w2ap = (const float*)d_in[13];
  const float* g2ap = (const float*)d_in[14];
  const float* b2ap = (const float*)d_in[15];
  const float* w2bp = (const float*)d_in[16];
  const float* g2bp = (const float*)d_in[17];
  const float* b2bp = (const float*)d_in[18];
  const float* w2sp = (const float*)d_in[19];
  const float* g2sp = (const float*)d_in[20];
  const float* b2sp = (const float*)d_in[21];
  float* outp = (float*)d_out;

  char* ws = (char*)d_ws;
  size_t off = 0;
  auto alloc = [&](size_t bytes)->char*{
    char* p = ws + off;
    off = (off + bytes + 255) & ~(size_t)255;
    return p;
  };
  // tables (persistent)
  double* lf   = (double*)alloc(130*8);
  double* wq   = (double*)alloc(120*8);
  cplx* E16    = (cplx*)alloc(31*32*8);
  cplx* E8     = (cplx*)alloc(15*16*8);
  cplx* E4     = (cplx*)alloc(7*8*8);
  cplx* E0f    = (cplx*)alloc(31*64*8);
  float* d032w = (float*)alloc((size_t)64*16*31*4);
  float* dg32  = (float*)alloc((size_t)2*16*31*4);
  float* Wi16  = (float*)alloc((size_t)32*16*961*4);
  float* Wx16  = (float*)alloc((size_t)32*16*961*4);
  float* Dg16  = (float*)alloc((size_t)2*16*961*4);
  float* Wi8   = (float*)alloc((size_t)16*8*225*4);
  float* Wx8   = (float*)alloc((size_t)16*8*225*4);
  float* Dg8   = (float*)alloc((size_t)2*8*225*4);
  float* Wi4   = (float*)alloc((size_t)8*4*49*4);
  // norm stats
  double2* part = (double2*)alloc(2048*16);
  float2* st_h0 = (float2*)alloc(256*8);
  float2* st_l1 = (float2*)alloc(256*8);
  float2* st_l2 = (float2*)alloc(256*8);
  float2* st_s1 = (float2*)alloc(256*8);
  float2* st_l3 = (float2*)alloc(256*8);
  float2* st_l4 = (float2*)alloc(256*8);
  float2* st_s2 = (float2*)alloc(256*8);
  // arenas
  char* A_ZHF = alloc((size_t)63*1024*1024);
  char* A_X   = alloc((size_t)32*1024*1024);
  char* A_H1  = alloc((size_t)34*1024*1024);
  char* A_H2  = alloc((size_t)34*1024*1024);
  char* A_S   = alloc((size_t)8*1024*1024);

  // phase aliases
  cplx* xf0    = (cplx*)(A_S);
  cplx* X0     = (cplx*)(A_S + (512<<10));
  cplx* what0  = (cplx*)(A_S + (768<<10));
  cplx* Psi0   = (cplx*)(A_S + (1<<20));
  cplx* Zt0    = (cplx*)A_ZHF;
  float* h0    = (float*)A_H1;              // raw (GN folded into fft2 1a)
  cplx* hf1    = (cplx*)A_ZHF;
  cplx* X1     = (cplx*)A_X;
  cplx* what1a = (cplx*)A_S;
  cplx* Y1a    = (cplx*)A_H2;               // 22.3 MB (A_H2 free: no h0n anymore)
  cplx* Z1a    = (cplx*)A_ZHF;
  float* left1 = (float*)A_H2;              // raw; Y1a dead after zstep
  cplx* hf1b   = (cplx*)A_ZHF;
  cplx* X1b    = (cplx*)A_S;
  cplx* what1b = (cplx*)(A_S + (4<<20));
  cplx* Y1b    = (cplx*)A_H1;               // 2.8 MB; h0 dead after fft2(1a)
  cplx* Z1b    = (cplx*)A_ZHF;
  float* left2 = (float*)A_H1;              // raw 8.4 MB; Y1b dead
  cplx* Z1s    = (cplx*)A_ZHF;
  float* sc1   = (float*)(A_H1 + (12<<20)); // raw 8.4 MB
  float* h1    = (float*)A_H2;              // left1 dead after fft2(1b)
  cplx* hf2    = (cplx*)A_ZHF;
  cplx* X2     = (cplx*)A_X;
  cplx* what2a = (cplx*)A_S;
  cplx* Y2a    = (cplx*)A_H1;               // 5.6 MB; left2/sc1 dead after addrelu2
  cplx* Z2a    = (cplx*)A_ZHF;
  float* left3 = (float*)(A_H1 + (12<<20)); // raw 8.4 MB
  cplx* hf2b   = (cplx*)A_ZHF;
  cplx* X2b    = (cplx*)A_S;
  cplx* what2b = (cplx*)(A_S + (1<<20));
  cplx* Y2b    = (cplx*)(A_S + (2<<20));
  cplx* Z2b    = (cplx*)A_ZHF;
  float* left4 = (float*)A_H1;              // raw 2 MB; Y2a dead after zstep(2a)
  cplx* Z2s    = (cplx*)A_ZHF;
  float* sc2   = (float*)(A_H1 + (4<<20));  // raw 2 MB
  float* h2    = (float*)(A_H1 + (8<<20));
  // NOTE: h1 (A_H2) stays live through fft2(2a); Y2a/left3/left4/sc2 are in A_H1 — no overlap.

  auto ifft_smem = [](int b)->size_t{
    int M = 2*b-1, n2 = 2*b;
    return (size_t)(M*n2 + M*n2 + n2*(n2+2))*8;
  };
  auto fft2b_smem = [](int b, int Mt, int JB)->size_t{
    int n2 = 2*b; int ng = (Mt+3)/4, MtP = 4*ng;
    return (size_t)(JB*n2*(n2+1))*4 + (size_t)(JB*n2*MtP)*8
         + (size_t)(n2*MtP)*8 + (size_t)(Mt*(n2+1))*8;
  };

  // ---- tables ----
  k_tables<<<1,256,0,stream>>>(lf, wq);
  k_twiddle<<<(31*32+255)/256,256,0,stream>>>(E16, 31, 32, 15,  1.0);
  k_twiddle<<<1,256,0,stream>>>(E8, 15, 16, 7,  1.0);
  k_twiddle<<<1,64,0,stream>>>(E4, 7, 8, 3,  1.0);
  k_twiddle<<<(31*64+255)/256,256,0,stream>>>(E0f, 31, 64, 15, -1.0);
  k_wigner_col0<<<(64*16*31+255)/256,256,0,stream>>>(lf, d032w, 64, 16, 31, 0, 32, wq, 2);
  k_wigner_col0<<<(2*16*31+255)/256,256,0,stream>>>(lf, dg32, 2, 16, 31, 1, 0, wq, 0);
  k_wigner_full<<<(32*16*961+255)/256,256,0,stream>>>(lf, Wi16, 32, 16, 31, 0, 16, wq, 1);
  k_wigner_full<<<(32*16*961+255)/256,256,0,stream>>>(lf, Wx16, 32, 16, 31, 0, 16, wq+64, 2);
  k_wigner_full<<<(2*16*961+255)/256,256,0,stream>>>(lf, Dg16, 2, 16, 31, 1, 0, wq, 0);
  k_wigner_full<<<(16*8*225+255)/256,256,0,stream>>>(lf, Wi8, 16, 8, 15, 0, 8, wq, 1);
  k_wigner_full<<<(16*8*225+255)/256,256,0,stream>>>(lf, Wx8, 16, 8, 15, 0, 8, wq+96, 2);
  k_wigner_full<<<(2*8*225+255)/256,256,0,stream>>>(lf, Dg8, 2, 8, 15, 1, 0, wq, 0);
  k_wigner_full<<<(8*4*49+255)/256,256,0,stream>>>(lf, Wi4, 8, 4, 7, 0, 4, wq, 1);

  // ---- layer 0: s2_conv(x, w0, 32, 16); GN folded into fft2(1a) staging ----
  k_fft0<<<(1536*31+255)/256,256,0,stream>>>(xin, xf0, E0f);
  k_what0<<<(96*2*31+255)/256,256,0,stream>>>(w0p, E0f, what0);
  k_X0<<<(24*16*31+255)/256,256,0,stream>>>(xf0, d032w, X0);
  k_Psi0<<<(96*16*31+255)/256,256,0,stream>>>(what0, dg32, Psi0);
  k_Z0<<<(8*32*16*961+255)/256,256,0,stream>>>(X0, Psi0, Zt0);
  k_ifft_t<<<8*32*32,256,ifft_smem(16),stream>>>(Zt0, Wi16, E16, h0, 16);
  // GN stats for h0: C=32,G=16,cpg=2,S=32768 -> 128 groups, len 65536
  k_nstat_part<<<128*16,256,0,stream>>>(h0, part, 1, 65536, 0, 65536, 16);
  k_nstat_fin<<<1,256,0,stream>>>(part, st_h0, 128, 16, 65536.0);

  // ---- layer 1a: so3_conv(h, w1a, 16, 16); GN folded into fft2(1b) ----
  k_fft2_b<<<256*32,256,fft2b_smem(16,31,1),stream>>>(h0, hf1, E16, 16, 31, 1,
                                                      st_h0, g0p, b0p, 32, 2, 1);
  k_Xstep<<<(256*16*961+255)/256,256,0,stream>>>(hf1, Wx16, X1, 16, 16, 31, 256);
  k_what<<<(1024*2*31+255)/256,256,0,stream>>>(w1ap, what1a, E16, 32, 31, 0, 1024);
  { dim3 g((256*2*961+255)/256,1,16);
    k_ystep<<<g,256,0,stream>>>(X1, Dg16, Y1a, 256, 31, 31, 16, 16); }
  { dim3 g((8*8*961+255)/256,1,16);
    k_zstep<<<g,256,0,stream>>>(Y1a, what1a, Z1a, 8, 32, 32, 31, 4); }
  k_ifft_t<<<8*32*32,256,ifft_smem(16),stream>>>(Z1a, Wi16, E16, left1, 16);
  k_nstat_part<<<128*16,256,0,stream>>>(left1, part, 1, 65536, 0, 65536, 16);
  k_nstat_fin<<<1,256,0,stream>>>(part, st_l1, 128, 16, 65536.0);

  // ---- layer 1b: so3_conv(left, w1b, 16, 8) ----
  k_fft2_b<<<256*16,256,fft2b_smem(16,15,2),stream>>>(left1, hf1b, E16, 16, 15, 2,
                                                      st_l1, g1ap, b1ap, 32, 2, 0);
  k_Xstep<<<(256*8*225+255)/256,256,0,stream>>>(hf1b, Wx16, X1b, 16, 8, 15, 256);
  k_what<<<(2048*2*15+255)/256,256,0,stream>>>(w1bp, what1b, E16, 32, 15, 8, 2048);
  { dim3 g((256*2*225+255)/256,1,8);
    k_ystep<<<g,256,0,stream>>>(X1b, Dg16, Y1b, 256, 15, 31, 8, 16); }
  { dim3 g((8*16*225+255)/256,1,8);
    k_zstep<<<g,256,0,stream>>>(Y1b, what1b, Z1b, 8, 64, 32, 15, 4); }
  k_ifft_t<<<8*64*16,64,ifft_smem(8),stream>>>(Z1b, Wi8, E8, left2, 8);
  // GN stats left2: C=64,G=16,cpg=4,S=4096 -> 128 groups, len 16384
  k_nstat_part<<<128*8,256,0,stream>>>(left2, part, 1, 16384, 0, 16384, 8);
  k_nstat_fin<<<1,256,0,stream>>>(part, st_l2, 128, 8, 16384.0);

  // ---- layer 1s: shortcut conv + BN stats ----
  k_zid<<<(8*64*8*225+255)/256,256,0,stream>>>(X1, w1sp, Z1s, 8, 64, 32, 8, 15, 31, 16);
  k_ifft_t<<<8*64*16,64,ifft_smem(8),stream>>>(Z1s, Wi8, E8, sc1, 8);
  // BN stats sc1: 64 channels, nch=8, len=4096, stride=64*4096
  k_nstat_part<<<64*8,256,0,stream>>>(sc1, part, 8, 4096, (long)64*4096, 4096, 8);
  k_nstat_fin<<<1,256,0,stream>>>(part, st_s1, 64, 8, 32768.0);
  k_addrelu2<<<(2097152+255)/256,256,0,stream>>>(left2, sc1, st_l2, g1bp, b1bp,
                                                 st_s1, g1sp, b1sp, h1, 64, 4096, 16, 2097152);

  // ---- layer 2a: so3_conv(h, w2a, 8, 8) ----
  k_fft2_b<<<512*4,256,fft2b_smem(8,15,4),stream>>>(h1, hf2, E8, 8, 15, 4,
                                                    (const float2*)nullptr, nullptr, nullptr, 0, 1, 0);
  k_Xstep<<<(512*8*225+255)/256,256,0,stream>>>(hf2, Wx8, X2, 8, 8, 15, 512);
  k_what<<<(4096*2*15+255)/256,256,0,stream>>>(w2ap, what2a, E8, 16, 15, 0, 4096);
  { dim3 g((512*2*225+255)/256,1,8);
    k_ystep<<<g,256,0,stream>>>(X2, Dg8, Y2a, 512, 15, 15, 8, 8); }
  { dim3 g((8*16*225+255)/256,1,8);
    k_zstep<<<g,256,0,stream>>>(Y2a, what2a, Z2a, 8, 64, 64, 15, 4); }
  k_ifft_t<<<8*64*16,64,ifft_smem(8),stream>>>(Z2a, Wi8, E8, left3, 8);
  k_nstat_part<<<128*8,256,0,stream>>>(left3, part, 1, 16384, 0, 16384, 8);
  k_nstat_fin<<<1,256,0,stream>>>(part, st_l3, 128, 8, 16384.0);

  // ---- layer 2b: so3_conv(left, w2b, 8, 4) ----
  k_fft2_b<<<512*2,256,fft2b_smem(8,7,8),stream>>>(left3, hf2b, E8, 8, 7, 8,
                                                   st_l3, g2ap, b2ap, 64, 4, 0);
  k_Xstep<<<(512*4*49+255)/256,256,0,stream>>>(hf2b, Wx8, X2b, 8, 4, 7, 512);
  k_what<<<(8192*2*7+255)/256,256,0,stream>>>(w2bp, what2b, E8, 16, 7, 4, 8192);
  { dim3 g((512*2*49+255)/256,1,4);
    k_ystep<<<g,256,0,stream>>>(X2b, Dg8, Y2b, 512, 7, 15, 4, 8); }
  { dim3 g((8*32*49+255)/256,1,4);
    k_zstep<<<g,256,0,stream>>>(Y2b, what2b, Z2b, 8, 128, 64, 7, 4); }
  k_ifft_s<<<8*128*8,64,(49+56)*8,stream>>>(Z2b, Wi4, E4, left4, 4);
  // GN stats left4: C=128,G=32,cpg=4,S=512 -> 256 groups, len 2048
  k_nstat_part<<<256*4,256,0,stream>>>(left4, part, 1, 2048, 0, 2048, 4);
  k_nstat_fin<<<1,256,0,stream>>>(part, st_l4, 256, 4, 2048.0);

  // ---- layer 2s: shortcut conv + BN stats ----
  k_zid<<<(8*128*4*49+255)/256,256,0,stream>>>(X2, w2sp, Z2s, 8, 128, 64, 4, 7, 15, 8);
  k_ifft_s<<<8*128*8,64,(49+56)*8,stream>>>(Z2s, Wi4, E4, sc2, 4);
  // BN stats sc2: 128 channels, nch=8, len=512, stride=128*512
  k_nstat_part<<<128*4,256,0,stream>>>(sc2, part, 8, 512, (long)128*512, 512, 4);
  k_nstat_fin<<<1,256,0,stream>>>(part, st_s2, 128, 4, 4096.0);
  k_addrelu2<<<(524288+255)/256,256,0,stream>>>(left4, sc2, st_l4, g2bp, b2bp,
                                                st_s2, g2sp, b2sp, h2, 128, 512, 32, 524288);

  // ---- integrate ----
  k_integrate<<<1024,64,0,stream>>>(h2, wq+112, outp);
}

// Round 6
// 1483.214 us; speedup vs baseline: 2.3405x; 1.0545x over previous
//
#include <hip/hip_runtime.h>
#include <math.h>

typedef float2 cplx;
#define PI_D 3.14159265358979323846

__device__ __forceinline__ int iabs_(int v){ return v < 0 ? -v : v; }

// ======================= table kernels =======================
__global__ void k_tables(double* lf, double* wq){
  if(threadIdx.x == 0){
    lf[0] = 0.0;
    double acc = 0.0;
    for(int i = 1; i <= 128; ++i){ acc += log((double)i); lf[i] = acc; }
  }
  int t = threadIdx.x;
  int b, j, off;
  if(t < 64){ b = 32; j = t; off = 0; }
  else if(t < 96){ b = 16; j = t - 64; off = 64; }
  else if(t < 112){ b = 8; j = t - 96; off = 96; }
  else if(t < 120){ b = 4; j = t - 112; off = 112; }
  else return;
  double beta = PI_D * (2*j+1) / (4.0*b);
  double s = 0.0;
  for(int p = 0; p < b; ++p) s += sin((2*p+1)*beta) / (2*p+1);
  wq[off+j] = 2.0*PI_D/((double)b*b) * sin(beta) * s;
}

__global__ void k_twiddle(cplx* E, int nfreq, int n, int center, double sgn){
  int idx = blockIdx.x*blockDim.x + threadIdx.x;
  if(idx >= nfreq*n) return;
  int p = idx / n, a = idx % n;
  double ang = sgn * 2.0*PI_D * (double)(p-center) * (double)a / (double)n;
  E[idx] = make_float2((float)cos(ang), (float)sin(ang));
}

// Wigner-d, n=0 column only; smode: 0 none, 1 *(2l+1), 2 *wqs[j]
__global__ void k_wigner_col0(const double* __restrict__ lf, float* __restrict__ out,
                              int nb, int Lmax, int W, int mode, int bq,
                              const double* __restrict__ wqs, int smode){
  int idx = blockIdx.x*blockDim.x + threadIdx.x;
  int total = nb*Lmax*W;
  if(idx >= total) return;
  int m = idx % W;
  int l = (idx/W) % Lmax;
  int j = idx/(W*Lmax);
  int cw = (W-1)/2;
  int mh = m - cw;
  float r = 0.f;
  if(iabs_(mh) <= l){
    double beta = (mode==0) ? PI_D*(2*j+1)/(4.0*bq) : PI_D*(j+1)/16.0;
    double cb = cos(0.5*beta), sb = sin(0.5*beta);
    double lcb = log(cb), lsb = log(sb);
    int k0 = (mh < 0) ? -mh : 0;
    int k1 = (mh > 0) ? (l - mh) : l;
    double s = 0.0;
    for(int k = k0; k <= k1; ++k){
      double logc = 0.5*(lf[l+mh] + lf[l-mh] + 2.0*lf[l])
                    - lf[l-k] - lf[k] - lf[mh+k] - lf[l-mh-k];
      double term = exp(logc + (double)(2*l - mh - 2*k)*lcb + (double)(mh + 2*k)*lsb);
      s += ((mh + k) & 1) ? -term : term;
    }
    if(smode == 1) s *= (double)(2*l+1);
    else if(smode == 2) s *= wqs[j];
    r = (float)s;
  }
  out[idx] = r;
}

// Full Wigner-d; smode: 0 none, 1 *(2l+1), 2 *wqs[j]
__global__ void k_wigner_full(const double* __restrict__ lf, float* __restrict__ out,
                              int nb, int L, int W, int mode, int bq,
                              const double* __restrict__ wqs, int smode){
  int idx = blockIdx.x*blockDim.x + threadIdx.x;
  int total = nb*L*W*W;
  if(idx >= total) return;
  int q = idx % W;
  int p = (idx/W) % W;
  int l = (idx/(W*W)) % L;
  int j = idx/(W*W*L);
  int cw = (W-1)/2;
  int mh = p - cw, nh = q - cw;
  float r = 0.f;
  if(iabs_(mh) <= l && iabs_(nh) <= l){
    double beta = (mode==0) ? PI_D*(2*j+1)/(4.0*bq) : PI_D*(j+1)/16.0;
    double cb = cos(0.5*beta), sb = sin(0.5*beta);
    double lcb = log(cb), lsb = log(sb);
    int k0 = (nh - mh > 0) ? (nh - mh) : 0;
    int a1 = l + nh, b1 = l - mh;
    int k1 = (a1 < b1) ? a1 : b1;
    double s = 0.0;
    for(int k = k0; k <= k1; ++k){
      double logc = 0.5*(lf[l+mh] + lf[l-mh] + lf[l+nh] + lf[l-nh])
                    - lf[l+nh-k] - lf[k] - lf[mh-nh+k] - lf[l-mh-k];
      double term = exp(logc + (double)(2*l + nh - mh - 2*k)*lcb + (double)(mh - nh + 2*k)*lsb);
      s += ((mh - nh + k) & 1) ? -term : term;
    }
    if(smode == 1) s *= (double)(2*l+1);
    else if(smode == 2) s *= wqs[j];
    r = (float)s;
  }
  out[idx] = r;
}

// ======================= layer-0 (S2) kernels =======================
__global__ void k_fft0(const float* __restrict__ x, cplx* __restrict__ xf, const cplx* __restrict__ E0f){
  int idx = blockIdx.x*blockDim.x + threadIdx.x;
  if(idx >= 1536*31) return;
  int m = idx % 31;
  int r = idx / 31;
  const float* xr = x + (size_t)r*64;
  float sr = 0.f, si = 0.f;
  for(int a = 0; a < 64; ++a){
    cplx e = E0f[m*64 + a];
    float v = xr[a];
    sr += v*e.x; si += v*e.y;
  }
  xf[idx] = make_float2(sr*(1.f/64.f), si*(1.f/64.f));
}

__global__ void k_what0(const float* __restrict__ w0, const cplx* __restrict__ E0f, cplx* __restrict__ what0){
  int idx = blockIdx.x*blockDim.x + threadIdx.x;
  if(idx >= 96*2*31) return;
  int m = idx % 31;
  int bi = (idx/31) & 1;
  int oi = idx/62;
  const float* wr = w0 + (size_t)oi*128 + bi*64;
  float sr = 0.f, si = 0.f;
  for(int a = 0; a < 64; ++a){
    cplx e = E0f[m*64 + a];
    float v = wr[a];
    sr += v*e.x; si += v*e.y;
  }
  what0[idx] = make_float2(sr, si);
}

__global__ void k_X0(const cplx* __restrict__ xf, const float* __restrict__ d032w,
                     cplx* __restrict__ X0){
  int idx = blockIdx.x*blockDim.x + threadIdx.x;
  if(idx >= 24*16*31) return;
  int m = idx % 31;
  int l = (idx/31) % 16;
  int ci = idx/(31*16);
  float sx = 0.f, sy = 0.f;
  if(iabs_(m-15) <= l){
    for(int j = 0; j < 64; ++j){
      float d = d032w[((size_t)j*16 + l)*31 + m];
      cplx v = xf[((size_t)ci*64 + j)*31 + m];
      sx += d*v.x; sy += d*v.y;
    }
  }
  X0[idx] = make_float2(sx, sy);
}

__global__ void k_Psi0(const cplx* __restrict__ what0, const float* __restrict__ dg32, cplx* __restrict__ Psi0){
  int idx = blockIdx.x*blockDim.x + threadIdx.x;
  if(idx >= 96*16*31) return;
  int m = idx % 31;
  int l = (idx/31) % 16;
  int oi = idx/(31*16);
  float sx = 0.f, sy = 0.f;
  if(iabs_(m-15) <= l){
    for(int bi = 0; bi < 2; ++bi){
      float d = dg32[((size_t)bi*16 + l)*31 + m];
      cplx v = what0[((size_t)oi*2 + bi)*31 + m];
      sx += d*v.x; sy += d*v.y;
    }
  }
  Psi0[idx] = make_float2(sx, sy);
}

__global__ void k_Z0(const cplx* __restrict__ X0, const cplx* __restrict__ Psi0, cplx* __restrict__ Z){
  int idx = blockIdx.x*blockDim.x + threadIdx.x;
  if(idx >= 8*32*16*961) return;
  int q = idx % 31;
  int p = (idx/31) % 31;
  int l = (idx/961) % 16;
  int o = (idx/(961*16)) % 32;
  int c = idx/(961*16*32);
  float sx = 0.f, sy = 0.f;
  if(iabs_(p-15) <= l && iabs_(q-15) <= l){
    for(int i = 0; i < 3; ++i){
      cplx a = X0[(((size_t)c*3 + i)*16 + l)*31 + p];
      cplx b = Psi0[(((size_t)o*3 + i)*16 + l)*31 + q];
      sx += a.x*b.x + a.y*b.y;
      sy += a.y*b.x - a.x*b.y;
    }
  }
  Z[idx] = make_float2(sx, sy);
}

// ======================= j-batched tiled SO3 inverse FFT =======================
// blockDim = JB * n2 * ((M+3)/4) ; grid = C*O * (n2/JB)
// Stage 1 reads each Z element ONCE and applies JB Wigner rows (register accum).
template<int JB>
__global__ void k_ifft_b(const cplx* __restrict__ Zt, const float* __restrict__ Wst,
                         const cplx* __restrict__ E, float* __restrict__ out, int b){
  int M = 2*b-1, n2 = 2*b, Mp = n2, Mpt = n2+2, cw = b-1;
  int ng = (M+3)/4;
  extern __shared__ char smem[];
  cplx* Es = (cplx*)smem;              // M*n2
  cplx* gt = Es + M*n2;                // JB*M*Mp
  cplx* Tt = gt + JB*M*Mp;             // JB*n2*Mpt
  int nj = n2/JB;
  int j0 = (blockIdx.x % nj)*JB;
  int co = blockIdx.x / nj;
  int tid = threadIdx.x, bd = blockDim.x;
  for(int t = tid; t < M*n2; t += bd) Es[t] = E[t];
  // zero pad columns of gt (cols M..Mp-1) for each slab
  for(int t = tid; t < JB*M*(Mp-M); t += bd){
    int s = t/(M*(Mp-M));
    int rr = t - s*(M*(Mp-M));
    int r = rr/(Mp-M), c = M + rr%(Mp-M);
    gt[s*M*Mp + r*Mp + c] = make_float2(0.f, 0.f);
  }
  const cplx* Zp = Zt + (size_t)co*b*M*M;
  for(int t = tid; t < M*M; t += bd){
    int p = t/M, q = t - p*M;
    int lmin = iabs_(p-cw); int l2 = iabs_(q-cw); if(l2 > lmin) lmin = l2;
    float sx[JB], sy[JB];
    #pragma unroll
    for(int s = 0; s < JB; ++s){ sx[s] = 0.f; sy[s] = 0.f; }
    for(int l = lmin; l < b; ++l){
      cplx z = Zp[(size_t)l*M*M + t];
      #pragma unroll
      for(int s = 0; s < JB; ++s){
        float w = Wst[((size_t)(j0+s)*b + l)*M*M + t];
        sx[s] += w*z.x; sy[s] += w*z.y;
      }
    }
    #pragma unroll
    for(int s = 0; s < JB; ++s)
      gt[s*M*Mp + p*Mp + q] = make_float2(sx[s], sy[s]);
  }
  __syncthreads();
  int tpj = n2*ng;
  int slab = tid / tpj, tl = tid - slab*tpj;
  // stage 2: Tt[a][q] = sum_p Es[p][a] * gt[p][q]
  {
    int a = tl/ng, qg = tl - a*ng; int q0 = 4*qg;
    const cplx* gts = gt + slab*M*Mp;
    float ax0=0,ax1=0,ax2=0,ax3=0, ay0=0,ay1=0,ay2=0,ay3=0;
    for(int p = 0; p < M; ++p){
      cplx e = Es[p*n2 + a];
      const float4* g4 = (const float4*)(gts + p*Mp + q0);
      float4 ga = g4[0], gb = g4[1];
      ax0 += ga.x*e.x - ga.y*e.y; ay0 += ga.x*e.y + ga.y*e.x;
      ax1 += ga.z*e.x - ga.w*e.y; ay1 += ga.z*e.y + ga.w*e.x;
      ax2 += gb.x*e.x - gb.y*e.y; ay2 += gb.x*e.y + gb.y*e.x;
      ax3 += gb.z*e.x - gb.w*e.y; ay3 += gb.z*e.y + gb.w*e.x;
    }
    cplx* tp = Tt + slab*n2*Mpt + a*Mpt + q0;
    tp[0] = make_float2(ax0,ay0); tp[1] = make_float2(ax1,ay1);
    tp[2] = make_float2(ax2,ay2); tp[3] = make_float2(ax3,ay3);
  }
  __syncthreads();
  // stage 3: out[a][g] = Re sum_q Tt[a][q] * Es[q][g]
  {
    int gc = n2/4;
    int a = tl/gc, gg = tl - a*gc; int g0 = 4*gg;
    if(a < n2){
      const cplx* Tts = Tt + slab*n2*Mpt;
      float s0=0,s1=0,s2=0,s3=0;
      for(int q = 0; q < M; ++q){
        cplx T = Tts[a*Mpt + q];
        const float4* e4 = (const float4*)(Es + q*n2 + g0);
        float4 ea = e4[0], eb = e4[1];
        s0 += T.x*ea.x - T.y*ea.y;
        s1 += T.x*ea.z - T.y*ea.w;
        s2 += T.x*eb.x - T.y*eb.y;
        s3 += T.x*eb.z - T.y*eb.w;
      }
      float* op = out + (size_t)co*n2*n2*n2 + (size_t)(j0+slab)*n2*n2 + a*n2 + g0;
      *(float4*)op = make_float4(s0,s1,s2,s3);
    }
  }
}

// small (b=4) ifft
__global__ void k_ifft_s(const cplx* __restrict__ Zt, const float* __restrict__ Wst,
                         const cplx* __restrict__ E, float* __restrict__ out, int b){
  int M = 2*b-1, n2 = 2*b, cw = b-1;
  extern __shared__ char smem[];
  cplx* gt = (cplx*)smem;
  cplx* Tt = gt + M*M;
  int blk = blockIdx.x;
  int j = blk % n2;
  int co = blk / n2;
  const cplx* Zp = Zt + (size_t)co * b * M * M;
  for(int t = threadIdx.x; t < M*M; t += blockDim.x){
    int p = t / M, q = t % M;
    int lmin = iabs_(p-cw); int l2 = iabs_(q-cw); if(l2 > lmin) lmin = l2;
    float sx = 0.f, sy = 0.f;
    for(int l = lmin; l < b; ++l){
      float w = Wst[(((size_t)j*b + l)*M + p)*M + q];
      cplx z = Zp[((size_t)l*M + p)*M + q];
      sx += w*z.x; sy += w*z.y;
    }
    gt[t] = make_float2(sx, sy);
  }
  __syncthreads();
  for(int t = threadIdx.x; t < n2*M; t += blockDim.x){
    int a = t / M, q = t % M;
    float sx = 0.f, sy = 0.f;
    for(int p = 0; p < M; ++p){
      cplx e = E[p*n2 + a];
      cplx g = gt[p*M + q];
      sx += g.x*e.x - g.y*e.y;
      sy += g.x*e.y + g.y*e.x;
    }
    Tt[t] = make_float2(sx, sy);
  }
  __syncthreads();
  float* op = out + (size_t)co*n2*n2*n2 + (size_t)j*n2*n2;
  for(int t = threadIdx.x; t < n2*n2; t += blockDim.x){
    int a = t / n2, g = t % n2;
    float s = 0.f;
    for(int q = 0; q < M; ++q){
      cplx e = E[q*n2 + g];
      cplx T = Tt[a*M + q];
      s += T.x*e.x - T.y*e.y;
    }
    op[t] = s;
  }
}

// ======================= batched forward 2D DFT (+fused GN apply) =======================
// blockDim = JB * n2 * ng ; grid = CI * (n2/JB)
__global__ void k_fft2_b(const float* __restrict__ f, cplx* __restrict__ hf,
                         const cplx* __restrict__ E, int b, int Mt, int JB,
                         const float2* __restrict__ st, const float* __restrict__ gam,
                         const float* __restrict__ bet, int Cch, int cpg, int relu){
  int M = 2*b-1, n2 = 2*b;
  int off = (M - Mt)/2;
  int ng = (Mt+3)/4, MtP = 4*ng;
  int fs = n2+1, es = n2+1;
  int tpj = n2*ng;
  extern __shared__ char smem[];
  float* ft = (float*)smem;                       // JB*n2*fs
  cplx* Ft  = (cplx*)(ft + JB*n2*fs);             // JB*n2*MtP
  cplx* EsT = Ft + (size_t)JB*n2*MtP;             // n2*MtP
  cplx* Es  = EsT + (size_t)n2*MtP;               // Mt*es
  int nj = n2/JB;
  int ci = blockIdx.x / nj, jg = blockIdx.x % nj;
  int tid = threadIdx.x, bd = blockDim.x;
  float mu = 0.f, inv = 1.f, ga = 1.f, be = 0.f;
  if(st){
    int c = ci % Cch, n = ci / Cch;
    float2 sv = st[n*(Cch/cpg) + c/cpg];
    mu = sv.x; inv = sv.y; ga = gam[c]; be = bet[c];
  }
  const float* fbase = f + ((size_t)ci*n2 + (size_t)jg*JB)*n2*n2;
  for(int t = tid; t < JB*n2*n2; t += bd){
    int sj = t/(n2*n2); int r = t - sj*n2*n2;
    float v = fbase[(size_t)sj*n2*n2 + r];
    if(st){ v = (v - mu)*inv*ga + be; if(relu) v = fmaxf(v, 0.f); }
    ft[sj*n2*fs + (r/n2)*fs + (r%n2)] = v;
  }
  for(int t = tid; t < n2*MtP; t += bd){
    int g = t/MtP, q = t - g*MtP;
    cplx v = make_float2(0.f, 0.f);
    if(q < Mt) v = E[(q+off)*n2 + g];
    EsT[t] = v;
  }
  for(int t = tid; t < Mt*n2; t += bd){
    int r = t/n2, a = t - r*n2;
    Es[r*es + a] = E[(r+off)*n2 + a];
  }
  __syncthreads();
  int slab = tid / tpj, tl = tid - slab*tpj;
  // stage A: Ft[a][q] = sum_g ft[a][g]*conj(E[q][g])
  {
    int a = tl/ng, qg = tl - a*ng; int q0 = 4*qg;
    const float* fr = ft + slab*n2*fs + a*fs;
    float ax0=0,ax1=0,ax2=0,ax3=0, ay0=0,ay1=0,ay2=0,ay3=0;
    for(int g = 0; g < n2; ++g){
      float v = fr[g];
      const float4* e4 = (const float4*)(EsT + g*MtP + q0);
      float4 ea = e4[0], eb = e4[1];
      ax0 += v*ea.x; ay0 -= v*ea.y;
      ax1 += v*ea.z; ay1 -= v*ea.w;
      ax2 += v*eb.x; ay2 -= v*eb.y;
      ax3 += v*eb.z; ay3 -= v*eb.w;
    }
    cplx* Fp = Ft + slab*n2*MtP + a*MtP + q0;
    Fp[0] = make_float2(ax0,ay0); Fp[1] = make_float2(ax1,ay1);
    Fp[2] = make_float2(ax2,ay2); Fp[3] = make_float2(ax3,ay3);
  }
  __syncthreads();
  // stage B: hf[p][q] = (1/n2^2) sum_a conj(Es[p][a]) * Ft[a][q]
  {
    int p = tl/ng, qg = tl - p*ng; int q0 = 4*qg;
    if(p < Mt){
      float ax0=0,ax1=0,ax2=0,ax3=0, ay0=0,ay1=0,ay2=0,ay3=0;
      const cplx* Fb = Ft + slab*n2*MtP;
      for(int a = 0; a < n2; ++a){
        cplx e = Es[p*es + a];
        const float4* F4 = (const float4*)(Fb + a*MtP + q0);
        float4 Fa = F4[0], Fbv = F4[1];
        ax0 += e.x*Fa.x + e.y*Fa.y;  ay0 += e.x*Fa.y - e.y*Fa.x;
        ax1 += e.x*Fa.z + e.y*Fa.w;  ay1 += e.x*Fa.w - e.y*Fa.z;
        ax2 += e.x*Fbv.x + e.y*Fbv.y; ay2 += e.x*Fbv.y - e.y*Fbv.x;
        ax3 += e.x*Fbv.z + e.y*Fbv.w; ay3 += e.x*Fbv.w - e.y*Fbv.z;
      }
      float invn = 1.0f/((float)n2*(float)n2);
      int j = jg*JB + slab;
      cplx* hp = hf + ((size_t)ci*n2 + j)*Mt*Mt + p*Mt;
      if(q0   < Mt) hp[q0  ] = make_float2(ax0*invn, ay0*invn);
      if(q0+1 < Mt) hp[q0+1] = make_float2(ax1*invn, ay1*invn);
      if(q0+2 < Mt) hp[q0+2] = make_float2(ax2*invn, ay2*invn);
      if(q0+3 < Mt) hp[q0+3] = make_float2(ax3*invn, ay3*invn);
    }
  }
}

// X[ci,l,p,q] = sum_j Wx[j,l,p,q]*hf[ci,j,p,q]  (wq pre-folded into Wx)
__global__ void k_Xstep(const cplx* __restrict__ hf, const float* __restrict__ Wst,
                        cplx* __restrict__ X, int b, int Lout, int Mt, int CI){
  int M = 2*b-1, n2 = 2*b;
  int off = (M - Mt)/2, cw = (Mt-1)/2;
  int total = CI*Lout*Mt*Mt;
  int idx = blockIdx.x*blockDim.x + threadIdx.x;
  if(idx >= total) return;
  int q = idx % Mt;
  int p = (idx/Mt) % Mt;
  int l = (idx/(Mt*Mt)) % Lout;
  int ci = idx/(Mt*Mt*Lout);
  float sx = 0.f, sy = 0.f;
  if(iabs_(p-cw) <= l && iabs_(q-cw) <= l){
    for(int j = 0; j < n2; ++j){
      float w = Wst[(((size_t)j*b + l)*M + p + off)*M + q + off];
      cplx v = hf[(((size_t)ci*n2 + j)*Mt + p)*Mt + q];
      sx += w*v.x; sy += w*v.y;
    }
  }
  X[idx] = make_float2(sx, sy);
}

__global__ void k_what(const float* __restrict__ w, cplx* __restrict__ what,
                       const cplx* __restrict__ E, int n2, int Mt, int off, int OI){
  int total = OI*2*Mt;
  int idx = blockIdx.x*blockDim.x + threadIdx.x;
  if(idx >= total) return;
  int p = idx % Mt;
  int bi = (idx/Mt) & 1;
  int oi = idx/(2*Mt);
  const float* wr = w + (size_t)oi*4*n2 + (size_t)bi*2*n2;
  float sr = 0.f, si = 0.f;
  for(int a = 0; a < n2; ++a){
    float v = wr[2*a] + wr[2*a+1];
    cplx e = E[(p+off)*n2 + a];
    sr += v*e.x; si -= v*e.y;
  }
  what[idx] = make_float2(sr, si);
}

// ---- factorized spectral conv ----
__global__ void k_ystep(const cplx* __restrict__ X, const float* __restrict__ Dg,
                        cplx* __restrict__ Y, int CI, int Wt, int Wd, int Lx, int Ld){
  int l = blockIdx.z;
  int K21 = 2*l+1;
  int cw = (Wt-1)/2, cwd = (Wd-1)/2;
  int l0 = cw - l, l0d = cwd - l;
  int tot = CI*2*K21*K21;
  int idx = blockIdx.x*blockDim.x + threadIdx.x;
  if(idx >= tot) return;
  int qq = idx % K21;
  int bi = (idx/K21) & 1;
  int rest = idx/(2*K21);
  int pp = rest % K21;
  int ci = rest / K21;
  size_t yoff = (size_t)CI*2*((size_t)l*(2*l-1)*(2*l+1)/3);
  const cplx* xp = X + (((size_t)ci*Lx + l)*Wt + (pp+l0))*Wt + l0;
  const float* dp = Dg + (((size_t)bi*Ld + l)*Wd + (qq+l0d))*Wd + l0d;
  float sx = 0.f, sy = 0.f;
  for(int k = 0; k < K21; ++k){
    float d = dp[k];
    cplx v = xp[k];
    sx += d*v.x; sy += d*v.y;
  }
  Y[yoff + (((size_t)ci*K21 + pp)*2 + bi)*K21 + qq] = make_float2(sx, sy);
}

__global__ void k_zstep(const cplx* __restrict__ Y, const cplx* __restrict__ what,
                        cplx* __restrict__ Z, int C, int O, int I, int Wt, int No){
  int l = blockIdx.z;
  int Lz = gridDim.z;
  int K21 = 2*l+1;
  int cw = (Wt-1)/2;
  int l0 = cw - l;
  int Og = O/No;
  int tot = C*Og*Wt*Wt;
  int idx = blockIdx.x*blockDim.x + threadIdx.x;
  if(idx >= tot) return;
  int q = idx % Wt;
  int p = (idx/Wt) % Wt;
  int og = (idx/(Wt*Wt)) % Og;
  int c = idx/(Wt*Wt*Og);
  bool valid = (iabs_(p-cw) <= l) && (iabs_(q-cw) <= l);
  if(!valid){
    for(int t = 0; t < No; ++t){
      int o = og*No + t;
      Z[((((size_t)c*O + o)*Lz + l)*Wt + p)*Wt + q] = make_float2(0.f, 0.f);
    }
    return;
  }
  int pp = p - l0, qq = q - l0;
  size_t yoff = (size_t)C*I*2*((size_t)l*(2*l-1)*(2*l+1)/3);
  const cplx* yrow = Y + yoff + (((size_t)(c*I)*K21 + pp)*2)*K21 + qq;
  size_t ystride = (size_t)K21*2*K21;
  const cplx* wp = what + q;
  float ax[8], ay[8];
  for(int t = 0; t < No; ++t){ ax[t] = 0.f; ay[t] = 0.f; }
  for(int i = 0; i < I; ++i){
    cplx y0 = yrow[(size_t)i*ystride];
    cplx y1 = yrow[(size_t)i*ystride + K21];
    int wb = ((og*No)*I + i)*2*Wt;
    int ws = I*2*Wt;
    for(int t = 0; t < No; ++t){
      cplx w0 = wp[wb + t*ws];
      cplx w1 = wp[wb + t*ws + Wt];
      ax[t] += y0.x*w0.x + y0.y*w0.y + y1.x*w1.x + y1.y*w1.y;
      ay[t] += y0.y*w0.x - y0.x*w0.y + y1.y*w1.x - y1.x*w1.y;
    }
  }
  for(int t = 0; t < No; ++t){
    int o = og*No + t;
    Z[((((size_t)c*O + o)*Lz + l)*Wt + p)*Wt + q] = make_float2(ax[t], ay[t]);
  }
}

__global__ void k_zid(const cplx* __restrict__ X, const float* __restrict__ w,
                      cplx* __restrict__ Z, int C, int O, int I, int Lz, int Wt, int Wx, int Lx){
  int total = C*O*Lz*Wt*Wt;
  int idx = blockIdx.x*blockDim.x + threadIdx.x;
  if(idx >= total) return;
  int q = idx % Wt;
  int p = (idx/Wt) % Wt;
  int l = (idx/(Wt*Wt)) % Lz;
  int o = (idx/(Wt*Wt*Lz)) % O;
  int c = idx/(Wt*Wt*Lz*O);
  int cw = (Wt-1)/2, offx = (Wx-Wt)/2;
  float sx = 0.f, sy = 0.f;
  if(iabs_(p-cw) <= l && iabs_(q-cw) <= l){
    for(int i = 0; i < I; ++i){
      cplx v = X[((((size_t)c*I + i)*Lx + l)*Wx + p + offx)*Wx + q + offx];
      float wv = w[o*I + i];
      sx += wv*v.x; sy += wv*v.y;
    }
  }
  Z[idx] = make_float2(sx, sy);
}

// ======================= norm (split stats + fused apply) =======================
__global__ void k_nstat_part(const float* __restrict__ x, double2* __restrict__ part,
                             int nch, int len, long stride, long grpbase, int P){
  int gi = blockIdx.x / P, pp = blockIdx.x % P;
  const float* gx = x + (long)gi*grpbase;
  long total = (long)nch*len;
  long per = (total + P - 1)/P;
  long s0 = (long)pp*per;
  long s1 = s0 + per; if(s1 > total) s1 = total;
  double s = 0.0, sq = 0.0;
  for(long f = s0 + threadIdx.x; f < s1; f += blockDim.x){
    long ch = f/len, e = f - ch*len;
    float v = gx[ch*stride + e];
    s += v; sq += (double)v*v;
  }
  __shared__ double rs[256], rq[256];
  int tid = threadIdx.x;
  rs[tid] = s; rq[tid] = sq;
  __syncthreads();
  for(int o = 128; o > 0; o >>= 1){
    if(tid < o){ rs[tid] += rs[tid+o]; rq[tid] += rq[tid+o]; }
    __syncthreads();
  }
  if(tid == 0) part[gi*P + pp] = make_double2(rs[0], rq[0]);
}

__global__ void k_nstat_fin(const double2* __restrict__ part, float2* __restrict__ st,
                            int ngroups, int P, double cnt){
  int gi = threadIdx.x;
  if(gi >= ngroups) return;
  double s = 0.0, sq = 0.0;
  for(int p = 0; p < P; ++p){ double2 v = part[gi*P + p]; s += v.x; sq += v.y; }
  double mu = s/cnt;
  double var = sq/cnt - mu*mu;
  st[gi] = make_float2((float)mu, (float)(1.0/sqrt(var + 1e-5)));
}

// y = relu( relu(gn(a)) + bn(b) )
__global__ void k_addrelu2(const float* __restrict__ a, const float* __restrict__ b,
                           const float2* __restrict__ gst, const float* __restrict__ gga,
                           const float* __restrict__ gbe,
                           const float2* __restrict__ bst, const float* __restrict__ bga,
                           const float* __restrict__ bbe,
                           float* __restrict__ y, int C, int S, int G, int n_total){
  int idx = blockIdx.x*blockDim.x + threadIdx.x;
  if(idx >= n_total) return;
  int c = (idx/S) % C;
  int n = idx/(S*C);
  int cpg = C/G;
  float2 gs = gst[n*G + c/cpg];
  float2 bs = bst[c];
  float va = fmaxf((a[idx]-gs.x)*gs.y*gga[c] + gbe[c], 0.f);
  float vb = (b[idx]-bs.x)*bs.y*bga[c] + bbe[c];
  y[idx] = fmaxf(va + vb, 0.f);
}

__global__ void k_integrate(const float* __restrict__ h, const double* __restrict__ wq4,
                            float* __restrict__ out){
  int nc = blockIdx.x;
  const float* hp = h + (size_t)nc*512;
  float s = 0.f;
  for(int t = threadIdx.x; t < 512; t += 64){
    int j = t >> 6;
    s += hp[t] * (float)wq4[j];
  }
  for(int o = 32; o > 0; o >>= 1) s += __shfl_down(s, o);
  if(threadIdx.x == 0) out[nc] = s * (1.f/64.f);
}

// ======================= launch =======================
extern "C" void kernel_launch(void* const* d_in, const int* in_sizes, int n_in,
                              void* d_out, int out_size, void* d_ws, size_t ws_size,
                              hipStream_t stream){
  const float* xin = (const float*)d_in[0];
  const float* w0p = (const float*)d_in[1];
  const float* g0p = (const float*)d_in[2];
  const float* b0p = (const float*)d_in[3];
  const float* w1ap = (const float*)d_in[4];
  const float* g1ap = (const float*)d_in[5];
  const float* b1ap = (const float*)d_in[6];
  const float* w1bp = (const float*)d_in[7];
  const float* g1bp = (const float*)d_in[8];
  const float* b1bp = (const float*)d_in[9];
  const float* w1sp = (const float*)d_in[10];
  const float* g1sp = (const float*)d_in[11];
  const float* b1sp = (const float*)d_in[12];
  const float* w2ap = (const float*)d_in[13];
  const float* g2ap = (const float*)d_in[14];
  const float* b2ap = (const float*)d_in[15];
  const float* w2bp = (const float*)d_in[16];
  const float* g2bp = (const float*)d_in[17];
  const float* b2bp = (const float*)d_in[18];
  const float* w2sp = (const float*)d_in[19];
  const float* g2sp = (const float*)d_in[20];
  const float* b2sp = (const float*)d_in[21];
  float* outp = (float*)d_out;

  char* ws = (char*)d_ws;
  size_t off = 0;
  auto alloc = [&](size_t bytes)->char*{
    char* p = ws + off;
    off = (off + bytes + 255) & ~(size_t)255;
    return p;
  };
  // tables (persistent)
  double* lf   = (double*)alloc(130*8);
  double* wq   = (double*)alloc(120*8);
  cplx* E16    = (cplx*)alloc(31*32*8);
  cplx* E8     = (cplx*)alloc(15*16*8);
  cplx* E4     = (cplx*)alloc(7*8*8);
  cplx* E0f    = (cplx*)alloc(31*64*8);
  float* d032w = (float*)alloc((size_t)64*16*31*4);
  float* dg32  = (float*)alloc((size_t)2*16*31*4);
  float* Wi16  = (float*)alloc((size_t)32*16*961*4);
  float* Wx16  = (float*)alloc((size_t)32*16*961*4);
  float* Dg16  = (float*)alloc((size_t)2*16*961*4);
  float* Wi8   = (float*)alloc((size_t)16*8*225*4);
  float* Wx8   = (float*)alloc((size_t)16*8*225*4);
  float* Dg8   = (float*)alloc((size_t)2*8*225*4);
  float* Wi4   = (float*)alloc((size_t)8*4*49*4);
  // norm stats
  double2* part = (double2*)alloc(2048*16);
  float2* st_h0 = (float2*)alloc(256*8);
  float2* st_l1 = (float2*)alloc(256*8);
  float2* st_l2 = (float2*)alloc(256*8);
  float2* st_s1 = (float2*)alloc(256*8);
  float2* st_l3 = (float2*)alloc(256*8);
  float2* st_l4 = (float2*)alloc(256*8);
  float2* st_s2 = (float2*)alloc(256*8);
  // arenas
  char* A_ZHF = alloc((size_t)63*1024*1024);
  char* A_X   = alloc((size_t)32*1024*1024);
  char* A_H1  = alloc((size_t)34*1024*1024);
  char* A_H2  = alloc((size_t)34*1024*1024);
  char* A_S   = alloc((size_t)8*1024*1024);

  // phase aliases
  cplx* xf0    = (cplx*)(A_S);
  cplx* X0     = (cplx*)(A_S + (512<<10));
  cplx* what0  = (cplx*)(A_S + (768<<10));
  cplx* Psi0   = (cplx*)(A_S + (1<<20));
  cplx* Zt0    = (cplx*)A_ZHF;
  float* h0    = (float*)A_H1;
  cplx* hf1    = (cplx*)A_ZHF;
  cplx* X1     = (cplx*)A_X;
  cplx* what1a = (cplx*)A_S;
  cplx* Y1a    = (cplx*)A_H2;
  cplx* Z1a    = (cplx*)A_ZHF;
  float* left1 = (float*)A_H2;
  cplx* hf1b   = (cplx*)A_ZHF;
  cplx* X1b    = (cplx*)A_S;
  cplx* what1b = (cplx*)(A_S + (4<<20));
  cplx* Y1b    = (cplx*)A_H1;
  cplx* Z1b    = (cplx*)A_ZHF;
  float* left2 = (float*)A_H1;
  cplx* Z1s    = (cplx*)A_ZHF;
  float* sc1   = (float*)(A_H1 + (12<<20));
  float* h1    = (float*)A_H2;
  cplx* hf2    = (cplx*)A_ZHF;
  cplx* X2     = (cplx*)A_X;
  cplx* what2a = (cplx*)A_S;
  cplx* Y2a    = (cplx*)A_H1;
  cplx* Z2a    = (cplx*)A_ZHF;
  float* left3 = (float*)(A_H1 + (12<<20));
  cplx* hf2b   = (cplx*)A_ZHF;
  cplx* X2b    = (cplx*)A_S;
  cplx* what2b = (cplx*)(A_S + (1<<20));
  cplx* Y2b    = (cplx*)(A_S + (2<<20));
  cplx* Z2b    = (cplx*)A_ZHF;
  float* left4 = (float*)A_H1;
  cplx* Z2s    = (cplx*)A_ZHF;
  float* sc2   = (float*)(A_H1 + (4<<20));
  float* h2    = (float*)(A_H1 + (8<<20));

  auto ifftb_smem = [](int b, int JB)->size_t{
    int M = 2*b-1, n2 = 2*b;
    return (size_t)(M*n2 + JB*M*n2 + JB*n2*(n2+2))*8;
  };
  auto fft2b_smem = [](int b, int Mt, int JB)->size_t{
    int n2 = 2*b; int ng = (Mt+3)/4, MtP = 4*ng;
    return (size_t)(JB*n2*(n2+1))*4 + (size_t)(JB*n2*MtP)*8
         + (size_t)(n2*MtP)*8 + (size_t)(Mt*(n2+1))*8;
  };

  // ---- tables ----
  k_tables<<<1,256,0,stream>>>(lf, wq);
  k_twiddle<<<(31*32+255)/256,256,0,stream>>>(E16, 31, 32, 15,  1.0);
  k_twiddle<<<1,256,0,stream>>>(E8, 15, 16, 7,  1.0);
  k_twiddle<<<1,64,0,stream>>>(E4, 7, 8, 3,  1.0);
  k_twiddle<<<(31*64+255)/256,256,0,stream>>>(E0f, 31, 64, 15, -1.0);
  k_wigner_col0<<<(64*16*31+255)/256,256,0,stream>>>(lf, d032w, 64, 16, 31, 0, 32, wq, 2);
  k_wigner_col0<<<(2*16*31+255)/256,256,0,stream>>>(lf, dg32, 2, 16, 31, 1, 0, wq, 0);
  k_wigner_full<<<(32*16*961+255)/256,256,0,stream>>>(lf, Wi16, 32, 16, 31, 0, 16, wq, 1);
  k_wigner_full<<<(32*16*961+255)/256,256,0,stream>>>(lf, Wx16, 32, 16, 31, 0, 16, wq+64, 2);
  k_wigner_full<<<(2*16*961+255)/256,256,0,stream>>>(lf, Dg16, 2, 16, 31, 1, 0, wq, 0);
  k_wigner_full<<<(16*8*225+255)/256,256,0,stream>>>(lf, Wi8, 16, 8, 15, 0, 8, wq, 1);
  k_wigner_full<<<(16*8*225+255)/256,256,0,stream>>>(lf, Wx8, 16, 8, 15, 0, 8, wq+96, 2);
  k_wigner_full<<<(2*8*225+255)/256,256,0,stream>>>(lf, Dg8, 2, 8, 15, 1, 0, wq, 0);
  k_wigner_full<<<(8*4*49+255)/256,256,0,stream>>>(lf, Wi4, 8, 4, 7, 0, 4, wq, 1);

  // ---- layer 0: s2_conv(x, w0, 32, 16); GN folded into fft2(1a) staging ----
  k_fft0<<<(1536*31+255)/256,256,0,stream>>>(xin, xf0, E0f);
  k_what0<<<(96*2*31+255)/256,256,0,stream>>>(w0p, E0f, what0);
  k_X0<<<(24*16*31+255)/256,256,0,stream>>>(xf0, d032w, X0);
  k_Psi0<<<(96*16*31+255)/256,256,0,stream>>>(what0, dg32, Psi0);
  k_Z0<<<(8*32*16*961+255)/256,256,0,stream>>>(X0, Psi0, Zt0);
  k_ifft_b<2><<<8*32*16,512,ifftb_smem(16,2),stream>>>(Zt0, Wi16, E16, h0, 16);
  k_nstat_part<<<128*16,256,0,stream>>>(h0, part, 1, 65536, 0, 65536, 16);
  k_nstat_fin<<<1,256,0,stream>>>(part, st_h0, 128, 16, 65536.0);

  // ---- layer 1a: so3_conv(h, w1a, 16, 16); GN folded into fft2 staging ----
  k_fft2_b<<<256*16,512,fft2b_smem(16,31,2),stream>>>(h0, hf1, E16, 16, 31, 2,
                                                      st_h0, g0p, b0p, 32, 2, 1);
  k_Xstep<<<(256*16*961+255)/256,256,0,stream>>>(hf1, Wx16, X1, 16, 16, 31, 256);
  k_what<<<(1024*2*31+255)/256,256,0,stream>>>(w1ap, what1a, E16, 32, 31, 0, 1024);
  { dim3 g((256*2*961+255)/256,1,16);
    k_ystep<<<g,256,0,stream>>>(X1, Dg16, Y1a, 256, 31, 31, 16, 16); }
  { dim3 g((8*8*961+255)/256,1,16);
    k_zstep<<<g,256,0,stream>>>(Y1a, what1a, Z1a, 8, 32, 32, 31, 4); }
  k_ifft_b<2><<<8*32*16,512,ifftb_smem(16,2),stream>>>(Z1a, Wi16, E16, left1, 16);
  k_nstat_part<<<128*16,256,0,stream>>>(left1, part, 1, 65536, 0, 65536, 16);
  k_nstat_fin<<<1,256,0,stream>>>(part, st_l1, 128, 16, 65536.0);

  // ---- layer 1b: so3_conv(left, w1b, 16, 8) ----
  k_fft2_b<<<256*16,256,fft2b_smem(16,15,2),stream>>>(left1, hf1b, E16, 16, 15, 2,
                                                      st_l1, g1ap, b1ap, 32, 2, 0);
  k_Xstep<<<(256*8*225+255)/256,256,0,stream>>>(hf1b, Wx16, X1b, 16, 8, 15, 256);
  k_what<<<(2048*2*15+255)/256,256,0,stream>>>(w1bp, what1b, E16, 32, 15, 8, 2048);
  { dim3 g((256*2*225+255)/256,1,8);
    k_ystep<<<g,256,0,stream>>>(X1b, Dg16, Y1b, 256, 15, 31, 8, 16); }
  { dim3 g((8*16*225+255)/256,1,8);
    k_zstep<<<g,256,0,stream>>>(Y1b, what1b, Z1b, 8, 64, 32, 15, 4); }
  k_ifft_b<4><<<8*64*4,256,ifftb_smem(8,4),stream>>>(Z1b, Wi8, E8, left2, 8);
  k_nstat_part<<<128*8,256,0,stream>>>(left2, part, 1, 16384, 0, 16384, 8);
  k_nstat_fin<<<1,256,0,stream>>>(part, st_l2, 128, 8, 16384.0);

  // ---- layer 1s: shortcut conv + BN stats ----
  k_zid<<<(8*64*8*225+255)/256,256,0,stream>>>(X1, w1sp, Z1s, 8, 64, 32, 8, 15, 31, 16);
  k_ifft_b<4><<<8*64*4,256,ifftb_smem(8,4),stream>>>(Z1s, Wi8, E8, sc1, 8);
  k_nstat_part<<<64*8,256,0,stream>>>(sc1, part, 8, 4096, (long)64*4096, 4096, 8);
  k_nstat_fin<<<1,256,0,stream>>>(part, st_s1, 64, 8, 32768.0);
  k_addrelu2<<<(2097152+255)/256,256,0,stream>>>(left2, sc1, st_l2, g1bp, b1bp,
                                                 st_s1, g1sp, b1sp, h1, 64, 4096, 16, 2097152);

  // ---- layer 2a: so3_conv(h, w2a, 8, 8) ----
  k_fft2_b<<<512*4,256,fft2b_smem(8,15,4),stream>>>(h1, hf2, E8, 8, 15, 4,
                                                    (const float2*)nullptr, nullptr, nullptr, 0, 1, 0);
  k_Xstep<<<(512*8*225+255)/256,256,0,stream>>>(hf2, Wx8, X2, 8, 8, 15, 512);
  k_what<<<(4096*2*15+255)/256,256,0,stream>>>(w2ap, what2a, E8, 16, 15, 0, 4096);
  { dim3 g((512*2*225+255)/256,1,8);
    k_ystep<<<g,256,0,stream>>>(X2, Dg8, Y2a, 512, 15, 15, 8, 8); }
  { dim3 g((8*16*225+255)/256,1,8);
    k_zstep<<<g,256,0,stream>>>(Y2a, what2a, Z2a, 8, 64, 64, 15, 4); }
  k_ifft_b<4><<<8*64*4,256,ifftb_smem(8,4),stream>>>(Z2a, Wi8, E8, left3, 8);
  k_nstat_part<<<128*8,256,0,stream>>>(left3, part, 1, 16384, 0, 16384, 8);
  k_nstat_fin<<<1,256,0,stream>>>(part, st_l3, 128, 8, 16384.0);

  // ---- layer 2b: so3_conv(left, w2b, 8, 4) ----
  k_fft2_b<<<512*2,256,fft2b_smem(8,7,8),stream>>>(left3, hf2b, E8, 8, 7, 8,
                                                   st_l3, g2ap, b2ap, 64, 4, 0);
  k_Xstep<<<(512*4*49+255)/256,256,0,stream>>>(hf2b, Wx8, X2b, 8, 4, 7, 512);
  k_what<<<(8192*2*7+255)/256,256,0,stream>>>(w2bp, what2b, E8, 16, 7, 4, 8192);
  { dim3 g((512*2*49+255)/256,1,4);
    k_ystep<<<g,256,0,stream>>>(X2b, Dg8, Y2b, 512, 7, 15, 4, 8); }
  { dim3 g((8*32*49+255)/256,1,4);
    k_zstep<<<g,256,0,stream>>>(Y2b, what2b, Z2b, 8, 128, 64, 7, 4); }
  k_ifft_s<<<8*128*8,64,(49+56)*8,stream>>>(Z2b, Wi4, E4, left4, 4);
  k_nstat_part<<<256*4,256,0,stream>>>(left4, part, 1, 2048, 0, 2048, 4);
  k_nstat_fin<<<1,256,0,stream>>>(part, st_l4, 256, 4, 2048.0);

  // ---- layer 2s: shortcut conv + BN stats ----
  k_zid<<<(8*128*4*49+255)/256,256,0,stream>>>(X2, w2sp, Z2s, 8, 128, 64, 4, 7, 15, 8);
  k_ifft_s<<<8*128*8,64,(49+56)*8,stream>>>(Z2s, Wi4, E4, sc2, 4);
  k_nstat_part<<<128*4,256,0,stream>>>(sc2, part, 8, 512, (long)128*512, 512, 4);
  k_nstat_fin<<<1,256,0,stream>>>(part, st_s2, 128, 4, 4096.0);
  k_addrelu2<<<(524288+255)/256,256,0,stream>>>(left4, sc2, st_l4, g2bp, b2bp,
                                                st_s2, g2sp, b2sp, h2, 128, 512, 32, 524288);

  // ---- integrate ----
  k_integrate<<<1024,64,0,stream>>>(h2, wq+112, outp);
}

// Round 7
// 1431.214 us; speedup vs baseline: 2.4256x; 1.0363x over previous
//
#include <hip/hip_runtime.h>
#include <math.h>

typedef float2 cplx;
#define PI_D 3.14159265358979323846

__device__ __forceinline__ int iabs_(int v){ return v < 0 ? -v : v; }

// ======================= table kernels =======================
__global__ void k_tables(double* lf, double* wq){
  if(threadIdx.x == 0){
    lf[0] = 0.0;
    double acc = 0.0;
    for(int i = 1; i <= 128; ++i){ acc += log((double)i); lf[i] = acc; }
  }
  int t = threadIdx.x;
  int b, j, off;
  if(t < 64){ b = 32; j = t; off = 0; }
  else if(t < 96){ b = 16; j = t - 64; off = 64; }
  else if(t < 112){ b = 8; j = t - 96; off = 96; }
  else if(t < 120){ b = 4; j = t - 112; off = 112; }
  else return;
  double beta = PI_D * (2*j+1) / (4.0*b);
  double s = 0.0;
  for(int p = 0; p < b; ++p) s += sin((2*p+1)*beta) / (2*p+1);
  wq[off+j] = 2.0*PI_D/((double)b*b) * sin(beta) * s;
}

__global__ void k_twiddle(cplx* E, int nfreq, int n, int center, double sgn){
  int idx = blockIdx.x*blockDim.x + threadIdx.x;
  if(idx >= nfreq*n) return;
  int p = idx / n, a = idx % n;
  double ang = sgn * 2.0*PI_D * (double)(p-center) * (double)a / (double)n;
  E[idx] = make_float2((float)cos(ang), (float)sin(ang));
}

// Wigner-d, n=0 column only; smode: 0 none, 1 *(2l+1), 2 *wqs[j]
__global__ void k_wigner_col0(const double* __restrict__ lf, float* __restrict__ out,
                              int nb, int Lmax, int W, int mode, int bq,
                              const double* __restrict__ wqs, int smode){
  int idx = blockIdx.x*blockDim.x + threadIdx.x;
  int total = nb*Lmax*W;
  if(idx >= total) return;
  int m = idx % W;
  int l = (idx/W) % Lmax;
  int j = idx/(W*Lmax);
  int cw = (W-1)/2;
  int mh = m - cw;
  float r = 0.f;
  if(iabs_(mh) <= l){
    double beta = (mode==0) ? PI_D*(2*j+1)/(4.0*bq) : PI_D*(j+1)/16.0;
    double cb = cos(0.5*beta), sb = sin(0.5*beta);
    double lcb = log(cb), lsb = log(sb);
    int k0 = (mh < 0) ? -mh : 0;
    int k1 = (mh > 0) ? (l - mh) : l;
    double s = 0.0;
    for(int k = k0; k <= k1; ++k){
      double logc = 0.5*(lf[l+mh] + lf[l-mh] + 2.0*lf[l])
                    - lf[l-k] - lf[k] - lf[mh+k] - lf[l-mh-k];
      double term = exp(logc + (double)(2*l - mh - 2*k)*lcb + (double)(mh + 2*k)*lsb);
      s += ((mh + k) & 1) ? -term : term;
    }
    if(smode == 1) s *= (double)(2*l+1);
    else if(smode == 2) s *= wqs[j];
    r = (float)s;
  }
  out[idx] = r;
}

// Full Wigner-d; smode: 0 none, 1 *(2l+1), 2 *wqs[j]
__global__ void k_wigner_full(const double* __restrict__ lf, float* __restrict__ out,
                              int nb, int L, int W, int mode, int bq,
                              const double* __restrict__ wqs, int smode){
  int idx = blockIdx.x*blockDim.x + threadIdx.x;
  int total = nb*L*W*W;
  if(idx >= total) return;
  int q = idx % W;
  int p = (idx/W) % W;
  int l = (idx/(W*W)) % L;
  int j = idx/(W*W*L);
  int cw = (W-1)/2;
  int mh = p - cw, nh = q - cw;
  float r = 0.f;
  if(iabs_(mh) <= l && iabs_(nh) <= l){
    double beta = (mode==0) ? PI_D*(2*j+1)/(4.0*bq) : PI_D*(j+1)/16.0;
    double cb = cos(0.5*beta), sb = sin(0.5*beta);
    double lcb = log(cb), lsb = log(sb);
    int k0 = (nh - mh > 0) ? (nh - mh) : 0;
    int a1 = l + nh, b1 = l - mh;
    int k1 = (a1 < b1) ? a1 : b1;
    double s = 0.0;
    for(int k = k0; k <= k1; ++k){
      double logc = 0.5*(lf[l+mh] + lf[l-mh] + lf[l+nh] + lf[l-nh])
                    - lf[l+nh-k] - lf[k] - lf[mh-nh+k] - lf[l-mh-k];
      double term = exp(logc + (double)(2*l + nh - mh - 2*k)*lcb + (double)(mh - nh + 2*k)*lsb);
      s += ((mh - nh + k) & 1) ? -term : term;
    }
    if(smode == 1) s *= (double)(2*l+1);
    else if(smode == 2) s *= wqs[j];
    r = (float)s;
  }
  out[idx] = r;
}

// K[l,l',pq]  = sum_j Wx[j,l,pg,qg]*Wi[j,l',pg,qg]
// KB[l,l',pq] = sum_j Wx[j,l,pg,qg]*Wi[j,l',M-1-pg,M-1-qg]
__global__ void k_ktab(const float* __restrict__ Wx, const float* __restrict__ Wi,
                       float* __restrict__ K, float* __restrict__ KB,
                       int Lout, int Lz, int Lfull, int Mt, int M, int off, int nj){
  int MtMt = Mt*Mt;
  int total = Lout*Lz*MtMt;
  int idx = blockIdx.x*blockDim.x + threadIdx.x;
  if(idx >= total) return;
  int pq = idx % MtMt;
  int lp = (idx/MtMt) % Lz;
  int l = idx/(MtMt*Lz);
  int p = pq/Mt, q = pq - p*Mt;
  int pg = p + off, qg = q + off;
  float sA = 0.f, sB = 0.f;
  for(int j = 0; j < nj; ++j){
    float wx = Wx[(((size_t)j*Lfull + l)*M + pg)*M + qg];
    sA += wx * Wi[(((size_t)j*Lfull + lp)*M + pg)*M + qg];
    sB += wx * Wi[(((size_t)j*Lfull + lp)*M + (M-1-pg))*M + (M-1-qg)];
  }
  K[idx] = sA;
  KB[idx] = sB;
}

__global__ void k_wxdc(const float* __restrict__ Wx, float* __restrict__ dc,
                       int Lout, int Lfull, int M, int nj){
  int l = threadIdx.x;
  if(l >= Lout) return;
  int c0 = (M-1)/2;
  float s = 0.f;
  for(int j = 0; j < nj; ++j)
    s += Wx[(((size_t)j*Lfull + l)*M + c0)*M + c0];
  dc[l] = s;
}

// ======================= layer-0 (S2) kernels =======================
__global__ void k_fft0(const float* __restrict__ x, cplx* __restrict__ xf, const cplx* __restrict__ E0f){
  int idx = blockIdx.x*blockDim.x + threadIdx.x;
  if(idx >= 1536*31) return;
  int m = idx % 31;
  int r = idx / 31;
  const float* xr = x + (size_t)r*64;
  float sr = 0.f, si = 0.f;
  for(int a = 0; a < 64; ++a){
    cplx e = E0f[m*64 + a];
    float v = xr[a];
    sr += v*e.x; si += v*e.y;
  }
  xf[idx] = make_float2(sr*(1.f/64.f), si*(1.f/64.f));
}

__global__ void k_what0(const float* __restrict__ w0, const cplx* __restrict__ E0f, cplx* __restrict__ what0){
  int idx = blockIdx.x*blockDim.x + threadIdx.x;
  if(idx >= 96*2*31) return;
  int m = idx % 31;
  int bi = (idx/31) & 1;
  int oi = idx/62;
  const float* wr = w0 + (size_t)oi*128 + bi*64;
  float sr = 0.f, si = 0.f;
  for(int a = 0; a < 64; ++a){
    cplx e = E0f[m*64 + a];
    float v = wr[a];
    sr += v*e.x; si += v*e.y;
  }
  what0[idx] = make_float2(sr, si);
}

__global__ void k_X0(const cplx* __restrict__ xf, const float* __restrict__ d032w,
                     cplx* __restrict__ X0){
  int idx = blockIdx.x*blockDim.x + threadIdx.x;
  if(idx >= 24*16*31) return;
  int m = idx % 31;
  int l = (idx/31) % 16;
  int ci = idx/(31*16);
  float sx = 0.f, sy = 0.f;
  if(iabs_(m-15) <= l){
    for(int j = 0; j < 64; ++j){
      float d = d032w[((size_t)j*16 + l)*31 + m];
      cplx v = xf[((size_t)ci*64 + j)*31 + m];
      sx += d*v.x; sy += d*v.y;
    }
  }
  X0[idx] = make_float2(sx, sy);
}

__global__ void k_Psi0(const cplx* __restrict__ what0, const float* __restrict__ dg32, cplx* __restrict__ Psi0){
  int idx = blockIdx.x*blockDim.x + threadIdx.x;
  if(idx >= 96*16*31) return;
  int m = idx % 31;
  int l = (idx/31) % 16;
  int oi = idx/(31*16);
  float sx = 0.f, sy = 0.f;
  if(iabs_(m-15) <= l){
    for(int bi = 0; bi < 2; ++bi){
      float d = dg32[((size_t)bi*16 + l)*31 + m];
      cplx v = what0[((size_t)oi*2 + bi)*31 + m];
      sx += d*v.x; sy += d*v.y;
    }
  }
  Psi0[idx] = make_float2(sx, sy);
}

__global__ void k_Z0(const cplx* __restrict__ X0, const cplx* __restrict__ Psi0, cplx* __restrict__ Z){
  int idx = blockIdx.x*blockDim.x + threadIdx.x;
  if(idx >= 8*32*16*961) return;
  int q = idx % 31;
  int p = (idx/31) % 31;
  int l = (idx/961) % 16;
  int o = (idx/(961*16)) % 32;
  int c = idx/(961*16*32);
  float sx = 0.f, sy = 0.f;
  if(iabs_(p-15) <= l && iabs_(q-15) <= l){
    for(int i = 0; i < 3; ++i){
      cplx a = X0[(((size_t)c*3 + i)*16 + l)*31 + p];
      cplx b = Psi0[(((size_t)o*3 + i)*16 + l)*31 + q];
      sx += a.x*b.x + a.y*b.y;
      sy += a.y*b.x - a.x*b.y;
    }
  }
  Z[idx] = make_float2(sx, sy);
}

// ======================= j-batched tiled SO3 inverse FFT =======================
template<int JB>
__global__ void k_ifft_b(const cplx* __restrict__ Zt, const float* __restrict__ Wst,
                         const cplx* __restrict__ E, float* __restrict__ out, int b){
  int M = 2*b-1, n2 = 2*b, Mp = n2, Mpt = n2+2, cw = b-1;
  int ng = (M+3)/4;
  extern __shared__ char smem[];
  cplx* Es = (cplx*)smem;              // M*n2
  cplx* gt = Es + M*n2;                // JB*M*Mp
  cplx* Tt = gt + JB*M*Mp;             // JB*n2*Mpt
  int nj = n2/JB;
  int j0 = (blockIdx.x % nj)*JB;
  int co = blockIdx.x / nj;
  int tid = threadIdx.x, bd = blockDim.x;
  for(int t = tid; t < M*n2; t += bd) Es[t] = E[t];
  for(int t = tid; t < JB*M*(Mp-M); t += bd){
    int s = t/(M*(Mp-M));
    int rr = t - s*(M*(Mp-M));
    int r = rr/(Mp-M), c = M + rr%(Mp-M);
    gt[s*M*Mp + r*Mp + c] = make_float2(0.f, 0.f);
  }
  const cplx* Zp = Zt + (size_t)co*b*M*M;
  for(int t = tid; t < M*M; t += bd){
    int p = t/M, q = t - p*M;
    int lmin = iabs_(p-cw); int l2 = iabs_(q-cw); if(l2 > lmin) lmin = l2;
    float sx[JB], sy[JB];
    #pragma unroll
    for(int s = 0; s < JB; ++s){ sx[s] = 0.f; sy[s] = 0.f; }
    for(int l = lmin; l < b; ++l){
      cplx z = Zp[(size_t)l*M*M + t];
      #pragma unroll
      for(int s = 0; s < JB; ++s){
        float w = Wst[((size_t)(j0+s)*b + l)*M*M + t];
        sx[s] += w*z.x; sy[s] += w*z.y;
      }
    }
    #pragma unroll
    for(int s = 0; s < JB; ++s)
      gt[s*M*Mp + p*Mp + q] = make_float2(sx[s], sy[s]);
  }
  __syncthreads();
  int tpj = n2*ng;
  int slab = tid / tpj, tl = tid - slab*tpj;
  {
    int a = tl/ng, qg = tl - a*ng; int q0 = 4*qg;
    const cplx* gts = gt + slab*M*Mp;
    float ax0=0,ax1=0,ax2=0,ax3=0, ay0=0,ay1=0,ay2=0,ay3=0;
    for(int p = 0; p < M; ++p){
      cplx e = Es[p*n2 + a];
      const float4* g4 = (const float4*)(gts + p*Mp + q0);
      float4 ga = g4[0], gb = g4[1];
      ax0 += ga.x*e.x - ga.y*e.y; ay0 += ga.x*e.y + ga.y*e.x;
      ax1 += ga.z*e.x - ga.w*e.y; ay1 += ga.z*e.y + ga.w*e.x;
      ax2 += gb.x*e.x - gb.y*e.y; ay2 += gb.x*e.y + gb.y*e.x;
      ax3 += gb.z*e.x - gb.w*e.y; ay3 += gb.z*e.y + gb.w*e.x;
    }
    cplx* tp = Tt + slab*n2*Mpt + a*Mpt + q0;
    tp[0] = make_float2(ax0,ay0); tp[1] = make_float2(ax1,ay1);
    tp[2] = make_float2(ax2,ay2); tp[3] = make_float2(ax3,ay3);
  }
  __syncthreads();
  {
    int gc = n2/4;
    int a = tl/gc, gg = tl - a*gc; int g0 = 4*gg;
    if(a < n2){
      const cplx* Tts = Tt + slab*n2*Mpt;
      float s0=0,s1=0,s2=0,s3=0;
      for(int q = 0; q < M; ++q){
        cplx T = Tts[a*Mpt + q];
        const float4* e4 = (const float4*)(Es + q*n2 + g0);
        float4 ea = e4[0], eb = e4[1];
        s0 += T.x*ea.x - T.y*ea.y;
        s1 += T.x*ea.z - T.y*ea.w;
        s2 += T.x*eb.x - T.y*eb.y;
        s3 += T.x*eb.z - T.y*eb.w;
      }
      float* op = out + (size_t)co*n2*n2*n2 + (size_t)(j0+slab)*n2*n2 + a*n2 + g0;
      *(float4*)op = make_float4(s0,s1,s2,s3);
    }
  }
}

// small (b=4) ifft
__global__ void k_ifft_s(const cplx* __restrict__ Zt, const float* __restrict__ Wst,
                         const cplx* __restrict__ E, float* __restrict__ out, int b){
  int M = 2*b-1, n2 = 2*b, cw = b-1;
  extern __shared__ char smem[];
  cplx* gt = (cplx*)smem;
  cplx* Tt = gt + M*M;
  int blk = blockIdx.x;
  int j = blk % n2;
  int co = blk / n2;
  const cplx* Zp = Zt + (size_t)co * b * M * M;
  for(int t = threadIdx.x; t < M*M; t += blockDim.x){
    int p = t / M, q = t % M;
    int lmin = iabs_(p-cw); int l2 = iabs_(q-cw); if(l2 > lmin) lmin = l2;
    float sx = 0.f, sy = 0.f;
    for(int l = lmin; l < b; ++l){
      float w = Wst[(((size_t)j*b + l)*M + p)*M + q];
      cplx z = Zp[((size_t)l*M + p)*M + q];
      sx += w*z.x; sy += w*z.y;
    }
    gt[t] = make_float2(sx, sy);
  }
  __syncthreads();
  for(int t = threadIdx.x; t < n2*M; t += blockDim.x){
    int a = t / M, q = t % M;
    float sx = 0.f, sy = 0.f;
    for(int p = 0; p < M; ++p){
      cplx e = E[p*n2 + a];
      cplx g = gt[p*M + q];
      sx += g.x*e.x - g.y*e.y;
      sy += g.x*e.y + g.y*e.x;
    }
    Tt[t] = make_float2(sx, sy);
  }
  __syncthreads();
  float* op = out + (size_t)co*n2*n2*n2 + (size_t)j*n2*n2;
  for(int t = threadIdx.x; t < n2*n2; t += blockDim.x){
    int a = t / n2, g = t % n2;
    float s = 0.f;
    for(int q = 0; q < M; ++q){
      cplx e = E[q*n2 + g];
      cplx T = Tt[a*M + q];
      s += T.x*e.x - T.y*e.y;
    }
    op[t] = s;
  }
}

// ===== gstat: Wigner-stage + Parseval GN stats in frequency domain =====
// part[co*nj + jg] = (sum_j Re g[DC],  sum_j sum_pq |(g[m]+conj g[-m])/2|^2)
template<int JB>
__global__ void k_gstat(const cplx* __restrict__ Zt, const float* __restrict__ Wst,
                        float2* __restrict__ part, int b){
  int M = 2*b-1, n2 = 2*b, cw = b-1;
  int MM = M*M, center = (MM-1)/2;
  extern __shared__ char smem[];
  cplx* gt = (cplx*)smem;   // JB*MM
  __shared__ float2 red[256];
  int nj = n2/JB;
  int j0 = (blockIdx.x % nj)*JB;
  int co = blockIdx.x / nj;
  int tid = threadIdx.x, bd = blockDim.x;
  const cplx* Zp = Zt + (size_t)co*b*MM;
  for(int t = tid; t < MM; t += bd){
    int p = t/M, q = t - p*M;
    int lmin = iabs_(p-cw); int l2 = iabs_(q-cw); if(l2 > lmin) lmin = l2;
    float sx[JB], sy[JB];
    #pragma unroll
    for(int s = 0; s < JB; ++s){ sx[s] = 0.f; sy[s] = 0.f; }
    for(int l = lmin; l < b; ++l){
      cplx z = Zp[(size_t)l*MM + t];
      #pragma unroll
      for(int s = 0; s < JB; ++s){
        float w = Wst[((size_t)(j0+s)*b + l)*MM + t];
        sx[s] += w*z.x; sy[s] += w*z.y;
      }
    }
    #pragma unroll
    for(int s = 0; s < JB; ++s)
      gt[s*MM + t] = make_float2(sx[s], sy[s]);
  }
  __syncthreads();
  float a1 = 0.f, a2 = 0.f;
  for(int t = tid; t < MM; t += bd){
    int mt = MM-1-t;
    #pragma unroll
    for(int s = 0; s < JB; ++s){
      cplx g = gt[s*MM + t];
      cplx m = gt[s*MM + mt];
      float hx = 0.5f*(g.x + m.x);
      float hy = 0.5f*(g.y - m.y);
      a2 += hx*hx + hy*hy;
      if(t == center) a1 += g.x;
    }
  }
  red[tid] = make_float2(a1, a2);
  __syncthreads();
  for(int o = 128; o > 0; o >>= 1){
    if(tid < o){ red[tid].x += red[tid+o].x; red[tid].y += red[tid+o].y; }
    __syncthreads();
  }
  if(tid == 0) part[blockIdx.x] = red[0];
}

__global__ void k_gstat_fin(const float2* __restrict__ part, float2* __restrict__ st,
                            int N, int Cch, int G, int nj, float denom_inv){
  int gi = threadIdx.x;
  if(gi >= N*G) return;
  int n = gi/G, grp = gi - n*G;
  int cpg = Cch/G;
  double s1 = 0.0, s2 = 0.0;
  for(int cc = 0; cc < cpg; ++cc){
    int co = n*Cch + grp*cpg + cc;
    for(int jg = 0; jg < nj; ++jg){
      float2 v = part[co*nj + jg];
      s1 += v.x; s2 += v.y;
    }
  }
  double mu = s1*denom_inv;
  double e2 = s2*denom_inv;
  st[gi] = make_float2((float)mu, (float)(1.0/sqrt(e2 - mu*mu + 1e-5)));
}

// ===== k_xk: fused ifft->GN(affine)->fft2->Xstep via K tables =====
// X[ci,l,p,q] = s_c*0.5*(sum K*Z(m) + conj(sum KB*Z(-m))) + t_c*WxDC[l]*delta_DC
__global__ void k_xk(const cplx* __restrict__ Z, const float* __restrict__ K,
                     const float* __restrict__ KB, const float* __restrict__ WxDC,
                     const float2* __restrict__ st, const float* __restrict__ gam,
                     const float* __restrict__ bet, cplx* __restrict__ X,
                     int CI, int Cch, int G, int Lout, int Lz, int Mt, int M, int off){
  int MtMt = Mt*Mt;
  int total = CI*MtMt;
  int idx = blockIdx.x*blockDim.x + threadIdx.x;
  if(idx >= total) return;
  int pq = idx % MtMt;
  int ci = idx/MtMt;
  int p = pq/Mt, q = pq - p*Mt;
  int cwt = (Mt-1)/2;
  int dp = iabs_(p-cwt), dq = iabs_(q-cwt);
  int lmin = dp > dq ? dp : dq;
  int n = ci/Cch, c = ci - n*Cch;
  int cpg = Cch/G;
  float2 sv = st[n*G + c/cpg];
  float sc = sv.y*gam[c];
  float tc = bet[c] - sv.x*sc;
  int pg = p + off, qg = q + off;
  const cplx* Za = Z + (size_t)ci*Lz*M*M + (size_t)pg*M + qg;
  const cplx* Zb = Z + (size_t)ci*Lz*M*M + (size_t)(M-1-pg)*M + (M-1-qg);
  for(int l = 0; l < Lout; ++l){
    cplx o = make_float2(0.f, 0.f);
    if(l >= lmin){
      float Ax=0.f, Ay=0.f, Bx=0.f, By=0.f;
      const float* Kl = K + ((size_t)l*Lz)*MtMt + pq;
      const float* KBl = KB + ((size_t)l*Lz)*MtMt + pq;
      for(int lp = lmin; lp < Lz; ++lp){
        float k = Kl[(size_t)lp*MtMt];
        float kb = KBl[(size_t)lp*MtMt];
        cplx za = Za[(size_t)lp*M*M];
        cplx zb = Zb[(size_t)lp*M*M];
        Ax += k*za.x; Ay += k*za.y;
        Bx += kb*zb.x; By += kb*zb.y;
      }
      o.x = 0.5f*sc*(Ax + Bx);
      o.y = 0.5f*sc*(Ay - By);
      if(dp == 0 && dq == 0) o.x += tc*WxDC[l];
    }
    X[((size_t)(ci*Lout + l)*Mt + p)*Mt + q] = o;
  }
}

// ======================= batched forward 2D DFT (+fused GN apply) =======================
__global__ void k_fft2_b(const float* __restrict__ f, cplx* __restrict__ hf,
                         const cplx* __restrict__ E, int b, int Mt, int JB,
                         const float2* __restrict__ st, const float* __restrict__ gam,
                         const float* __restrict__ bet, int Cch, int cpg, int relu){
  int M = 2*b-1, n2 = 2*b;
  int off = (M - Mt)/2;
  int ng = (Mt+3)/4, MtP = 4*ng;
  int fs = n2+1, es = n2+1;
  int tpj = n2*ng;
  extern __shared__ char smem[];
  float* ft = (float*)smem;                       // JB*n2*fs
  cplx* Ft  = (cplx*)(ft + JB*n2*fs);             // JB*n2*MtP
  cplx* EsT = Ft + (size_t)JB*n2*MtP;             // n2*MtP
  cplx* Es  = EsT + (size_t)n2*MtP;               // Mt*es
  int nj = n2/JB;
  int ci = blockIdx.x / nj, jg = blockIdx.x % nj;
  int tid = threadIdx.x, bd = blockDim.x;
  float mu = 0.f, inv = 1.f, ga = 1.f, be = 0.f;
  if(st){
    int c = ci % Cch, n = ci / Cch;
    float2 sv = st[n*(Cch/cpg) + c/cpg];
    mu = sv.x; inv = sv.y; ga = gam[c]; be = bet[c];
  }
  const float* fbase = f + ((size_t)ci*n2 + (size_t)jg*JB)*n2*n2;
  for(int t = tid; t < JB*n2*n2; t += bd){
    int sj = t/(n2*n2); int r = t - sj*n2*n2;
    float v = fbase[(size_t)sj*n2*n2 + r];
    if(st){ v = (v - mu)*inv*ga + be; if(relu) v = fmaxf(v, 0.f); }
    ft[sj*n2*fs + (r/n2)*fs + (r%n2)] = v;
  }
  for(int t = tid; t < n2*MtP; t += bd){
    int g = t/MtP, q = t - g*MtP;
    cplx v = make_float2(0.f, 0.f);
    if(q < Mt) v = E[(q+off)*n2 + g];
    EsT[t] = v;
  }
  for(int t = tid; t < Mt*n2; t += bd){
    int r = t/n2, a = t - r*n2;
    Es[r*es + a] = E[(r+off)*n2 + a];
  }
  __syncthreads();
  int slab = tid / tpj, tl = tid - slab*tpj;
  {
    int a = tl/ng, qg = tl - a*ng; int q0 = 4*qg;
    const float* fr = ft + slab*n2*fs + a*fs;
    float ax0=0,ax1=0,ax2=0,ax3=0, ay0=0,ay1=0,ay2=0,ay3=0;
    for(int g = 0; g < n2; ++g){
      float v = fr[g];
      const float4* e4 = (const float4*)(EsT + g*MtP + q0);
      float4 ea = e4[0], eb = e4[1];
      ax0 += v*ea.x; ay0 -= v*ea.y;
      ax1 += v*ea.z; ay1 -= v*ea.w;
      ax2 += v*eb.x; ay2 -= v*eb.y;
      ax3 += v*eb.z; ay3 -= v*eb.w;
    }
    cplx* Fp = Ft + slab*n2*MtP + a*MtP + q0;
    Fp[0] = make_float2(ax0,ay0); Fp[1] = make_float2(ax1,ay1);
    Fp[2] = make_float2(ax2,ay2); Fp[3] = make_float2(ax3,ay3);
  }
  __syncthreads();
  {
    int p = tl/ng, qg = tl - p*ng; int q0 = 4*qg;
    if(p < Mt){
      float ax0=0,ax1=0,ax2=0,ax3=0, ay0=0,ay1=0,ay2=0,ay3=0;
      const cplx* Fb = Ft + slab*n2*MtP;
      for(int a = 0; a < n2; ++a){
        cplx e = Es[p*es + a];
        const float4* F4 = (const float4*)(Fb + a*MtP + q0);
        float4 Fa = F4[0], Fbv = F4[1];
        ax0 += e.x*Fa.x + e.y*Fa.y;  ay0 += e.x*Fa.y - e.y*Fa.x;
        ax1 += e.x*Fa.z + e.y*Fa.w;  ay1 += e.x*Fa.w - e.y*Fa.z;
        ax2 += e.x*Fbv.x + e.y*Fbv.y; ay2 += e.x*Fbv.y - e.y*Fbv.x;
        ax3 += e.x*Fbv.z + e.y*Fbv.w; ay3 += e.x*Fbv.w - e.y*Fbv.z;
      }
      float invn = 1.0f/((float)n2*(float)n2);
      int j = jg*JB + slab;
      cplx* hp = hf + ((size_t)ci*n2 + j)*Mt*Mt + p*Mt;
      if(q0   < Mt) hp[q0  ] = make_float2(ax0*invn, ay0*invn);
      if(q0+1 < Mt) hp[q0+1] = make_float2(ax1*invn, ay1*invn);
      if(q0+2 < Mt) hp[q0+2] = make_float2(ax2*invn, ay2*invn);
      if(q0+3 < Mt) hp[q0+3] = make_float2(ax3*invn, ay3*invn);
    }
  }
}

// X[ci,l,p,q] = sum_j Wx[j,l,p,q]*hf[ci,j,p,q]
__global__ void k_Xstep(const cplx* __restrict__ hf, const float* __restrict__ Wst,
                        cplx* __restrict__ X, int b, int Lout, int Mt, int CI){
  int M = 2*b-1, n2 = 2*b;
  int off = (M - Mt)/2, cw = (Mt-1)/2;
  int total = CI*Lout*Mt*Mt;
  int idx = blockIdx.x*blockDim.x + threadIdx.x;
  if(idx >= total) return;
  int q = idx % Mt;
  int p = (idx/Mt) % Mt;
  int l = (idx/(Mt*Mt)) % Lout;
  int ci = idx/(Mt*Mt*Lout);
  float sx = 0.f, sy = 0.f;
  if(iabs_(p-cw) <= l && iabs_(q-cw) <= l){
    for(int j = 0; j < n2; ++j){
      float w = Wst[(((size_t)j*b + l)*M + p + off)*M + q + off];
      cplx v = hf[(((size_t)ci*n2 + j)*Mt + p)*Mt + q];
      sx += w*v.x; sy += w*v.y;
    }
  }
  X[idx] = make_float2(sx, sy);
}

__global__ void k_what(const float* __restrict__ w, cplx* __restrict__ what,
                       const cplx* __restrict__ E, int n2, int Mt, int off, int OI){
  int total = OI*2*Mt;
  int idx = blockIdx.x*blockDim.x + threadIdx.x;
  if(idx >= total) return;
  int p = idx % Mt;
  int bi = (idx/Mt) & 1;
  int oi = idx/(2*Mt);
  const float* wr = w + (size_t)oi*4*n2 + (size_t)bi*2*n2;
  float sr = 0.f, si = 0.f;
  for(int a = 0; a < n2; ++a){
    float v = wr[2*a] + wr[2*a+1];
    cplx e = E[(p+off)*n2 + a];
    sr += v*e.x; si -= v*e.y;
  }
  what[idx] = make_float2(sr, si);
}

// ---- factorized spectral conv ----
__global__ void k_ystep(const cplx* __restrict__ X, const float* __restrict__ Dg,
                        cplx* __restrict__ Y, int CI, int Wt, int Wd, int Lx, int Ld){
  int l = blockIdx.z;
  int K21 = 2*l+1;
  int cw = (Wt-1)/2, cwd = (Wd-1)/2;
  int l0 = cw - l, l0d = cwd - l;
  int tot = CI*2*K21*K21;
  int idx = blockIdx.x*blockDim.x + threadIdx.x;
  if(idx >= tot) return;
  int qq = idx % K21;
  int bi = (idx/K21) & 1;
  int rest = idx/(2*K21);
  int pp = rest % K21;
  int ci = rest / K21;
  size_t yoff = (size_t)CI*2*((size_t)l*(2*l-1)*(2*l+1)/3);
  const cplx* xp = X + (((size_t)ci*Lx + l)*Wt + (pp+l0))*Wt + l0;
  const float* dp = Dg + (((size_t)bi*Ld + l)*Wd + (qq+l0d))*Wd + l0d;
  float sx = 0.f, sy = 0.f;
  for(int k = 0; k < K21; ++k){
    float d = dp[k];
    cplx v = xp[k];
    sx += d*v.x; sy += d*v.y;
  }
  Y[yoff + (((size_t)ci*K21 + pp)*2 + bi)*K21 + qq] = make_float2(sx, sy);
}

__global__ void k_zstep(const cplx* __restrict__ Y, const cplx* __restrict__ what,
                        cplx* __restrict__ Z, int C, int O, int I, int Wt, int No){
  int l = blockIdx.z;
  int Lz = gridDim.z;
  int K21 = 2*l+1;
  int cw = (Wt-1)/2;
  int l0 = cw - l;
  int Og = O/No;
  int tot = C*Og*Wt*Wt;
  int idx = blockIdx.x*blockDim.x + threadIdx.x;
  if(idx >= tot) return;
  int q = idx % Wt;
  int p = (idx/Wt) % Wt;
  int og = (idx/(Wt*Wt)) % Og;
  int c = idx/(Wt*Wt*Og);
  bool valid = (iabs_(p-cw) <= l) && (iabs_(q-cw) <= l);
  if(!valid){
    for(int t = 0; t < No; ++t){
      int o = og*No + t;
      Z[((((size_t)c*O + o)*Lz + l)*Wt + p)*Wt + q] = make_float2(0.f, 0.f);
    }
    return;
  }
  int pp = p - l0, qq = q - l0;
  size_t yoff = (size_t)C*I*2*((size_t)l*(2*l-1)*(2*l+1)/3);
  const cplx* yrow = Y + yoff + (((size_t)(c*I)*K21 + pp)*2)*K21 + qq;
  size_t ystride = (size_t)K21*2*K21;
  const cplx* wp = what + q;
  float ax[8], ay[8];
  for(int t = 0; t < No; ++t){ ax[t] = 0.f; ay[t] = 0.f; }
  for(int i = 0; i < I; ++i){
    cplx y0 = yrow[(size_t)i*ystride];
    cplx y1 = yrow[(size_t)i*ystride + K21];
    int wb = ((og*No)*I + i)*2*Wt;
    int ws = I*2*Wt;
    for(int t = 0; t < No; ++t){
      cplx w0 = wp[wb + t*ws];
      cplx w1 = wp[wb + t*ws + Wt];
      ax[t] += y0.x*w0.x + y0.y*w0.y + y1.x*w1.x + y1.y*w1.y;
      ay[t] += y0.y*w0.x - y0.x*w0.y + y1.y*w1.x - y1.x*w1.y;
    }
  }
  for(int t = 0; t < No; ++t){
    int o = og*No + t;
    Z[((((size_t)c*O + o)*Lz + l)*Wt + p)*Wt + q] = make_float2(ax[t], ay[t]);
  }
}

__global__ void k_zid(const cplx* __restrict__ X, const float* __restrict__ w,
                      cplx* __restrict__ Z, int C, int O, int I, int Lz, int Wt, int Wx, int Lx){
  int total = C*O*Lz*Wt*Wt;
  int idx = blockIdx.x*blockDim.x + threadIdx.x;
  if(idx >= total) return;
  int q = idx % Wt;
  int p = (idx/Wt) % Wt;
  int l = (idx/(Wt*Wt)) % Lz;
  int o = (idx/(Wt*Wt*Lz)) % O;
  int c = idx/(Wt*Wt*Lz*O);
  int cw = (Wt-1)/2, offx = (Wx-Wt)/2;
  float sx = 0.f, sy = 0.f;
  if(iabs_(p-cw) <= l && iabs_(q-cw) <= l){
    for(int i = 0; i < I; ++i){
      cplx v = X[((((size_t)c*I + i)*Lx + l)*Wx + p + offx)*Wx + q + offx];
      float wv = w[o*I + i];
      sx += wv*v.x; sy += wv*v.y;
    }
  }
  Z[idx] = make_float2(sx, sy);
}

// ======================= norm (split stats + fused apply) =======================
__global__ void k_nstat_part(const float* __restrict__ x, double2* __restrict__ part,
                             int nch, int len, long stride, long grpbase, int P){
  int gi = blockIdx.x / P, pp = blockIdx.x % P;
  const float* gx = x + (long)gi*grpbase;
  long total = (long)nch*len;
  long per = (total + P - 1)/P;
  long s0 = (long)pp*per;
  long s1 = s0 + per; if(s1 > total) s1 = total;
  double s = 0.0, sq = 0.0;
  for(long f = s0 + threadIdx.x; f < s1; f += blockDim.x){
    long ch = f/len, e = f - ch*len;
    float v = gx[ch*stride + e];
    s += v; sq += (double)v*v;
  }
  __shared__ double rs[256], rq[256];
  int tid = threadIdx.x;
  rs[tid] = s; rq[tid] = sq;
  __syncthreads();
  for(int o = 128; o > 0; o >>= 1){
    if(tid < o){ rs[tid] += rs[tid+o]; rq[tid] += rq[tid+o]; }
    __syncthreads();
  }
  if(tid == 0) part[gi*P + pp] = make_double2(rs[0], rq[0]);
}

__global__ void k_nstat_fin(const double2* __restrict__ part, float2* __restrict__ st,
                            int ngroups, int P, double cnt){
  int gi = threadIdx.x;
  if(gi >= ngroups) return;
  double s = 0.0, sq = 0.0;
  for(int p = 0; p < P; ++p){ double2 v = part[gi*P + p]; s += v.x; sq += v.y; }
  double mu = s/cnt;
  double var = sq/cnt - mu*mu;
  st[gi] = make_float2((float)mu, (float)(1.0/sqrt(var + 1e-5)));
}

// y = relu( relu(gn(a)) + bn(b) )
__global__ void k_addrelu2(const float* __restrict__ a, const float* __restrict__ b,
                           const float2* __restrict__ gst, const float* __restrict__ gga,
                           const float* __restrict__ gbe,
                           const float2* __restrict__ bst, const float* __restrict__ bga,
                           const float* __restrict__ bbe,
                           float* __restrict__ y, int C, int S, int G, int n_total){
  int idx = blockIdx.x*blockDim.x + threadIdx.x;
  if(idx >= n_total) return;
  int c = (idx/S) % C;
  int n = idx/(S*C);
  int cpg = C/G;
  float2 gs = gst[n*G + c/cpg];
  float2 bs = bst[c];
  float va = fmaxf((a[idx]-gs.x)*gs.y*gga[c] + gbe[c], 0.f);
  float vb = (b[idx]-bs.x)*bs.y*bga[c] + bbe[c];
  y[idx] = fmaxf(va + vb, 0.f);
}

__global__ void k_integrate(const float* __restrict__ h, const double* __restrict__ wq4,
                            float* __restrict__ out){
  int nc = blockIdx.x;
  const float* hp = h + (size_t)nc*512;
  float s = 0.f;
  for(int t = threadIdx.x; t < 512; t += 64){
    int j = t >> 6;
    s += hp[t] * (float)wq4[j];
  }
  for(int o = 32; o > 0; o >>= 1) s += __shfl_down(s, o);
  if(threadIdx.x == 0) out[nc] = s * (1.f/64.f);
}

// ======================= launch =======================
extern "C" void kernel_launch(void* const* d_in, const int* in_sizes, int n_in,
                              void* d_out, int out_size, void* d_ws, size_t ws_size,
                              hipStream_t stream){
  const float* xin = (const float*)d_in[0];
  const float* w0p = (const float*)d_in[1];
  const float* g0p = (const float*)d_in[2];
  const float* b0p = (const float*)d_in[3];
  const float* w1ap = (const float*)d_in[4];
  const float* g1ap = (const float*)d_in[5];
  const float* b1ap = (const float*)d_in[6];
  const float* w1bp = (const float*)d_in[7];
  const float* g1bp = (const float*)d_in[8];
  const float* b1bp = (const float*)d_in[9];
  const float* w1sp = (const float*)d_in[10];
  const float* g1sp = (const float*)d_in[11];
  const float* b1sp = (const float*)d_in[12];
  const float* w2ap = (const float*)d_in[13];
  const float* g2ap = (const float*)d_in[14];
  const float* b2ap = (const float*)d_in[15];
  const float* w2bp = (const float*)d_in[16];
  const float* g2bp = (const float*)d_in[17];
  const float* b2bp = (const float*)d_in[18];
  const float* w2sp = (const float*)d_in[19];
  const float* g2sp = (const float*)d_in[20];
  const float* b2sp = (const float*)d_in[21];
  float* outp = (float*)d_out;

  char* ws = (char*)d_ws;
  size_t off = 0;
  auto alloc = [&](size_t bytes)->char*{
    char* p = ws + off;
    off = (off + bytes + 255) & ~(size_t)255;
    return p;
  };
  // tables (persistent)
  double* lf   = (double*)alloc(130*8);
  double* wq   = (double*)alloc(120*8);
  cplx* E16    = (cplx*)alloc(31*32*8);
  cplx* E8     = (cplx*)alloc(15*16*8);
  cplx* E4     = (cplx*)alloc(7*8*8);
  cplx* E0f    = (cplx*)alloc(31*64*8);
  float* d032w = (float*)alloc((size_t)64*16*31*4);
  float* dg32  = (float*)alloc((size_t)2*16*31*4);
  float* Wi16  = (float*)alloc((size_t)32*16*961*4);
  float* Wx16  = (float*)alloc((size_t)32*16*961*4);
  float* Dg16  = (float*)alloc((size_t)2*16*961*4);
  float* Wi8   = (float*)alloc((size_t)16*8*225*4);
  float* Wx8   = (float*)alloc((size_t)16*8*225*4);
  float* Dg8   = (float*)alloc((size_t)2*8*225*4);
  float* Wi4   = (float*)alloc((size_t)8*4*49*4);
  // K tables (fused 1a->1b, 2a->2b links)
  float* K16   = (float*)alloc((size_t)8*16*225*4);
  float* KB16  = (float*)alloc((size_t)8*16*225*4);
  float* K8    = (float*)alloc((size_t)4*8*49*4);
  float* KB8   = (float*)alloc((size_t)4*8*49*4);
  float* WxDC16= (float*)alloc(8*4);
  float* WxDC8 = (float*)alloc(4*4);
  // norm stats
  double2* part = (double2*)alloc(2048*16);
  float2* part_f = (float2*)part;   // alias (gstat partials)
  float2* st_h0 = (float2*)alloc(256*8);
  float2* st_l1 = (float2*)alloc(256*8);
  float2* st_l2 = (float2*)alloc(256*8);
  float2* st_s1 = (float2*)alloc(256*8);
  float2* st_l3 = (float2*)alloc(256*8);
  float2* st_l4 = (float2*)alloc(256*8);
  float2* st_s2 = (float2*)alloc(256*8);
  // arenas
  char* A_ZHF = alloc((size_t)63*1024*1024);
  char* A_X   = alloc((size_t)32*1024*1024);
  char* A_H1  = alloc((size_t)34*1024*1024);
  char* A_H2  = alloc((size_t)34*1024*1024);
  char* A_S   = alloc((size_t)8*1024*1024);

  // phase aliases
  cplx* xf0    = (cplx*)(A_S);
  cplx* X0     = (cplx*)(A_S + (512<<10));
  cplx* what0  = (cplx*)(A_S + (768<<10));
  cplx* Psi0   = (cplx*)(A_S + (1<<20));
  cplx* Zt0    = (cplx*)A_ZHF;
  float* h0    = (float*)A_H1;
  cplx* hf1    = (cplx*)A_ZHF;
  cplx* X1     = (cplx*)A_X;
  cplx* what1a = (cplx*)A_S;
  cplx* Y1a    = (cplx*)A_H2;
  cplx* Z1a    = (cplx*)A_ZHF;
  cplx* X1b    = (cplx*)A_S;                // 3.69 MB (what1a dead after zstep 1a)
  cplx* what1b = (cplx*)(A_S + (4<<20));
  cplx* Y1b    = (cplx*)A_H1;               // h0 dead after fft2(1a)
  cplx* Z1b    = (cplx*)A_ZHF;              // Z1a dead after gstat+xk
  float* left2 = (float*)A_H1;
  cplx* Z1s    = (cplx*)A_ZHF;
  float* sc1   = (float*)(A_H1 + (12<<20));
  float* h1    = (float*)A_H2;              // Y1a dead after zstep(1a)
  cplx* hf2    = (cplx*)A_ZHF;
  cplx* X2     = (cplx*)A_X;
  cplx* what2a = (cplx*)A_S;
  cplx* Y2a    = (cplx*)A_H1;
  cplx* Z2a    = (cplx*)A_ZHF;
  cplx* X2b    = (cplx*)A_S;                // 0.8 MB (what2a dead after zstep 2a)
  cplx* what2b = (cplx*)(A_S + (1<<20));
  cplx* Y2b    = (cplx*)(A_S + (2<<20));
  cplx* Z2b    = (cplx*)A_ZHF;              // Z2a dead after gstat+xk
  float* left4 = (float*)A_H1;
  cplx* Z2s    = (cplx*)A_ZHF;
  float* sc2   = (float*)(A_H1 + (4<<20));
  float* h2    = (float*)(A_H1 + (8<<20));

  auto ifftb_smem = [](int b, int JB)->size_t{
    int M = 2*b-1, n2 = 2*b;
    return (size_t)(M*n2 + JB*M*n2 + JB*n2*(n2+2))*8;
  };
  auto fft2b_smem = [](int b, int Mt, int JB)->size_t{
    int n2 = 2*b; int ng = (Mt+3)/4, MtP = 4*ng;
    return (size_t)(JB*n2*(n2+1))*4 + (size_t)(JB*n2*MtP)*8
         + (size_t)(n2*MtP)*8 + (size_t)(Mt*(n2+1))*8;
  };

  // ---- tables ----
  k_tables<<<1,256,0,stream>>>(lf, wq);
  k_twiddle<<<(31*32+255)/256,256,0,stream>>>(E16, 31, 32, 15,  1.0);
  k_twiddle<<<1,256,0,stream>>>(E8, 15, 16, 7,  1.0);
  k_twiddle<<<1,64,0,stream>>>(E4, 7, 8, 3,  1.0);
  k_twiddle<<<(31*64+255)/256,256,0,stream>>>(E0f, 31, 64, 15, -1.0);
  k_wigner_col0<<<(64*16*31+255)/256,256,0,stream>>>(lf, d032w, 64, 16, 31, 0, 32, wq, 2);
  k_wigner_col0<<<(2*16*31+255)/256,256,0,stream>>>(lf, dg32, 2, 16, 31, 1, 0, wq, 0);
  k_wigner_full<<<(32*16*961+255)/256,256,0,stream>>>(lf, Wi16, 32, 16, 31, 0, 16, wq, 1);
  k_wigner_full<<<(32*16*961+255)/256,256,0,stream>>>(lf, Wx16, 32, 16, 31, 0, 16, wq+64, 2);
  k_wigner_full<<<(2*16*961+255)/256,256,0,stream>>>(lf, Dg16, 2, 16, 31, 1, 0, wq, 0);
  k_wigner_full<<<(16*8*225+255)/256,256,0,stream>>>(lf, Wi8, 16, 8, 15, 0, 8, wq, 1);
  k_wigner_full<<<(16*8*225+255)/256,256,0,stream>>>(lf, Wx8, 16, 8, 15, 0, 8, wq+96, 2);
  k_wigner_full<<<(2*8*225+255)/256,256,0,stream>>>(lf, Dg8, 2, 8, 15, 1, 0, wq, 0);
  k_wigner_full<<<(8*4*49+255)/256,256,0,stream>>>(lf, Wi4, 8, 4, 7, 0, 4, wq, 1);
  // K tables (depend on Wx/Wi)
  k_ktab<<<(8*16*225+255)/256,256,0,stream>>>(Wx16, Wi16, K16, KB16, 8, 16, 16, 15, 31, 8, 32);
  k_ktab<<<(4*8*49+255)/256,256,0,stream>>>(Wx8, Wi8, K8, KB8, 4, 8, 8, 7, 15, 4, 16);
  k_wxdc<<<1,64,0,stream>>>(Wx16, WxDC16, 8, 16, 31, 32);
  k_wxdc<<<1,64,0,stream>>>(Wx8, WxDC8, 4, 8, 15, 16);

  // ---- layer 0: s2_conv(x, w0, 32, 16); GN folded into fft2(1a) staging ----
  k_fft0<<<(1536*31+255)/256,256,0,stream>>>(xin, xf0, E0f);
  k_what0<<<(96*2*31+255)/256,256,0,stream>>>(w0p, E0f, what0);
  k_X0<<<(24*16*31+255)/256,256,0,stream>>>(xf0, d032w, X0);
  k_Psi0<<<(96*16*31+255)/256,256,0,stream>>>(what0, dg32, Psi0);
  k_Z0<<<(8*32*16*961+255)/256,256,0,stream>>>(X0, Psi0, Zt0);
  k_ifft_b<2><<<8*32*16,512,ifftb_smem(16,2),stream>>>(Zt0, Wi16, E16, h0, 16);
  k_nstat_part<<<128*16,256,0,stream>>>(h0, part, 1, 65536, 0, 65536, 16);
  k_nstat_fin<<<1,256,0,stream>>>(part, st_h0, 128, 16, 65536.0);

  // ---- layer 1a: so3_conv(h, w1a, 16, 16) ----
  k_fft2_b<<<256*16,512,fft2b_smem(16,31,2),stream>>>(h0, hf1, E16, 16, 31, 2,
                                                      st_h0, g0p, b0p, 32, 2, 1);
  k_Xstep<<<(256*16*961+255)/256,256,0,stream>>>(hf1, Wx16, X1, 16, 16, 31, 256);
  k_what<<<(1024*2*31+255)/256,256,0,stream>>>(w1ap, what1a, E16, 32, 31, 0, 1024);
  { dim3 g((256*2*961+255)/256,1,16);
    k_ystep<<<g,256,0,stream>>>(X1, Dg16, Y1a, 256, 31, 31, 16, 16); }
  { dim3 g((8*8*961+255)/256,1,16);
    k_zstep<<<g,256,0,stream>>>(Y1a, what1a, Z1a, 8, 32, 32, 31, 4); }
  // GN stats of (unmaterialized) left1 via Parseval on Wigner-stage g
  k_gstat<4><<<256*8,256,(size_t)4*961*8,stream>>>(Z1a, Wi16, part_f, 16);
  k_gstat_fin<<<1,128,0,stream>>>(part_f, st_l1, 8, 32, 16, 8, 1.f/64.f);
  // fused ifft->GN->fft2->Xstep: X1b directly from Z1a
  k_xk<<<(256*225+255)/256,256,0,stream>>>(Z1a, K16, KB16, WxDC16,
                                           st_l1, g1ap, b1ap, X1b,
                                           256, 32, 16, 8, 16, 15, 31, 8);

  // ---- layer 1b: so3_conv(left, w1b, 16, 8) ----
  k_what<<<(2048*2*15+255)/256,256,0,stream>>>(w1bp, what1b, E16, 32, 15, 8, 2048);
  { dim3 g((256*2*225+255)/256,1,8);
    k_ystep<<<g,256,0,stream>>>(X1b, Dg16, Y1b, 256, 15, 31, 8, 16); }
  { dim3 g((8*16*225+255)/256,1,8);
    k_zstep<<<g,256,0,stream>>>(Y1b, what1b, Z1b, 8, 64, 32, 15, 4); }
  k_ifft_b<4><<<8*64*4,256,ifftb_smem(8,4),stream>>>(Z1b, Wi8, E8, left2, 8);
  k_nstat_part<<<128*8,256,0,stream>>>(left2, part, 1, 16384, 0, 16384, 8);
  k_nstat_fin<<<1,256,0,stream>>>(part, st_l2, 128, 8, 16384.0);

  // ---- layer 1s: shortcut conv + BN stats ----
  k_zid<<<(8*64*8*225+255)/256,256,0,stream>>>(X1, w1sp, Z1s, 8, 64, 32, 8, 15, 31, 16);
  k_ifft_b<4><<<8*64*4,256,ifftb_smem(8,4),stream>>>(Z1s, Wi8, E8, sc1, 8);
  k_nstat_part<<<64*8,256,0,stream>>>(sc1, part, 8, 4096, (long)64*4096, 4096, 8);
  k_nstat_fin<<<1,256,0,stream>>>(part, st_s1, 64, 8, 32768.0);
  k_addrelu2<<<(2097152+255)/256,256,0,stream>>>(left2, sc1, st_l2, g1bp, b1bp,
                                                 st_s1, g1sp, b1sp, h1, 64, 4096, 16, 2097152);

  // ---- layer 2a: so3_conv(h, w2a, 8, 8) ----
  k_fft2_b<<<512*4,256,fft2b_smem(8,15,4),stream>>>(h1, hf2, E8, 8, 15, 4,
                                                    (const float2*)nullptr, nullptr, nullptr, 0, 1, 0);
  k_Xstep<<<(512*8*225+255)/256,256,0,stream>>>(hf2, Wx8, X2, 8, 8, 15, 512);
  k_what<<<(4096*2*15+255)/256,256,0,stream>>>(w2ap, what2a, E8, 16, 15, 0, 4096);
  { dim3 g((512*2*225+255)/256,1,8);
    k_ystep<<<g,256,0,stream>>>(X2, Dg8, Y2a, 512, 15, 15, 8, 8); }
  { dim3 g((8*16*225+255)/256,1,8);
    k_zstep<<<g,256,0,stream>>>(Y2a, what2a, Z2a, 8, 64, 64, 15, 4); }
  k_gstat<8><<<512*2,256,(size_t)8*225*8,stream>>>(Z2a, Wi8, part_f, 8);
  k_gstat_fin<<<1,128,0,stream>>>(part_f, st_l3, 8, 64, 16, 2, 1.f/64.f);
  k_xk<<<(512*49+255)/256,256,0,stream>>>(Z2a, K8, KB8, WxDC8,
                                          st_l3, g2ap, b2ap, X2b,
                                          512, 64, 16, 4, 8, 7, 15, 4);

  // ---- layer 2b: so3_conv(left, w2b, 8, 4) ----
  k_what<<<(8192*2*7+255)/256,256,0,stream>>>(w2bp, what2b, E8, 16, 7, 4, 8192);
  { dim3 g((512*2*49+255)/256,1,4);
    k_ystep<<<g,256,0,stream>>>(X2b, Dg8, Y2b, 512, 7, 15, 4, 8); }
  { dim3 g((8*32*49+255)/256,1,4);
    k_zstep<<<g,256,0,stream>>>(Y2b, what2b, Z2b, 8, 128, 64, 7, 4); }
  k_ifft_s<<<8*128*8,64,(49+56)*8,stream>>>(Z2b, Wi4, E4, left4, 4);
  k_nstat_part<<<256*4,256,0,stream>>>(left4, part, 1, 2048, 0, 2048, 4);
  k_nstat_fin<<<1,256,0,stream>>>(part, st_l4, 256, 4, 2048.0);

  // ---- layer 2s: shortcut conv + BN stats ----
  k_zid<<<(8*128*4*49+255)/256,256,0,stream>>>(X2, w2sp, Z2s, 8, 128, 64, 4, 7, 15, 8);
  k_ifft_s<<<8*128*8,64,(49+56)*8,stream>>>(Z2s, Wi4, E4, sc2, 4);
  k_nstat_part<<<128*4,256,0,stream>>>(sc2, part, 8, 512, (long)128*512, 512, 4);
  k_nstat_fin<<<1,256,0,stream>>>(part, st_s2, 128, 4, 4096.0);
  k_addrelu2<<<(524288+255)/256,256,0,stream>>>(left4, sc2, st_l4, g2bp, b2bp,
                                                st_s2, g2sp, b2sp, h2, 128, 512, 32, 524288);

  // ---- integrate ----
  k_integrate<<<1024,64,0,stream>>>(h2, wq+112, outp);
}